// Round 1
// baseline (3531.299 us; speedup 1.0000x reference)
//
#include <hip/hip_runtime.h>

// ---------------------------------------------------------------------------
// BlockRC2: PRM (3 dilated stride-2 convs + GELU) -> LN1 -> kqv ->
// performer attention -> proj+skip -> LN2 -> MLP -> skip.
// Round 1: all-fp32 vector kernels, SGPR-weight GEMM idiom, correctness-first.
// ---------------------------------------------------------------------------

#define TOK 4096          // tokens per batch (64x64)
#define NB  32            // batch

__device__ __forceinline__ float gelu_exact(float v) {
    return 0.5f * v * (1.f + erff(v * 0.70710678118654752f));
}

// ---------------------------------------------------------------------------
// Prep: transpose weights for scalar-load-friendly layouts.
//  conv_w [3][64e][64c][3][3] -> wt [3][kh3][kw3][64c][64e]
//  kqv_w  [192i][192o]        -> kwT [192o][192i]
//  proj_w [64i][64o]          -> pwT [64o][64i]
//  mlp_w1 [64i][64o]          -> w1T [64o][64i]
// ---------------------------------------------------------------------------
__global__ __launch_bounds__(256) void k_prep(
        const float* __restrict__ cw, const float* __restrict__ kw,
        const float* __restrict__ pw, const float* __restrict__ w1,
        float* __restrict__ wt, float* __restrict__ kwT,
        float* __restrict__ pwT, float* __restrict__ w1T) {
    int idx = blockIdx.x * 256 + threadIdx.x;
    if (idx < 110592) {
        int e = idx & 63, r1 = idx >> 6;
        int c = r1 & 63, r2 = r1 >> 6;
        int kwi = r2 % 3, r3 = r2 / 3;
        int kh = r3 % 3, br = r3 / 3;
        wt[idx] = cw[(((br * 64 + e) * 64 + c) * 3 + kh) * 3 + kwi];
    } else if (idx < 110592 + 36864) {
        int i2 = idx - 110592;
        int o = i2 / 192, i = i2 % 192;
        kwT[i2] = kw[i * 192 + o];
    } else if (idx < 110592 + 36864 + 4096) {
        int i2 = idx - (110592 + 36864);
        int o = i2 >> 6, i = i2 & 63;
        pwT[i2] = pw[i * 64 + o];
    } else if (idx < 110592 + 36864 + 8192) {
        int i2 = idx - (110592 + 36864 + 4096);
        int o = i2 >> 6, i = i2 & 63;
        w1T[i2] = w1[i * 64 + o];
    }
}

// ---------------------------------------------------------------------------
// Conv + GELU. Block = (oh, b, br). 256 threads = 4 waves.
// Input x is [b][h*128+w][c] (NHWC, c fastest). LDS: 3 input rows, parity-split
// by iw (stride-2 conv -> all taps hit one parity, lanes read stride-1),
// float4-blocked over c. Wave w accumulates c-subset {w, w+4, w+8, w+12}(x4c)
// for all 64 e; cross-wave reduce via LDS psum.
// ---------------------------------------------------------------------------
__global__ __launch_bounds__(256) void k_conv(
        const float* __restrict__ x, const float* __restrict__ wt,
        const float* __restrict__ cb, float* __restrict__ tokens) {
    const int oh = blockIdx.x;
    const int b  = blockIdx.y;
    const int br = blockIdx.z;
    const int d  = br + 1;
    const int tid = threadIdx.x;
    const int lane = tid & 63;
    const int wv = __builtin_amdgcn_readfirstlane(tid >> 6);

    __shared__ float4 lds4[6528];   // [r(3)*2par][c4(16)][68 iw2]  = 104448 B
    const float4 z4 = make_float4(0.f, 0.f, 0.f, 0.f);
    for (int i = tid; i < 6528; i += 256) lds4[i] = z4;
    __syncthreads();

    for (int r = 0; r < 3; ++r) {
        int ih = 2 * oh + (r - 1) * d;
        if ((unsigned)ih < 128u) {
            const float4* src = (const float4*)(x + ((size_t)(b * 16384 + ih * 128)) * 64);
            for (int it = 0; it < 8; ++it) {
                int flat = it * 256 + tid;           // 0..2047
                int iw = flat >> 4, c4 = flat & 15;
                float4 v = src[iw * 16 + c4];
                lds4[((r * 2 + (iw & 1)) * 16 + c4) * 68 + ((iw + 4) >> 1)] = v;
            }
        }
    }
    __syncthreads();

    float acc[64];
#pragma unroll
    for (int e = 0; e < 64; ++e) acc[e] = 0.f;
    const int ow = lane;

    for (int r = 0; r < 3; ++r) {
        for (int kwi = 0; kwi < 3; ++kwi) {
            const int o = (kwi - 1) * d;
            const int par = (o + 4) & 1;
            const int sh = (o + 4) >> 1;             // iw2 = ow + sh
            const float* wbase = wt + (((br * 3 + r) * 3 + kwi) << 12);
#pragma unroll
            for (int c4i = 0; c4i < 4; ++c4i) {
                const int c4 = wv + (c4i << 2);
                float4 v = lds4[((r * 2 + par) * 16 + c4) * 68 + ow + sh];
#pragma unroll
                for (int cj = 0; cj < 4; ++cj) {
                    const float vv = (cj == 0 ? v.x : cj == 1 ? v.y : cj == 2 ? v.z : v.w);
                    const float* wp = wbase + ((c4 * 4 + cj) << 6);  // 64 e, uniform -> SGPR
#pragma unroll
                    for (int e = 0; e < 64; ++e) acc[e] = fmaf(wp[e], vv, acc[e]);
                }
            }
        }
    }

    __syncthreads();                 // done reading input; reuse LDS as psum
    float* ps = (float*)lds4;        // [4 wave][64 e][65]
#pragma unroll
    for (int e = 0; e < 64; ++e) ps[(wv * 64 + e) * 65 + ow] = acc[e];
    __syncthreads();

    const int eq = tid & 15, owb = tid >> 4;
    for (int it = 0; it < 4; ++it) {
        const int ow2 = owb + (it << 4);
        float4 o4;
#pragma unroll
        for (int j = 0; j < 4; ++j) {
            const int e = eq * 4 + j;
            float s = ps[(0 * 64 + e) * 65 + ow2] + ps[(1 * 64 + e) * 65 + ow2]
                    + ps[(2 * 64 + e) * 65 + ow2] + ps[(3 * 64 + e) * 65 + ow2];
            s += cb[br * 64 + e];
            ((float*)&o4)[j] = gelu_exact(s);
        }
        ((float4*)(tokens + ((size_t)(b * TOK + oh * 64 + ow2)) * 192 + br * 64))[eq] = o4;
    }
}

// ---------------------------------------------------------------------------
// LN1 + kqv GEMM. lane = token; h[192] in VGPRs; weights via scalar loads.
// Output kqvT [b][192 o][4096 t] (o-major, coalesced stores).
// ---------------------------------------------------------------------------
__global__ __launch_bounds__(256, 2) void k_lnkqv(
        const float* __restrict__ tokens, const float* __restrict__ g,
        const float* __restrict__ be, const float* __restrict__ wT,
        const float* __restrict__ bias, float* __restrict__ kqvT) {
    const int b = blockIdx.y;
    const int t = blockIdx.x * 256 + threadIdx.x;
    const float4* row = (const float4*)(tokens + ((size_t)(b * TOK) + t) * 192);
    float4 h[48];
    float mu = 0.f;
#pragma unroll
    for (int i = 0; i < 48; ++i) {
        h[i] = row[i];
        mu += h[i].x + h[i].y + h[i].z + h[i].w;
    }
    mu *= (1.f / 192.f);
    float var = 0.f;
#pragma unroll
    for (int i = 0; i < 48; ++i) {
        float a = h[i].x - mu, b2 = h[i].y - mu, c = h[i].z - mu, dd = h[i].w - mu;
        var += a * a + b2 * b2 + c * c + dd * dd;
    }
    const float rs = rsqrtf(var * (1.f / 192.f) + 1e-5f);
#pragma unroll
    for (int i = 0; i < 48; ++i) {
        h[i].x = (h[i].x - mu) * rs * g[4 * i + 0] + be[4 * i + 0];
        h[i].y = (h[i].y - mu) * rs * g[4 * i + 1] + be[4 * i + 1];
        h[i].z = (h[i].z - mu) * rs * g[4 * i + 2] + be[4 * i + 2];
        h[i].w = (h[i].w - mu) * rs * g[4 * i + 3] + be[4 * i + 3];
    }
    float* dst = kqvT + (size_t)b * 192 * TOK + t;
    for (int o = 0; o < 192; ++o) {
        const float* wr = wT + o * 192;   // uniform -> scalar loads
        float s = bias[o];
#pragma unroll
        for (int i = 0; i < 48; ++i) {
            s = fmaf(wr[4 * i + 0], h[i].x, s);
            s = fmaf(wr[4 * i + 1], h[i].y, s);
            s = fmaf(wr[4 * i + 2], h[i].z, s);
            s = fmaf(wr[4 * i + 3], h[i].w, s);
        }
        dst[(size_t)o * TOK] = s;
    }
}

// ---------------------------------------------------------------------------
// Performer features: kp (from k, rows 0:64) and qp (from q, rows 64:128).
// Both stored m-major [b][32 m][4096 t] (coalesced).
// ---------------------------------------------------------------------------
__global__ __launch_bounds__(256) void k_perf(
        const float* __restrict__ kqvT, const float* __restrict__ wperf,
        float* __restrict__ kpT, float* __restrict__ qpT) {
    const int b = blockIdx.y;
    const int t = blockIdx.x * 256 + threadIdx.x;
    const float* basek = kqvT + (size_t)b * 192 * TOK + t;
    for (int pass = 0; pass < 2; ++pass) {
        float kr[64];
        const float* src = basek + (size_t)pass * 64 * TOK;
#pragma unroll
        for (int i = 0; i < 64; ++i) kr[i] = src[(size_t)i * TOK];
        float xd = 0.f;
#pragma unroll
        for (int i = 0; i < 64; ++i) xd = fmaf(kr[i], kr[i], xd);
        xd *= 0.5f;
        float* dst = (pass == 0 ? kpT : qpT) + (size_t)b * 32 * TOK + t;
        for (int m = 0; m < 32; ++m) {
            const float* wr = wperf + m * 64;   // uniform
            float a = 0.f;
#pragma unroll
            for (int i = 0; i < 64; ++i) a = fmaf(wr[i], kr[i], a);
            dst[(size_t)m * TOK] = expf(a - xd) * 0.17677669529663687f;  // 1/sqrt(32)
        }
    }
}

// ---------------------------------------------------------------------------
// Per-chunk partials: kptv_part[b][ch][64 d][32 m] = sum_t v[t][d]*kp[t][m],
// sumkp_part[b][ch][32 m]. One block per (ch=256 tokens, b).
// ---------------------------------------------------------------------------
__global__ __launch_bounds__(256) void k_kptv(
        const float* __restrict__ kqvT, const float* __restrict__ kpT,
        float* __restrict__ kvp, float* __restrict__ skpp) {
    const int b = blockIdx.y, ch = blockIdx.x, tid = threadIdx.x;
    const int t = ch * 256 + tid;
    __shared__ float sv[256 * 65 + 256 * 36];   // v-tile [t][65], kp-tile [t][36]
    float* skp = sv + 256 * 65;
    for (int dd = 0; dd < 64; ++dd)
        sv[tid * 65 + dd] = kqvT[((size_t)(b * 192 + 128 + dd)) * TOK + t];
    for (int m = 0; m < 32; ++m)
        skp[tid * 36 + m] = kpT[((size_t)(b * 32 + m)) * TOK + t];
    __syncthreads();

    const int dd = tid & 63;
    const int mg = __builtin_amdgcn_readfirstlane(tid >> 6);
    float acc[8];
#pragma unroll
    for (int j = 0; j < 8; ++j) acc[j] = 0.f;
    for (int tt = 0; tt < 256; ++tt) {
        float vv = sv[tt * 65 + dd];
        const float4* kq = (const float4*)(skp + tt * 36 + mg * 8);  // broadcast
        float4 a0 = kq[0], a1 = kq[1];
        acc[0] = fmaf(vv, a0.x, acc[0]);
        acc[1] = fmaf(vv, a0.y, acc[1]);
        acc[2] = fmaf(vv, a0.z, acc[2]);
        acc[3] = fmaf(vv, a0.w, acc[3]);
        acc[4] = fmaf(vv, a1.x, acc[4]);
        acc[5] = fmaf(vv, a1.y, acc[5]);
        acc[6] = fmaf(vv, a1.z, acc[6]);
        acc[7] = fmaf(vv, a1.w, acc[7]);
    }
    float* dst = kvp + (((size_t)(b * 16 + ch) * 64 + dd) * 32) + mg * 8;
#pragma unroll
    for (int j = 0; j < 8; ++j) dst[j] = acc[j];

    if (tid < 32) {
        float s = 0.f;
        for (int tt = 0; tt < 256; ++tt) s += skp[tt * 36 + tid];
        skpp[(b * 16 + ch) * 32 + tid] = s;
    }
}

// Reduce 16 chunk partials -> kptvT [b][32 m][64 d], sum_kp [b][32 m].
__global__ __launch_bounds__(256) void k_reduce(
        const float* __restrict__ kvp, const float* __restrict__ skpp,
        float* __restrict__ kptvT, float* __restrict__ sum_kp) {
    int idx = blockIdx.x * 256 + threadIdx.x;
    if (idx < 65536) {
        int b = idx >> 11, rem = idx & 2047, m = rem >> 6, dd = rem & 63;
        float s = 0.f;
        for (int ch = 0; ch < 16; ++ch) s += kvp[((b * 16 + ch) * 64 + dd) * 32 + m];
        kptvT[idx] = s;     // idx == (b*32+m)*64+dd
    } else if (idx < 65536 + 1024) {
        int i = idx - 65536;
        int b = i >> 5, m = i & 31;
        float s = 0.f;
        for (int ch = 0; ch < 16; ++ch) s += skpp[(b * 16 + ch) * 32 + m];
        sum_kp[i] = s;
    }
}

// ---------------------------------------------------------------------------
// yatt = (qp @ kptv^T)/(D+eps); out = v + yatt@proj + proj_b. lane = token.
// Output yattT [b][64 o][4096 t].
// ---------------------------------------------------------------------------
__global__ __launch_bounds__(256) void k_yatt(
        const float* __restrict__ kqvT, const float* __restrict__ qpT,
        const float* __restrict__ sum_kp, const float* __restrict__ kptvT,
        const float* __restrict__ projT, const float* __restrict__ proj_b,
        float* __restrict__ yattT) {
    const int b = blockIdx.y;
    const int t = blockIdx.x * 256 + threadIdx.x;
    const float* sk = sum_kp + b * 32;
    const float* kv = kptvT + b * 2048;
    const float* qpp = qpT + (size_t)b * 32 * TOK + t;
    float a[64];
#pragma unroll
    for (int i = 0; i < 64; ++i) a[i] = 0.f;
    float D = 0.f;
    for (int m = 0; m < 32; ++m) {
        float q = qpp[(size_t)m * TOK];
        D = fmaf(q, sk[m], D);
        const float* kvr = kv + m * 64;   // uniform
#pragma unroll
        for (int i = 0; i < 64; ++i) a[i] = fmaf(q, kvr[i], a[i]);
    }
    const float rD = 1.f / (D + 1e-8f);
#pragma unroll
    for (int i = 0; i < 64; ++i) a[i] *= rD;

    const float* vb = kqvT + ((size_t)(b * 192 + 128)) * TOK + t;
    float* yb = yattT + (size_t)b * 64 * TOK + t;
    for (int o = 0; o < 64; ++o) {
        const float* pw = projT + o * 64;  // uniform
        float s = proj_b[o];
#pragma unroll
        for (int i = 0; i < 64; ++i) s = fmaf(pw[i], a[i], s);
        s += vb[(size_t)o * TOK];
        yb[(size_t)o * TOK] = s;
    }
}

// ---------------------------------------------------------------------------
// LN2 + MLP + skip. lane = token; out accumulated over hidden i so all register
// arrays are statically indexed. Row-major store via per-wave LDS transpose.
// ---------------------------------------------------------------------------
__global__ __launch_bounds__(256, 2) void k_mlp(
        const float* __restrict__ yattT, const float* __restrict__ g2,
        const float* __restrict__ b2ln, const float* __restrict__ w1T,
        const float* __restrict__ b1, const float* __restrict__ w2,
        const float* __restrict__ b2, float* __restrict__ out) {
    const int b = blockIdx.y;
    const int tid = threadIdx.x;
    const int lane = tid & 63;
    const int wv = tid >> 6;
    const int t = blockIdx.x * 256 + tid;
    __shared__ float tile[4 * 64 * 65];
    float* tl = tile + wv * 64 * 65;

    const float* yb = yattT + (size_t)b * 64 * TOK + t;
    float y[64];
#pragma unroll
    for (int i = 0; i < 64; ++i) y[i] = yb[(size_t)i * TOK];
    float mu = 0.f;
#pragma unroll
    for (int i = 0; i < 64; ++i) mu += y[i];
    mu *= (1.f / 64.f);
    float var = 0.f;
#pragma unroll
    for (int i = 0; i < 64; ++i) { float d = y[i] - mu; var = fmaf(d, d, var); }
    const float rs = rsqrtf(var * (1.f / 64.f) + 1e-5f);
    float h[64];
#pragma unroll
    for (int i = 0; i < 64; ++i) h[i] = (y[i] - mu) * rs * g2[i] + b2ln[i];
    float o[64];
#pragma unroll
    for (int i = 0; i < 64; ++i) o[i] = y[i] + b2[i];

    for (int i = 0; i < 64; ++i) {        // hidden dim, dynamic
        const float* w1r = w1T + i * 64;  // uniform
        float s = b1[i];
#pragma unroll
        for (int j = 0; j < 64; ++j) s = fmaf(w1r[j], h[j], s);
        const float hg = gelu_exact(s);
        const float* w2r = w2 + i * 64;   // uniform (row-major mlp_w2)
#pragma unroll
        for (int j = 0; j < 64; ++j) o[j] = fmaf(w2r[j], hg, o[j]);
    }

#pragma unroll
    for (int i = 0; i < 64; ++i) tl[lane * 65 + i] = o[i];
    __syncthreads();
    const int t0 = blockIdx.x * 256 + wv * 64;
    float* ob = out + ((size_t)b * TOK + t0) * 64;
    for (int it = 0; it < 16; ++it) {
        int flat = it * 64 + lane;
        int trow = flat >> 4, oq = flat & 15;
        float4 v;
        v.x = tl[trow * 65 + oq * 4 + 0];
        v.y = tl[trow * 65 + oq * 4 + 1];
        v.z = tl[trow * 65 + oq * 4 + 2];
        v.w = tl[trow * 65 + oq * 4 + 3];
        ((float4*)(ob + trow * 64))[oq] = v;
    }
}

// ---------------------------------------------------------------------------
extern "C" void kernel_launch(void* const* d_in, const int* in_sizes, int n_in,
                              void* d_out, int out_size, void* d_ws, size_t ws_size,
                              hipStream_t stream) {
    const float* x      = (const float*)d_in[0];
    const float* conv_w = (const float*)d_in[1];
    const float* conv_b = (const float*)d_in[2];
    const float* ln1_g  = (const float*)d_in[3];
    const float* ln1_b  = (const float*)d_in[4];
    const float* kqv_w  = (const float*)d_in[5];
    const float* kqv_b  = (const float*)d_in[6];
    const float* proj_w = (const float*)d_in[7];
    const float* proj_b = (const float*)d_in[8];
    const float* w_perf = (const float*)d_in[9];
    const float* ln2_g  = (const float*)d_in[10];
    const float* ln2_b  = (const float*)d_in[11];
    const float* mlp_w1 = (const float*)d_in[12];
    const float* mlp_b1 = (const float*)d_in[13];
    const float* mlp_w2 = (const float*)d_in[14];
    const float* mlp_b2 = (const float*)d_in[15];

    float* ws = (float*)d_ws;
    // prep weights
    float* wt    = ws;                 // 110592
    float* kqvwT = ws + 110592;        // 36864
    float* projT = ws + 147456;        // 4096
    float* w1T   = ws + 151552;        // 4096
    // big region A (tokens, later reused)
    float* tokens = ws + 155648;       // 25165824 floats
    float* qpT    = tokens;                      // 4194304
    float* kpT    = tokens + 4194304;            // 4194304
    float* skpp   = tokens + 8388608;            // 16384
    float* kvp    = tokens + 8404992;            // 1048576
    float* sum_kp = tokens + 9453568;            // 1024
    float* kptvT  = tokens + 9454592;            // 65536
    float* yattT  = tokens + 9520128;            // 8388608
    // big region B
    float* kqvT   = ws + 155648 + 25165824;      // 25165824
    float* outp   = (float*)d_out;

    k_prep <<<608, 256, 0, stream>>>(conv_w, kqv_w, proj_w, mlp_w1, wt, kqvwT, projT, w1T);
    k_conv <<<dim3(64, 32, 3), 256, 0, stream>>>(x, wt, conv_b, tokens);
    k_lnkqv<<<dim3(16, 32), 256, 0, stream>>>(tokens, ln1_g, ln1_b, kqvwT, kqv_b, kqvT);
    k_perf <<<dim3(16, 32), 256, 0, stream>>>(kqvT, w_perf, kpT, qpT);
    k_kptv <<<dim3(16, 32), 256, 0, stream>>>(kqvT, kpT, kvp, skpp);
    k_reduce<<<261, 256, 0, stream>>>(kvp, skpp, kptvT, sum_kp);
    k_yatt <<<dim3(16, 32), 256, 0, stream>>>(kqvT, qpT, sum_kp, kptvT, projT, proj_b, yattT);
    k_mlp  <<<dim3(16, 32), 256, 0, stream>>>(yattT, ln2_g, ln2_b, w1T, mlp_b1, mlp_w2, mlp_b2, outp);
}

// Round 2
// 2146.898 us; speedup vs baseline: 1.6448x; 1.6448x over previous
//
#include <hip/hip_runtime.h>

// ---------------------------------------------------------------------------
// BlockRC2: PRM (3 dilated stride-2 convs + GELU) -> LN1 -> kqv ->
// performer attention -> proj+skip -> LN2 -> MLP -> skip.
// Round 2: fix register-spill disaster in k_lnkqv/k_mlp (launch_bounds(,2)
// capped VGPRs at 128 while kernels hold ~192 live floats -> scratch spill,
// 19 TB scratch traffic, VALUBusy 3%). Now (256,1): keep state in VGPRs.
// ---------------------------------------------------------------------------

#define TOK 4096          // tokens per batch (64x64)
#define NB  32            // batch

__device__ __forceinline__ float gelu_exact(float v) {
    return 0.5f * v * (1.f + erff(v * 0.70710678118654752f));
}

// ---------------------------------------------------------------------------
// Prep: transpose weights for scalar-load-friendly layouts.
// ---------------------------------------------------------------------------
__global__ __launch_bounds__(256) void k_prep(
        const float* __restrict__ cw, const float* __restrict__ kw,
        const float* __restrict__ pw, const float* __restrict__ w1,
        float* __restrict__ wt, float* __restrict__ kwT,
        float* __restrict__ pwT, float* __restrict__ w1T) {
    int idx = blockIdx.x * 256 + threadIdx.x;
    if (idx < 110592) {
        int e = idx & 63, r1 = idx >> 6;
        int c = r1 & 63, r2 = r1 >> 6;
        int kwi = r2 % 3, r3 = r2 / 3;
        int kh = r3 % 3, br = r3 / 3;
        wt[idx] = cw[(((br * 64 + e) * 64 + c) * 3 + kh) * 3 + kwi];
    } else if (idx < 110592 + 36864) {
        int i2 = idx - 110592;
        int o = i2 / 192, i = i2 % 192;
        kwT[i2] = kw[i * 192 + o];
    } else if (idx < 110592 + 36864 + 4096) {
        int i2 = idx - (110592 + 36864);
        int o = i2 >> 6, i = i2 & 63;
        pwT[i2] = pw[i * 64 + o];
    } else if (idx < 110592 + 36864 + 8192) {
        int i2 = idx - (110592 + 36864 + 4096);
        int o = i2 >> 6, i = i2 & 63;
        w1T[i2] = w1[i * 64 + o];
    }
}

// ---------------------------------------------------------------------------
// Conv + GELU. Block = (oh, b, br). 256 threads = 4 waves.
// ---------------------------------------------------------------------------
__global__ __launch_bounds__(256) void k_conv(
        const float* __restrict__ x, const float* __restrict__ wt,
        const float* __restrict__ cb, float* __restrict__ tokens) {
    const int oh = blockIdx.x;
    const int b  = blockIdx.y;
    const int br = blockIdx.z;
    const int d  = br + 1;
    const int tid = threadIdx.x;
    const int lane = tid & 63;
    const int wv = __builtin_amdgcn_readfirstlane(tid >> 6);

    __shared__ float4 lds4[6528];   // [r(3)*2par][c4(16)][68 iw2]  = 104448 B
    const float4 z4 = make_float4(0.f, 0.f, 0.f, 0.f);
    for (int i = tid; i < 6528; i += 256) lds4[i] = z4;
    __syncthreads();

    for (int r = 0; r < 3; ++r) {
        int ih = 2 * oh + (r - 1) * d;
        if ((unsigned)ih < 128u) {
            const float4* src = (const float4*)(x + ((size_t)(b * 16384 + ih * 128)) * 64);
            for (int it = 0; it < 8; ++it) {
                int flat = it * 256 + tid;           // 0..2047
                int iw = flat >> 4, c4 = flat & 15;
                float4 v = src[iw * 16 + c4];
                lds4[((r * 2 + (iw & 1)) * 16 + c4) * 68 + ((iw + 4) >> 1)] = v;
            }
        }
    }
    __syncthreads();

    float acc[64];
#pragma unroll
    for (int e = 0; e < 64; ++e) acc[e] = 0.f;
    const int ow = lane;

    for (int r = 0; r < 3; ++r) {
        for (int kwi = 0; kwi < 3; ++kwi) {
            const int o = (kwi - 1) * d;
            const int par = (o + 4) & 1;
            const int sh = (o + 4) >> 1;             // iw2 = ow + sh
            const float* wbase = wt + (((br * 3 + r) * 3 + kwi) << 12);
#pragma unroll
            for (int c4i = 0; c4i < 4; ++c4i) {
                const int c4 = wv + (c4i << 2);
                float4 v = lds4[((r * 2 + par) * 16 + c4) * 68 + ow + sh];
#pragma unroll
                for (int cj = 0; cj < 4; ++cj) {
                    const float vv = (cj == 0 ? v.x : cj == 1 ? v.y : cj == 2 ? v.z : v.w);
                    const float* wp = wbase + ((c4 * 4 + cj) << 6);  // 64 e, uniform -> SGPR
#pragma unroll
                    for (int e = 0; e < 64; ++e) acc[e] = fmaf(wp[e], vv, acc[e]);
                }
            }
        }
    }

    __syncthreads();                 // done reading input; reuse LDS as psum
    float* ps = (float*)lds4;        // [4 wave][64 e][65]
#pragma unroll
    for (int e = 0; e < 64; ++e) ps[(wv * 64 + e) * 65 + ow] = acc[e];
    __syncthreads();

    const int eq = tid & 15, owb = tid >> 4;
    for (int it = 0; it < 4; ++it) {
        const int ow2 = owb + (it << 4);
        float4 o4;
#pragma unroll
        for (int j = 0; j < 4; ++j) {
            const int e = eq * 4 + j;
            float s = ps[(0 * 64 + e) * 65 + ow2] + ps[(1 * 64 + e) * 65 + ow2]
                    + ps[(2 * 64 + e) * 65 + ow2] + ps[(3 * 64 + e) * 65 + ow2];
            s += cb[br * 64 + e];
            ((float*)&o4)[j] = gelu_exact(s);
        }
        ((float4*)(tokens + ((size_t)(b * TOK + oh * 64 + ow2)) * 192 + br * 64))[eq] = o4;
    }
}

// ---------------------------------------------------------------------------
// LN1 + kqv GEMM. lane = token; h[192] in VGPRs (needs ~220 VGPRs: DO NOT cap
// occupancy -- (256,2) spilled h to scratch and cost 2.1 ms in round 1).
// Output kqvT [b][192 o][4096 t] (o-major, coalesced stores).
// ---------------------------------------------------------------------------
__global__ __launch_bounds__(256, 1) void k_lnkqv(
        const float* __restrict__ tokens, const float* __restrict__ g,
        const float* __restrict__ be, const float* __restrict__ wT,
        const float* __restrict__ bias, float* __restrict__ kqvT) {
    const int b = blockIdx.y;
    const int t = blockIdx.x * 256 + threadIdx.x;
    const float4* row = (const float4*)(tokens + ((size_t)(b * TOK) + t) * 192);
    float4 h[48];
    float mu = 0.f;
#pragma unroll
    for (int i = 0; i < 48; ++i) {
        h[i] = row[i];
        mu += h[i].x + h[i].y + h[i].z + h[i].w;
    }
    mu *= (1.f / 192.f);
    float var = 0.f;
#pragma unroll
    for (int i = 0; i < 48; ++i) {
        float a = h[i].x - mu, b2 = h[i].y - mu, c = h[i].z - mu, dd = h[i].w - mu;
        var += a * a + b2 * b2 + c * c + dd * dd;
    }
    const float rs = rsqrtf(var * (1.f / 192.f) + 1e-5f);
#pragma unroll
    for (int i = 0; i < 48; ++i) {
        h[i].x = (h[i].x - mu) * rs * g[4 * i + 0] + be[4 * i + 0];
        h[i].y = (h[i].y - mu) * rs * g[4 * i + 1] + be[4 * i + 1];
        h[i].z = (h[i].z - mu) * rs * g[4 * i + 2] + be[4 * i + 2];
        h[i].w = (h[i].w - mu) * rs * g[4 * i + 3] + be[4 * i + 3];
    }
    float* dst = kqvT + (size_t)b * 192 * TOK + t;
    for (int o = 0; o < 192; ++o) {
        const float* wr = wT + o * 192;   // uniform -> scalar loads
        float s = bias[o];
#pragma unroll
        for (int i = 0; i < 48; ++i) {
            s = fmaf(wr[4 * i + 0], h[i].x, s);
            s = fmaf(wr[4 * i + 1], h[i].y, s);
            s = fmaf(wr[4 * i + 2], h[i].z, s);
            s = fmaf(wr[4 * i + 3], h[i].w, s);
        }
        dst[(size_t)o * TOK] = s;
    }
}

// ---------------------------------------------------------------------------
// Performer features: kp (from k, rows 0:64) and qp (from q, rows 64:128).
// ---------------------------------------------------------------------------
__global__ __launch_bounds__(256) void k_perf(
        const float* __restrict__ kqvT, const float* __restrict__ wperf,
        float* __restrict__ kpT, float* __restrict__ qpT) {
    const int b = blockIdx.y;
    const int t = blockIdx.x * 256 + threadIdx.x;
    const float* basek = kqvT + (size_t)b * 192 * TOK + t;
    for (int pass = 0; pass < 2; ++pass) {
        float kr[64];
        const float* src = basek + (size_t)pass * 64 * TOK;
#pragma unroll
        for (int i = 0; i < 64; ++i) kr[i] = src[(size_t)i * TOK];
        float xd = 0.f;
#pragma unroll
        for (int i = 0; i < 64; ++i) xd = fmaf(kr[i], kr[i], xd);
        xd *= 0.5f;
        float* dst = (pass == 0 ? kpT : qpT) + (size_t)b * 32 * TOK + t;
        for (int m = 0; m < 32; ++m) {
            const float* wr = wperf + m * 64;   // uniform
            float a = 0.f;
#pragma unroll
            for (int i = 0; i < 64; ++i) a = fmaf(wr[i], kr[i], a);
            dst[(size_t)m * TOK] = expf(a - xd) * 0.17677669529663687f;  // 1/sqrt(32)
        }
    }
}

// ---------------------------------------------------------------------------
// Per-chunk partials: kptv_part[b][ch][64 d][32 m], sumkp_part[b][ch][32 m].
// ---------------------------------------------------------------------------
__global__ __launch_bounds__(256) void k_kptv(
        const float* __restrict__ kqvT, const float* __restrict__ kpT,
        float* __restrict__ kvp, float* __restrict__ skpp) {
    const int b = blockIdx.y, ch = blockIdx.x, tid = threadIdx.x;
    const int t = ch * 256 + tid;
    __shared__ float sv[256 * 65 + 256 * 36];   // v-tile [t][65], kp-tile [t][36]
    float* skp = sv + 256 * 65;
    for (int dd = 0; dd < 64; ++dd)
        sv[tid * 65 + dd] = kqvT[((size_t)(b * 192 + 128 + dd)) * TOK + t];
    for (int m = 0; m < 32; ++m)
        skp[tid * 36 + m] = kpT[((size_t)(b * 32 + m)) * TOK + t];
    __syncthreads();

    const int dd = tid & 63;
    const int mg = __builtin_amdgcn_readfirstlane(tid >> 6);
    float acc[8];
#pragma unroll
    for (int j = 0; j < 8; ++j) acc[j] = 0.f;
    for (int tt = 0; tt < 256; ++tt) {
        float vv = sv[tt * 65 + dd];
        const float4* kq = (const float4*)(skp + tt * 36 + mg * 8);  // broadcast
        float4 a0 = kq[0], a1 = kq[1];
        acc[0] = fmaf(vv, a0.x, acc[0]);
        acc[1] = fmaf(vv, a0.y, acc[1]);
        acc[2] = fmaf(vv, a0.z, acc[2]);
        acc[3] = fmaf(vv, a0.w, acc[3]);
        acc[4] = fmaf(vv, a1.x, acc[4]);
        acc[5] = fmaf(vv, a1.y, acc[5]);
        acc[6] = fmaf(vv, a1.z, acc[6]);
        acc[7] = fmaf(vv, a1.w, acc[7]);
    }
    float* dst = kvp + (((size_t)(b * 16 + ch) * 64 + dd) * 32) + mg * 8;
#pragma unroll
    for (int j = 0; j < 8; ++j) dst[j] = acc[j];

    if (tid < 32) {
        float s = 0.f;
        for (int tt = 0; tt < 256; ++tt) s += skp[tt * 36 + tid];
        skpp[(b * 16 + ch) * 32 + tid] = s;
    }
}

// Reduce 16 chunk partials -> kptvT [b][32 m][64 d], sum_kp [b][32 m].
__global__ __launch_bounds__(256) void k_reduce(
        const float* __restrict__ kvp, const float* __restrict__ skpp,
        float* __restrict__ kptvT, float* __restrict__ sum_kp) {
    int idx = blockIdx.x * 256 + threadIdx.x;
    if (idx < 65536) {
        int b = idx >> 11, rem = idx & 2047, m = rem >> 6, dd = rem & 63;
        float s = 0.f;
        for (int ch = 0; ch < 16; ++ch) s += kvp[((b * 16 + ch) * 64 + dd) * 32 + m];
        kptvT[idx] = s;     // idx == (b*32+m)*64+dd
    } else if (idx < 65536 + 1024) {
        int i = idx - 65536;
        int b = i >> 5, m = i & 31;
        float s = 0.f;
        for (int ch = 0; ch < 16; ++ch) s += skpp[(b * 16 + ch) * 32 + m];
        sum_kp[i] = s;
    }
}

// ---------------------------------------------------------------------------
// yatt = (qp @ kptv^T)/(D+eps); out = v + yatt@proj + proj_b. lane = token.
// ---------------------------------------------------------------------------
__global__ __launch_bounds__(256) void k_yatt(
        const float* __restrict__ kqvT, const float* __restrict__ qpT,
        const float* __restrict__ sum_kp, const float* __restrict__ kptvT,
        const float* __restrict__ projT, const float* __restrict__ proj_b,
        float* __restrict__ yattT) {
    const int b = blockIdx.y;
    const int t = blockIdx.x * 256 + threadIdx.x;
    const float* sk = sum_kp + b * 32;
    const float* kv = kptvT + b * 2048;
    const float* qpp = qpT + (size_t)b * 32 * TOK + t;
    float a[64];
#pragma unroll
    for (int i = 0; i < 64; ++i) a[i] = 0.f;
    float D = 0.f;
    for (int m = 0; m < 32; ++m) {
        float q = qpp[(size_t)m * TOK];
        D = fmaf(q, sk[m], D);
        const float* kvr = kv + m * 64;   // uniform
#pragma unroll
        for (int i = 0; i < 64; ++i) a[i] = fmaf(q, kvr[i], a[i]);
    }
    const float rD = 1.f / (D + 1e-8f);
#pragma unroll
    for (int i = 0; i < 64; ++i) a[i] *= rD;

    const float* vb = kqvT + ((size_t)(b * 192 + 128)) * TOK + t;
    float* yb = yattT + (size_t)b * 64 * TOK + t;
    for (int o = 0; o < 64; ++o) {
        const float* pw = projT + o * 64;  // uniform
        float s = proj_b[o];
#pragma unroll
        for (int i = 0; i < 64; ++i) s = fmaf(pw[i], a[i], s);
        s += vb[(size_t)o * TOK];
        yb[(size_t)o * TOK] = s;
    }
}

// ---------------------------------------------------------------------------
// LN2 + MLP + skip. lane = token; ~200 live floats -> (256,1), no spill.
// ---------------------------------------------------------------------------
__global__ __launch_bounds__(256, 1) void k_mlp(
        const float* __restrict__ yattT, const float* __restrict__ g2,
        const float* __restrict__ b2ln, const float* __restrict__ w1T,
        const float* __restrict__ b1, const float* __restrict__ w2,
        const float* __restrict__ b2, float* __restrict__ out) {
    const int b = blockIdx.y;
    const int tid = threadIdx.x;
    const int lane = tid & 63;
    const int wv = tid >> 6;
    const int t = blockIdx.x * 256 + tid;
    __shared__ float tile[4 * 64 * 65];
    float* tl = tile + wv * 64 * 65;

    const float* yb = yattT + (size_t)b * 64 * TOK + t;
    float y[64];
#pragma unroll
    for (int i = 0; i < 64; ++i) y[i] = yb[(size_t)i * TOK];
    float mu = 0.f;
#pragma unroll
    for (int i = 0; i < 64; ++i) mu += y[i];
    mu *= (1.f / 64.f);
    float var = 0.f;
#pragma unroll
    for (int i = 0; i < 64; ++i) { float d = y[i] - mu; var = fmaf(d, d, var); }
    const float rs = rsqrtf(var * (1.f / 64.f) + 1e-5f);
    float h[64];
#pragma unroll
    for (int i = 0; i < 64; ++i) h[i] = (y[i] - mu) * rs * g2[i] + b2ln[i];
    float o[64];
#pragma unroll
    for (int i = 0; i < 64; ++i) o[i] = y[i] + b2[i];

    for (int i = 0; i < 64; ++i) {        // hidden dim, dynamic
        const float* w1r = w1T + i * 64;  // uniform
        float s = b1[i];
#pragma unroll
        for (int j = 0; j < 64; ++j) s = fmaf(w1r[j], h[j], s);
        const float hg = gelu_exact(s);
        const float* w2r = w2 + i * 64;   // uniform (row-major mlp_w2)
#pragma unroll
        for (int j = 0; j < 64; ++j) o[j] = fmaf(w2r[j], hg, o[j]);
    }

#pragma unroll
    for (int i = 0; i < 64; ++i) tl[lane * 65 + i] = o[i];
    __syncthreads();
    const int t0 = blockIdx.x * 256 + wv * 64;
    float* ob = out + ((size_t)b * TOK + t0) * 64;
    for (int it = 0; it < 16; ++it) {
        int flat = it * 64 + lane;
        int trow = flat >> 4, oq = flat & 15;
        float4 v;
        v.x = tl[trow * 65 + oq * 4 + 0];
        v.y = tl[trow * 65 + oq * 4 + 1];
        v.z = tl[trow * 65 + oq * 4 + 2];
        v.w = tl[trow * 65 + oq * 4 + 3];
        ((float4*)(ob + trow * 64))[oq] = v;
    }
}

// ---------------------------------------------------------------------------
extern "C" void kernel_launch(void* const* d_in, const int* in_sizes, int n_in,
                              void* d_out, int out_size, void* d_ws, size_t ws_size,
                              hipStream_t stream) {
    const float* x      = (const float*)d_in[0];
    const float* conv_w = (const float*)d_in[1];
    const float* conv_b = (const float*)d_in[2];
    const float* ln1_g  = (const float*)d_in[3];
    const float* ln1_b  = (const float*)d_in[4];
    const float* kqv_w  = (const float*)d_in[5];
    const float* kqv_b  = (const float*)d_in[6];
    const float* proj_w = (const float*)d_in[7];
    const float* proj_b = (const float*)d_in[8];
    const float* w_perf = (const float*)d_in[9];
    const float* ln2_g  = (const float*)d_in[10];
    const float* ln2_b  = (const float*)d_in[11];
    const float* mlp_w1 = (const float*)d_in[12];
    const float* mlp_b1 = (const float*)d_in[13];
    const float* mlp_w2 = (const float*)d_in[14];
    const float* mlp_b2 = (const float*)d_in[15];

    float* ws = (float*)d_ws;
    // prep weights
    float* wt    = ws;                 // 110592
    float* kqvwT = ws + 110592;        // 36864
    float* projT = ws + 147456;        // 4096
    float* w1T   = ws + 151552;        // 4096
    // big region A (tokens, later reused)
    float* tokens = ws + 155648;       // 25165824 floats
    float* qpT    = tokens;                      // 4194304
    float* kpT    = tokens + 4194304;            // 4194304
    float* skpp   = tokens + 8388608;            // 16384
    float* kvp    = tokens + 8404992;            // 1048576
    float* sum_kp = tokens + 9453568;            // 1024
    float* kptvT  = tokens + 9454592;            // 65536
    float* yattT  = tokens + 9520128;            // 8388608
    // big region B
    float* kqvT   = ws + 155648 + 25165824;      // 25165824
    float* outp   = (float*)d_out;

    k_prep <<<608, 256, 0, stream>>>(conv_w, kqv_w, proj_w, mlp_w1, wt, kqvwT, projT, w1T);
    k_conv <<<dim3(64, 32, 3), 256, 0, stream>>>(x, wt, conv_b, tokens);
    k_lnkqv<<<dim3(16, 32), 256, 0, stream>>>(tokens, ln1_g, ln1_b, kqvwT, kqv_b, kqvT);
    k_perf <<<dim3(16, 32), 256, 0, stream>>>(kqvT, w_perf, kpT, qpT);
    k_kptv <<<dim3(16, 32), 256, 0, stream>>>(kqvT, kpT, kvp, skpp);
    k_reduce<<<261, 256, 0, stream>>>(kvp, skpp, kptvT, sum_kp);
    k_yatt <<<dim3(16, 32), 256, 0, stream>>>(kqvT, qpT, sum_kp, kptvT, projT, proj_b, yattT);
    k_mlp  <<<dim3(16, 32), 256, 0, stream>>>(yattT, ln2_g, ln2_b, w1T, mlp_b1, mlp_w2, mlp_b2, outp);
}

// Round 3
// 1231.200 us; speedup vs baseline: 2.8682x; 1.7437x over previous
//
#include <hip/hip_runtime.h>

// ---------------------------------------------------------------------------
// BlockRC2: PRM (3 dilated stride-2 convs + GELU) -> LN1 -> kqv ->
// performer attention -> proj+skip -> LN2 -> MLP -> skip.
// Round 3: conv -> bf16 MFMA implicit GEMM (round-2 conv was 1 block/CU,
// 1 wave/SIMD, VALUBusy 21%, 1135 us). LDS 52224 B -> 3 blocks/CU, zero
// barriers in K-loop, XOR-swizzled LDS reads, weights streamed from L2.
// ---------------------------------------------------------------------------

#define TOK 4096          // tokens per batch (64x64)
#define NB  32            // batch

typedef __attribute__((ext_vector_type(8)))  short short8;
typedef __attribute__((ext_vector_type(4)))  short short4v;
typedef __attribute__((ext_vector_type(16))) float f32x16;

__device__ __forceinline__ float gelu_exact(float v) {
    return 0.5f * v * (1.f + erff(v * 0.70710678118654752f));
}

// fp32 -> bf16 round-to-nearest-even, as raw short
__device__ __forceinline__ short f2bf(float f) {
    union { float f; unsigned u; } x; x.f = f;
    unsigned r = (x.u + 0x7FFFu + ((x.u >> 16) & 1u)) >> 16;
    return (short)r;
}

// ---------------------------------------------------------------------------
// Prep: conv_w [br][e][c][kh][kw] fp32 -> w2 [br][r][kw][e][c] bf16;
// kqv/proj/mlp_w1 transposes (fp32) unchanged.
// ---------------------------------------------------------------------------
__global__ __launch_bounds__(256) void k_prep(
        const float* __restrict__ cw, const float* __restrict__ kw,
        const float* __restrict__ pw, const float* __restrict__ w1,
        short* __restrict__ w2, float* __restrict__ kwT,
        float* __restrict__ pwT, float* __restrict__ w1T) {
    int idx = blockIdx.x * 256 + threadIdx.x;
    if (idx < 110592) {
        int c = idx & 63;
        int t = idx >> 6;
        int e = t & 63;
        int tap = t >> 6;            // (br*3+r)*3+kwi
        int kwi = tap % 3, t2 = tap / 3;
        int r = t2 % 3, brr = t2 / 3;
        w2[idx] = f2bf(cw[(((brr * 64 + e) * 64 + c) * 3 + r) * 3 + kwi]);
    } else if (idx < 110592 + 36864) {
        int i2 = idx - 110592;
        int o = i2 / 192, i = i2 % 192;
        kwT[i2] = kw[i * 192 + o];
    } else if (idx < 110592 + 36864 + 4096) {
        int i2 = idx - (110592 + 36864);
        int o = i2 >> 6, i = i2 & 63;
        pwT[i2] = pw[i * 64 + o];
    } else if (idx < 110592 + 36864 + 8192) {
        int i2 = idx - (110592 + 36864 + 4096);
        int o = i2 >> 6, i = i2 & 63;
        w1T[i2] = w1[i * 64 + o];
    }
}

// ---------------------------------------------------------------------------
// Conv via MFMA implicit GEMM. Block = (oh, b, br), 256 thr = 4 waves.
// Per block: output row oh = 64 ow x 64 e, K = 9 taps x 64 c.
// LDS: sA[r=3][iw4=136][c=64] bf16 (52224 B, 3 blocks/CU), iw padded +-4 with
// zeros (conv zero-padding), c-offset XOR-swizzled by (iw4&7)<<4 bytes.
// Wave wv: A-tile rows = (wv&1)*32, B-cols e = (wv>>1)*32.
// a_frag: lane row = lane&31, k = 8*(lane>>5)+j (contiguous c) from LDS.
// b_frag: lane col = lane&31, k contiguous from w2[e][c] in L2 (16B/lane).
// D (m74/m101): col = lane&31, row = (reg&3)+8*(reg>>2)+4*(lane>>5).
// ---------------------------------------------------------------------------
__global__ __launch_bounds__(256) void k_conv_mfma(
        const float* __restrict__ x, const short* __restrict__ w2,
        const float* __restrict__ cb, float* __restrict__ tokens) {
    const int oh = blockIdx.x;
    const int b  = blockIdx.y;
    const int br = blockIdx.z;
    const int d  = br + 1;
    const int tid = threadIdx.x;
    const int lane = tid & 63;
    const int wv = tid >> 6;
    const int wm = wv & 1;           // ow-tile (0/1)
    const int wn = wv >> 1;          // e-tile (0/1)

    __shared__ short sA[3 * 136 * 64];   // 52224 B

    // zero-fill (covers conv zero-padding borders and OOB rows)
    {
        short8 z = {0, 0, 0, 0, 0, 0, 0, 0};
        short8* p = (short8*)sA;
        for (int i = tid; i < 3 * 136 * 8; i += 256) p[i] = z;
    }
    __syncthreads();

    // stage 3 input rows fp32 -> bf16 (swizzled)
    for (int r = 0; r < 3; ++r) {
        int ih = 2 * oh + (r - 1) * d;
        if ((unsigned)ih < 128u) {               // block-uniform branch
            const float4* src = (const float4*)(x + ((size_t)(b * 16384 + ih * 128)) * 64);
            for (int it = 0; it < 8; ++it) {
                int flat = it * 256 + tid;       // 0..2047 = iw(128) x c4(16)
                int iw = flat >> 4, c4 = flat & 15;
                float4 v = src[iw * 16 + c4];
                short4v pk;
                pk.x = f2bf(v.x); pk.y = f2bf(v.y);
                pk.z = f2bf(v.z); pk.w = f2bf(v.w);
                int iw4 = iw + 4;
                char* dst = (char*)sA + (r * 136 + iw4) * 128
                          + ((c4 * 8) ^ ((iw4 & 7) << 4));
                *(short4v*)dst = pk;
            }
        }
    }
    __syncthreads();

    f32x16 acc = {0.f, 0.f, 0.f, 0.f, 0.f, 0.f, 0.f, 0.f,
                  0.f, 0.f, 0.f, 0.f, 0.f, 0.f, 0.f, 0.f};
    const int colL = lane & 31;
    const int g    = lane >> 5;
    const int ow   = wm * 32 + colL;             // A-row for this lane
    const short* wbr = w2 + br * 9 * 4096;

    for (int r = 0; r < 3; ++r) {
#pragma unroll
        for (int kwi = 0; kwi < 3; ++kwi) {
            const int iw4 = 2 * ow + (kwi - 1) * d + 4;       // in [1,133]
            const char* arow = (const char*)sA + (r * 136 + iw4) * 128;
            const int swz = (iw4 & 7) << 4;
            const short* wtap = wbr + (r * 3 + kwi) * 4096
                              + (wn * 32 + colL) * 64 + g * 8;
#pragma unroll
            for (int ks = 0; ks < 4; ++ks) {     // K=16 per MFMA, 64 c per tap
                short8 a = *(const short8*)(arow + ((ks * 32 + g * 16) ^ swz));
                short8 bf = *(const short8*)(wtap + ks * 16);
                acc = __builtin_amdgcn_mfma_f32_32x32x16_bf16(a, bf, acc, 0, 0, 0);
            }
        }
    }

    // epilogue: bias + GELU, coalesced 128B segments across lanes
    const int eG = br * 64 + wn * 32 + colL;
    const float bias = cb[eG];
    float* outb = tokens + ((size_t)(b * TOK + oh * 64 + wm * 32)) * 192 + eG;
#pragma unroll
    for (int reg = 0; reg < 16; ++reg) {
        int owl = (reg & 3) + 8 * (reg >> 2) + 4 * g;
        outb[(size_t)owl * 192] = gelu_exact(acc[reg] + bias);
    }
}

// ---------------------------------------------------------------------------
// LN1 + kqv GEMM. lane = token; h[192] in VGPRs (needs ~220 VGPRs: DO NOT cap
// occupancy). Output kqvT [b][192 o][4096 t] (o-major, coalesced stores).
// ---------------------------------------------------------------------------
__global__ __launch_bounds__(256, 1) void k_lnkqv(
        const float* __restrict__ tokens, const float* __restrict__ g,
        const float* __restrict__ be, const float* __restrict__ wT,
        const float* __restrict__ bias, float* __restrict__ kqvT) {
    const int b = blockIdx.y;
    const int t = blockIdx.x * 256 + threadIdx.x;
    const float4* row = (const float4*)(tokens + ((size_t)(b * TOK) + t) * 192);
    float4 h[48];
    float mu = 0.f;
#pragma unroll
    for (int i = 0; i < 48; ++i) {
        h[i] = row[i];
        mu += h[i].x + h[i].y + h[i].z + h[i].w;
    }
    mu *= (1.f / 192.f);
    float var = 0.f;
#pragma unroll
    for (int i = 0; i < 48; ++i) {
        float a = h[i].x - mu, b2 = h[i].y - mu, c = h[i].z - mu, dd = h[i].w - mu;
        var += a * a + b2 * b2 + c * c + dd * dd;
    }
    const float rs = rsqrtf(var * (1.f / 192.f) + 1e-5f);
#pragma unroll
    for (int i = 0; i < 48; ++i) {
        h[i].x = (h[i].x - mu) * rs * g[4 * i + 0] + be[4 * i + 0];
        h[i].y = (h[i].y - mu) * rs * g[4 * i + 1] + be[4 * i + 1];
        h[i].z = (h[i].z - mu) * rs * g[4 * i + 2] + be[4 * i + 2];
        h[i].w = (h[i].w - mu) * rs * g[4 * i + 3] + be[4 * i + 3];
    }
    float* dst = kqvT + (size_t)b * 192 * TOK + t;
    for (int o = 0; o < 192; ++o) {
        const float* wr = wT + o * 192;   // uniform -> scalar loads
        float s = bias[o];
#pragma unroll
        for (int i = 0; i < 48; ++i) {
            s = fmaf(wr[4 * i + 0], h[i].x, s);
            s = fmaf(wr[4 * i + 1], h[i].y, s);
            s = fmaf(wr[4 * i + 2], h[i].z, s);
            s = fmaf(wr[4 * i + 3], h[i].w, s);
        }
        dst[(size_t)o * TOK] = s;
    }
}

// ---------------------------------------------------------------------------
// Performer features: kp (rows 0:64) and qp (rows 64:128), m-major outputs.
// ---------------------------------------------------------------------------
__global__ __launch_bounds__(256) void k_perf(
        const float* __restrict__ kqvT, const float* __restrict__ wperf,
        float* __restrict__ kpT, float* __restrict__ qpT) {
    const int b = blockIdx.y;
    const int t = blockIdx.x * 256 + threadIdx.x;
    const float* basek = kqvT + (size_t)b * 192 * TOK + t;
    for (int pass = 0; pass < 2; ++pass) {
        float kr[64];
        const float* src = basek + (size_t)pass * 64 * TOK;
#pragma unroll
        for (int i = 0; i < 64; ++i) kr[i] = src[(size_t)i * TOK];
        float xd = 0.f;
#pragma unroll
        for (int i = 0; i < 64; ++i) xd = fmaf(kr[i], kr[i], xd);
        xd *= 0.5f;
        float* dst = (pass == 0 ? kpT : qpT) + (size_t)b * 32 * TOK + t;
        for (int m = 0; m < 32; ++m) {
            const float* wr = wperf + m * 64;   // uniform
            float a = 0.f;
#pragma unroll
            for (int i = 0; i < 64; ++i) a = fmaf(wr[i], kr[i], a);
            dst[(size_t)m * TOK] = expf(a - xd) * 0.17677669529663687f;  // 1/sqrt(32)
        }
    }
}

// ---------------------------------------------------------------------------
// Per-chunk partials: kptv_part[b][ch][64 d][32 m], sumkp_part[b][ch][32 m].
// ---------------------------------------------------------------------------
__global__ __launch_bounds__(256) void k_kptv(
        const float* __restrict__ kqvT, const float* __restrict__ kpT,
        float* __restrict__ kvp, float* __restrict__ skpp) {
    const int b = blockIdx.y, ch = blockIdx.x, tid = threadIdx.x;
    const int t = ch * 256 + tid;
    __shared__ float sv[256 * 65 + 256 * 36];   // v-tile [t][65], kp-tile [t][36]
    float* skp = sv + 256 * 65;
    for (int dd = 0; dd < 64; ++dd)
        sv[tid * 65 + dd] = kqvT[((size_t)(b * 192 + 128 + dd)) * TOK + t];
    for (int m = 0; m < 32; ++m)
        skp[tid * 36 + m] = kpT[((size_t)(b * 32 + m)) * TOK + t];
    __syncthreads();

    const int dd = tid & 63;
    const int mg = __builtin_amdgcn_readfirstlane(tid >> 6);
    float acc[8];
#pragma unroll
    for (int j = 0; j < 8; ++j) acc[j] = 0.f;
    for (int tt = 0; tt < 256; ++tt) {
        float vv = sv[tt * 65 + dd];
        const float4* kq = (const float4*)(skp + tt * 36 + mg * 8);  // broadcast
        float4 a0 = kq[0], a1 = kq[1];
        acc[0] = fmaf(vv, a0.x, acc[0]);
        acc[1] = fmaf(vv, a0.y, acc[1]);
        acc[2] = fmaf(vv, a0.z, acc[2]);
        acc[3] = fmaf(vv, a0.w, acc[3]);
        acc[4] = fmaf(vv, a1.x, acc[4]);
        acc[5] = fmaf(vv, a1.y, acc[5]);
        acc[6] = fmaf(vv, a1.z, acc[6]);
        acc[7] = fmaf(vv, a1.w, acc[7]);
    }
    float* dst = kvp + (((size_t)(b * 16 + ch) * 64 + dd) * 32) + mg * 8;
#pragma unroll
    for (int j = 0; j < 8; ++j) dst[j] = acc[j];

    if (tid < 32) {
        float s = 0.f;
        for (int tt = 0; tt < 256; ++tt) s += skp[tt * 36 + tid];
        skpp[(b * 16 + ch) * 32 + tid] = s;
    }
}

// Reduce 16 chunk partials -> kptvT [b][32 m][64 d], sum_kp [b][32 m].
__global__ __launch_bounds__(256) void k_reduce(
        const float* __restrict__ kvp, const float* __restrict__ skpp,
        float* __restrict__ kptvT, float* __restrict__ sum_kp) {
    int idx = blockIdx.x * 256 + threadIdx.x;
    if (idx < 65536) {
        int b = idx >> 11, rem = idx & 2047, m = rem >> 6, dd = rem & 63;
        float s = 0.f;
        for (int ch = 0; ch < 16; ++ch) s += kvp[((b * 16 + ch) * 64 + dd) * 32 + m];
        kptvT[idx] = s;     // idx == (b*32+m)*64+dd
    } else if (idx < 65536 + 1024) {
        int i = idx - 65536;
        int b = i >> 5, m = i & 31;
        float s = 0.f;
        for (int ch = 0; ch < 16; ++ch) s += skpp[(b * 16 + ch) * 32 + m];
        sum_kp[i] = s;
    }
}

// ---------------------------------------------------------------------------
// yatt = (qp @ kptv^T)/(D+eps); out = v + yatt@proj + proj_b. lane = token.
// ---------------------------------------------------------------------------
__global__ __launch_bounds__(256) void k_yatt(
        const float* __restrict__ kqvT, const float* __restrict__ qpT,
        const float* __restrict__ sum_kp, const float* __restrict__ kptvT,
        const float* __restrict__ projT, const float* __restrict__ proj_b,
        float* __restrict__ yattT) {
    const int b = blockIdx.y;
    const int t = blockIdx.x * 256 + threadIdx.x;
    const float* sk = sum_kp + b * 32;
    const float* kv = kptvT + b * 2048;
    const float* qpp = qpT + (size_t)b * 32 * TOK + t;
    float a[64];
#pragma unroll
    for (int i = 0; i < 64; ++i) a[i] = 0.f;
    float D = 0.f;
    for (int m = 0; m < 32; ++m) {
        float q = qpp[(size_t)m * TOK];
        D = fmaf(q, sk[m], D);
        const float* kvr = kv + m * 64;   // uniform
#pragma unroll
        for (int i = 0; i < 64; ++i) a[i] = fmaf(q, kvr[i], a[i]);
    }
    const float rD = 1.f / (D + 1e-8f);
#pragma unroll
    for (int i = 0; i < 64; ++i) a[i] *= rD;

    const float* vb = kqvT + ((size_t)(b * 192 + 128)) * TOK + t;
    float* yb = yattT + (size_t)b * 64 * TOK + t;
    for (int o = 0; o < 64; ++o) {
        const float* pw = projT + o * 64;  // uniform
        float s = proj_b[o];
#pragma unroll
        for (int i = 0; i < 64; ++i) s = fmaf(pw[i], a[i], s);
        s += vb[(size_t)o * TOK];
        yb[(size_t)o * TOK] = s;
    }
}

// ---------------------------------------------------------------------------
// LN2 + MLP + skip. lane = token; ~200 live floats -> (256,1), no spill.
// ---------------------------------------------------------------------------
__global__ __launch_bounds__(256, 1) void k_mlp(
        const float* __restrict__ yattT, const float* __restrict__ g2,
        const float* __restrict__ b2ln, const float* __restrict__ w1T,
        const float* __restrict__ b1, const float* __restrict__ w2m,
        const float* __restrict__ b2, float* __restrict__ out) {
    const int b = blockIdx.y;
    const int tid = threadIdx.x;
    const int lane = tid & 63;
    const int wv = tid >> 6;
    const int t = blockIdx.x * 256 + tid;
    __shared__ float tile[4 * 64 * 65];
    float* tl = tile + wv * 64 * 65;

    const float* yb = yattT + (size_t)b * 64 * TOK + t;
    float y[64];
#pragma unroll
    for (int i = 0; i < 64; ++i) y[i] = yb[(size_t)i * TOK];
    float mu = 0.f;
#pragma unroll
    for (int i = 0; i < 64; ++i) mu += y[i];
    mu *= (1.f / 64.f);
    float var = 0.f;
#pragma unroll
    for (int i = 0; i < 64; ++i) { float d = y[i] - mu; var = fmaf(d, d, var); }
    const float rs = rsqrtf(var * (1.f / 64.f) + 1e-5f);
    float h[64];
#pragma unroll
    for (int i = 0; i < 64; ++i) h[i] = (y[i] - mu) * rs * g2[i] + b2ln[i];
    float o[64];
#pragma unroll
    for (int i = 0; i < 64; ++i) o[i] = y[i] + b2[i];

    for (int i = 0; i < 64; ++i) {        // hidden dim, dynamic
        const float* w1r = w1T + i * 64;  // uniform
        float s = b1[i];
#pragma unroll
        for (int j = 0; j < 64; ++j) s = fmaf(w1r[j], h[j], s);
        const float hg = gelu_exact(s);
        const float* w2r = w2m + i * 64;  // uniform (row-major mlp_w2)
#pragma unroll
        for (int j = 0; j < 64; ++j) o[j] = fmaf(w2r[j], hg, o[j]);
    }

#pragma unroll
    for (int i = 0; i < 64; ++i) tl[lane * 65 + i] = o[i];
    __syncthreads();
    const int t0 = blockIdx.x * 256 + wv * 64;
    float* ob = out + ((size_t)b * TOK + t0) * 64;
    for (int it = 0; it < 16; ++it) {
        int flat = it * 64 + lane;
        int trow = flat >> 4, oq = flat & 15;
        float4 v;
        v.x = tl[trow * 65 + oq * 4 + 0];
        v.y = tl[trow * 65 + oq * 4 + 1];
        v.z = tl[trow * 65 + oq * 4 + 2];
        v.w = tl[trow * 65 + oq * 4 + 3];
        ((float4*)(ob + trow * 64))[oq] = v;
    }
}

// ---------------------------------------------------------------------------
extern "C" void kernel_launch(void* const* d_in, const int* in_sizes, int n_in,
                              void* d_out, int out_size, void* d_ws, size_t ws_size,
                              hipStream_t stream) {
    const float* x      = (const float*)d_in[0];
    const float* conv_w = (const float*)d_in[1];
    const float* conv_b = (const float*)d_in[2];
    const float* ln1_g  = (const float*)d_in[3];
    const float* ln1_b  = (const float*)d_in[4];
    const float* kqv_w  = (const float*)d_in[5];
    const float* kqv_b  = (const float*)d_in[6];
    const float* proj_w = (const float*)d_in[7];
    const float* proj_b = (const float*)d_in[8];
    const float* w_perf = (const float*)d_in[9];
    const float* ln2_g  = (const float*)d_in[10];
    const float* ln2_b  = (const float*)d_in[11];
    const float* mlp_w1 = (const float*)d_in[12];
    const float* mlp_b1 = (const float*)d_in[13];
    const float* mlp_w2 = (const float*)d_in[14];
    const float* mlp_b2 = (const float*)d_in[15];

    float* ws = (float*)d_ws;
    // prep weights
    short* w2    = (short*)ws;         // 110592 bf16 = 55296 floats
    float* kqvwT = ws + 110592;        // 36864
    float* projT = ws + 147456;        // 4096
    float* w1T   = ws + 151552;        // 4096
    // big region A
    float* tokens = ws + 155648;       // 25165824 floats
    float* qpT    = tokens;                      // 4194304
    float* kpT    = tokens + 4194304;            // 4194304
    float* skpp   = tokens + 8388608;            // 16384
    float* kvp    = tokens + 8404992;            // 1048576
    float* sum_kp = tokens + 9453568;            // 1024
    float* kptvT  = tokens + 9454592;            // 65536
    float* yattT  = tokens + 9520128;            // 8388608
    // big region B
    float* kqvT   = ws + 155648 + 25165824;      // 25165824
    float* outp   = (float*)d_out;

    k_prep <<<608, 256, 0, stream>>>(conv_w, kqv_w, proj_w, mlp_w1, w2, kqvwT, projT, w1T);
    k_conv_mfma<<<dim3(64, 32, 3), 256, 0, stream>>>(x, w2, conv_b, tokens);
    k_lnkqv<<<dim3(16, 32), 256, 0, stream>>>(tokens, ln1_g, ln1_b, kqvwT, kqv_b, kqvT);
    k_perf <<<dim3(16, 32), 256, 0, stream>>>(kqvT, w_perf, kpT, qpT);
    k_kptv <<<dim3(16, 32), 256, 0, stream>>>(kqvT, kpT, kvp, skpp);
    k_reduce<<<261, 256, 0, stream>>>(kvp, skpp, kptvT, sum_kp);
    k_yatt <<<dim3(16, 32), 256, 0, stream>>>(kqvT, qpT, sum_kp, kptvT, projT, proj_b, yattT);
    k_mlp  <<<dim3(16, 32), 256, 0, stream>>>(yattT, ln2_g, ln2_b, w1T, mlp_b1, mlp_w2, mlp_b2, outp);
}

// Round 4
// 512.063 us; speedup vs baseline: 6.8962x; 2.4044x over previous
//
#include <hip/hip_runtime.h>

// ---------------------------------------------------------------------------
// BlockRC2: PRM (3 dilated stride-2 convs + GELU) -> LN1 -> kqv ->
// performer attention -> proj+skip -> LN2 -> MLP -> skip.
// Round 4: LN1+kqv -> fused bf16 MFMA GEMM (round-3 k_lnkqv was scalar-FMA
// bound: 845 us, VALUBusy 14%, 1 wave/SIMD). Weights from L2, tokens via
// swizzled LDS bf16 tile, o-major coalesced stores, bias fused.
// ---------------------------------------------------------------------------

#define TOK 4096          // tokens per batch (64x64)
#define NB  32            // batch

typedef __attribute__((ext_vector_type(8)))  short short8;
typedef __attribute__((ext_vector_type(4)))  short short4v;
typedef __attribute__((ext_vector_type(16))) float f32x16;

__device__ __forceinline__ float gelu_exact(float v) {
    return 0.5f * v * (1.f + erff(v * 0.70710678118654752f));
}

// fp32 -> bf16 round-to-nearest-even, as raw short
__device__ __forceinline__ short f2bf(float f) {
    union { float f; unsigned u; } x; x.f = f;
    unsigned r = (x.u + 0x7FFFu + ((x.u >> 16) & 1u)) >> 16;
    return (short)r;
}

// ---------------------------------------------------------------------------
// Prep: conv_w -> w2 [br][r][kw][e][c] bf16; kqv_w -> kwbf [o][i] bf16;
// proj_w/mlp_w1 fp32 transposes.
// ---------------------------------------------------------------------------
__global__ __launch_bounds__(256) void k_prep(
        const float* __restrict__ cw, const float* __restrict__ kw,
        const float* __restrict__ pw, const float* __restrict__ w1,
        short* __restrict__ w2, short* __restrict__ kwbf,
        float* __restrict__ pwT, float* __restrict__ w1T) {
    int idx = blockIdx.x * 256 + threadIdx.x;
    if (idx < 110592) {
        int c = idx & 63;
        int t = idx >> 6;
        int e = t & 63;
        int tap = t >> 6;            // (br*3+r)*3+kwi
        int kwi = tap % 3, t2 = tap / 3;
        int r = t2 % 3, brr = t2 / 3;
        w2[idx] = f2bf(cw[(((brr * 64 + e) * 64 + c) * 3 + r) * 3 + kwi]);
    } else if (idx < 110592 + 36864) {
        int i2 = idx - 110592;
        int o = i2 / 192, i = i2 % 192;
        kwbf[i2] = f2bf(kw[i * 192 + o]);
    } else if (idx < 110592 + 36864 + 4096) {
        int i2 = idx - (110592 + 36864);
        int o = i2 >> 6, i = i2 & 63;
        pwT[i2] = pw[i * 64 + o];
    } else if (idx < 110592 + 36864 + 8192) {
        int i2 = idx - (110592 + 36864 + 4096);
        int o = i2 >> 6, i = i2 & 63;
        w1T[i2] = w1[i * 64 + o];
    }
}

// ---------------------------------------------------------------------------
// Conv via MFMA implicit GEMM. Block = (oh, b, br), 256 thr = 4 waves.
// (unchanged from round 3: 1135 -> ~130 us)
// ---------------------------------------------------------------------------
__global__ __launch_bounds__(256) void k_conv_mfma(
        const float* __restrict__ x, const short* __restrict__ w2,
        const float* __restrict__ cb, float* __restrict__ tokens) {
    const int oh = blockIdx.x;
    const int b  = blockIdx.y;
    const int br = blockIdx.z;
    const int d  = br + 1;
    const int tid = threadIdx.x;
    const int lane = tid & 63;
    const int wv = tid >> 6;
    const int wm = wv & 1;           // ow-tile (0/1)
    const int wn = wv >> 1;          // e-tile (0/1)

    __shared__ short sA[3 * 136 * 64];   // 52224 B

    {
        short8 z = {0, 0, 0, 0, 0, 0, 0, 0};
        short8* p = (short8*)sA;
        for (int i = tid; i < 3 * 136 * 8; i += 256) p[i] = z;
    }
    __syncthreads();

    for (int r = 0; r < 3; ++r) {
        int ih = 2 * oh + (r - 1) * d;
        if ((unsigned)ih < 128u) {               // block-uniform branch
            const float4* src = (const float4*)(x + ((size_t)(b * 16384 + ih * 128)) * 64);
            for (int it = 0; it < 8; ++it) {
                int flat = it * 256 + tid;       // 0..2047 = iw(128) x c4(16)
                int iw = flat >> 4, c4 = flat & 15;
                float4 v = src[iw * 16 + c4];
                short4v pk;
                pk.x = f2bf(v.x); pk.y = f2bf(v.y);
                pk.z = f2bf(v.z); pk.w = f2bf(v.w);
                int iw4 = iw + 4;
                char* dst = (char*)sA + (r * 136 + iw4) * 128
                          + ((c4 * 8) ^ ((iw4 & 7) << 4));
                *(short4v*)dst = pk;
            }
        }
    }
    __syncthreads();

    f32x16 acc = {0.f, 0.f, 0.f, 0.f, 0.f, 0.f, 0.f, 0.f,
                  0.f, 0.f, 0.f, 0.f, 0.f, 0.f, 0.f, 0.f};
    const int colL = lane & 31;
    const int g    = lane >> 5;
    const int ow   = wm * 32 + colL;             // A-row for this lane
    const short* wbr = w2 + br * 9 * 4096;

    for (int r = 0; r < 3; ++r) {
#pragma unroll
        for (int kwi = 0; kwi < 3; ++kwi) {
            const int iw4 = 2 * ow + (kwi - 1) * d + 4;       // in [1,133]
            const char* arow = (const char*)sA + (r * 136 + iw4) * 128;
            const int swz = (iw4 & 7) << 4;
            const short* wtap = wbr + (r * 3 + kwi) * 4096
                              + (wn * 32 + colL) * 64 + g * 8;
#pragma unroll
            for (int ks = 0; ks < 4; ++ks) {     // K=16 per MFMA, 64 c per tap
                short8 a = *(const short8*)(arow + ((ks * 32 + g * 16) ^ swz));
                short8 bf = *(const short8*)(wtap + ks * 16);
                acc = __builtin_amdgcn_mfma_f32_32x32x16_bf16(a, bf, acc, 0, 0, 0);
            }
        }
    }

    const int eG = br * 64 + wn * 32 + colL;
    const float bias = cb[eG];
    float* outb = tokens + ((size_t)(b * TOK + oh * 64 + wm * 32)) * 192 + eG;
#pragma unroll
    for (int reg = 0; reg < 16; ++reg) {
        int owl = (reg & 3) + 8 * (reg >> 2) + 4 * g;
        outb[(size_t)owl * 192] = gelu_exact(acc[reg] + bias);
    }
}

// ---------------------------------------------------------------------------
// LN1 + kqv via MFMA. Block = 64 tokens x all 192 outputs, 256 thr = 4 waves.
// Phase 1: LN (4 thr/token), normalized bf16 -> swizzled LDS tile [64][192].
// Phase 2: A = kwbf[o][i] from L2 (16B/lane), B = LDS tile; wave wv:
// t-tile = wv&1, o-tiles = {wv>>1, +2, +4} (B-frag reused across o-tiles).
// D: col=lane&31 -> token, row=(reg&3)+8*(reg>>2)+4*(lane>>5) -> o.
// Stores to kqvT[b][o][t]: 32 consecutive t per reg -> coalesced.
// ---------------------------------------------------------------------------
__global__ __launch_bounds__(256) void k_lnkqv_mfma(
        const float* __restrict__ tokens, const float* __restrict__ g,
        const float* __restrict__ be, const short* __restrict__ wbf,
        const float* __restrict__ bias, float* __restrict__ kqvT) {
    const int b = blockIdx.y;
    const int t0 = blockIdx.x * 64;
    const int tid = threadIdx.x;

    __shared__ short sB[64 * 192];       // 24576 B, XOR-swizzled rows
    __shared__ float red[64 * 8];

    // ---- Phase 1: LayerNorm ----
    const int r = tid >> 2, q = tid & 3;       // token row, quarter
    const float* rowp = tokens + ((size_t)(b * TOK + t0 + r)) * 192 + q * 48;
    float v[48];
    float s1 = 0.f, s2 = 0.f;
#pragma unroll
    for (int i = 0; i < 12; ++i) {
        float4 x4 = ((const float4*)rowp)[i];
        v[4 * i + 0] = x4.x; v[4 * i + 1] = x4.y;
        v[4 * i + 2] = x4.z; v[4 * i + 3] = x4.w;
        s1 += x4.x + x4.y + x4.z + x4.w;
        s2 += x4.x * x4.x + x4.y * x4.y + x4.z * x4.z + x4.w * x4.w;
    }
    red[r * 8 + q] = s1;
    red[r * 8 + 4 + q] = s2;
    __syncthreads();
    const float m1 = red[r * 8 + 0] + red[r * 8 + 1] + red[r * 8 + 2] + red[r * 8 + 3];
    const float m2 = red[r * 8 + 4] + red[r * 8 + 5] + red[r * 8 + 6] + red[r * 8 + 7];
    const float mu = m1 * (1.f / 192.f);
    const float var = m2 * (1.f / 192.f) - mu * mu;
    const float rs = rsqrtf(fmaxf(var, 0.f) + 1e-5f);
    const float4* g4 = (const float4*)(g + q * 48);
    const float4* b4 = (const float4*)(be + q * 48);
    char* rowB = (char*)sB + r * 384;
    const int swz = (r & 7) << 4;
#pragma unroll
    for (int i = 0; i < 12; ++i) {
        float4 gg = g4[i], bb = b4[i];
        short4v pk;
        pk.x = f2bf((v[4 * i + 0] - mu) * rs * gg.x + bb.x);
        pk.y = f2bf((v[4 * i + 1] - mu) * rs * gg.y + bb.y);
        pk.z = f2bf((v[4 * i + 2] - mu) * rs * gg.z + bb.z);
        pk.w = f2bf((v[4 * i + 3] - mu) * rs * gg.w + bb.w);
        *(short4v*)(rowB + (((q * 48 + i * 4) * 2) ^ swz)) = pk;
    }
    __syncthreads();

    // ---- Phase 2: MFMA ----
    const int lane = tid & 63;
    const int wv = tid >> 6;
    const int tt = wv & 1;
    const int wo = wv >> 1;
    const int colL = lane & 31;
    const int gq = lane >> 5;

    f32x16 acc0 = {0.f, 0.f, 0.f, 0.f, 0.f, 0.f, 0.f, 0.f,
                   0.f, 0.f, 0.f, 0.f, 0.f, 0.f, 0.f, 0.f};
    f32x16 acc1 = acc0, acc2 = acc0;
    const char* bbase = (const char*)sB + (tt * 32 + colL) * 384;
    const int bswz = ((tt * 32 + colL) & 7) << 4;
    const short* arow = wbf + (wo * 32 + colL) * 192 + gq * 8;

    for (int kk = 0; kk < 12; ++kk) {
        short8 bf = *(const short8*)(bbase + (((kk * 16 + gq * 8) * 2) ^ bswz));
        short8 a0 = *(const short8*)(arow + kk * 16);
        short8 a1 = *(const short8*)(arow + 64 * 192 + kk * 16);
        short8 a2 = *(const short8*)(arow + 128 * 192 + kk * 16);
        acc0 = __builtin_amdgcn_mfma_f32_32x32x16_bf16(a0, bf, acc0, 0, 0, 0);
        acc1 = __builtin_amdgcn_mfma_f32_32x32x16_bf16(a1, bf, acc1, 0, 0, 0);
        acc2 = __builtin_amdgcn_mfma_f32_32x32x16_bf16(a2, bf, acc2, 0, 0, 0);
    }

    const int tglob = t0 + tt * 32 + colL;
    float* outb = kqvT + (size_t)b * 192 * TOK + tglob;
#pragma unroll
    for (int j = 0; j < 3; ++j) {
        const int obase = (wo + 2 * j) * 32;
        const f32x16 ac = (j == 0 ? acc0 : j == 1 ? acc1 : acc2);
#pragma unroll
        for (int reg = 0; reg < 16; ++reg) {
            int orow = (reg & 3) + 8 * (reg >> 2) + 4 * gq;
            outb[(size_t)(obase + orow) * TOK] = ac[reg] + bias[obase + orow];
        }
    }
}

// ---------------------------------------------------------------------------
// Performer features: kp (rows 0:64) and qp (rows 64:128), m-major outputs.
// ---------------------------------------------------------------------------
__global__ __launch_bounds__(256) void k_perf(
        const float* __restrict__ kqvT, const float* __restrict__ wperf,
        float* __restrict__ kpT, float* __restrict__ qpT) {
    const int b = blockIdx.y;
    const int t = blockIdx.x * 256 + threadIdx.x;
    const float* basek = kqvT + (size_t)b * 192 * TOK + t;
    for (int pass = 0; pass < 2; ++pass) {
        float kr[64];
        const float* src = basek + (size_t)pass * 64 * TOK;
#pragma unroll
        for (int i = 0; i < 64; ++i) kr[i] = src[(size_t)i * TOK];
        float xd = 0.f;
#pragma unroll
        for (int i = 0; i < 64; ++i) xd = fmaf(kr[i], kr[i], xd);
        xd *= 0.5f;
        float* dst = (pass == 0 ? kpT : qpT) + (size_t)b * 32 * TOK + t;
        for (int m = 0; m < 32; ++m) {
            const float* wr = wperf + m * 64;   // uniform
            float a = 0.f;
#pragma unroll
            for (int i = 0; i < 64; ++i) a = fmaf(wr[i], kr[i], a);
            dst[(size_t)m * TOK] = expf(a - xd) * 0.17677669529663687f;  // 1/sqrt(32)
        }
    }
}

// ---------------------------------------------------------------------------
// Per-chunk partials: kptv_part[b][ch][64 d][32 m], sumkp_part[b][ch][32 m].
// ---------------------------------------------------------------------------
__global__ __launch_bounds__(256) void k_kptv(
        const float* __restrict__ kqvT, const float* __restrict__ kpT,
        float* __restrict__ kvp, float* __restrict__ skpp) {
    const int b = blockIdx.y, ch = blockIdx.x, tid = threadIdx.x;
    const int t = ch * 256 + tid;
    __shared__ float sv[256 * 65 + 256 * 36];   // v-tile [t][65], kp-tile [t][36]
    float* skp = sv + 256 * 65;
    for (int dd = 0; dd < 64; ++dd)
        sv[tid * 65 + dd] = kqvT[((size_t)(b * 192 + 128 + dd)) * TOK + t];
    for (int m = 0; m < 32; ++m)
        skp[tid * 36 + m] = kpT[((size_t)(b * 32 + m)) * TOK + t];
    __syncthreads();

    const int dd = tid & 63;
    const int mg = __builtin_amdgcn_readfirstlane(tid >> 6);
    float acc[8];
#pragma unroll
    for (int j = 0; j < 8; ++j) acc[j] = 0.f;
    for (int tt = 0; tt < 256; ++tt) {
        float vv = sv[tt * 65 + dd];
        const float4* kq = (const float4*)(skp + tt * 36 + mg * 8);  // broadcast
        float4 a0 = kq[0], a1 = kq[1];
        acc[0] = fmaf(vv, a0.x, acc[0]);
        acc[1] = fmaf(vv, a0.y, acc[1]);
        acc[2] = fmaf(vv, a0.z, acc[2]);
        acc[3] = fmaf(vv, a0.w, acc[3]);
        acc[4] = fmaf(vv, a1.x, acc[4]);
        acc[5] = fmaf(vv, a1.y, acc[5]);
        acc[6] = fmaf(vv, a1.z, acc[6]);
        acc[7] = fmaf(vv, a1.w, acc[7]);
    }
    float* dst = kvp + (((size_t)(b * 16 + ch) * 64 + dd) * 32) + mg * 8;
#pragma unroll
    for (int j = 0; j < 8; ++j) dst[j] = acc[j];

    if (tid < 32) {
        float s = 0.f;
        for (int tt = 0; tt < 256; ++tt) s += skp[tt * 36 + tid];
        skpp[(b * 16 + ch) * 32 + tid] = s;
    }
}

// Reduce 16 chunk partials -> kptvT [b][32 m][64 d], sum_kp [b][32 m].
__global__ __launch_bounds__(256) void k_reduce(
        const float* __restrict__ kvp, const float* __restrict__ skpp,
        float* __restrict__ kptvT, float* __restrict__ sum_kp) {
    int idx = blockIdx.x * 256 + threadIdx.x;
    if (idx < 65536) {
        int b = idx >> 11, rem = idx & 2047, m = rem >> 6, dd = rem & 63;
        float s = 0.f;
        for (int ch = 0; ch < 16; ++ch) s += kvp[((b * 16 + ch) * 64 + dd) * 32 + m];
        kptvT[idx] = s;     // idx == (b*32+m)*64+dd
    } else if (idx < 65536 + 1024) {
        int i = idx - 65536;
        int b = i >> 5, m = i & 31;
        float s = 0.f;
        for (int ch = 0; ch < 16; ++ch) s += skpp[(b * 16 + ch) * 32 + m];
        sum_kp[i] = s;
    }
}

// ---------------------------------------------------------------------------
// yatt = (qp @ kptv^T)/(D+eps); out = v + yatt@proj + proj_b. lane = token.
// ---------------------------------------------------------------------------
__global__ __launch_bounds__(256) void k_yatt(
        const float* __restrict__ kqvT, const float* __restrict__ qpT,
        const float* __restrict__ sum_kp, const float* __restrict__ kptvT,
        const float* __restrict__ projT, const float* __restrict__ proj_b,
        float* __restrict__ yattT) {
    const int b = blockIdx.y;
    const int t = blockIdx.x * 256 + threadIdx.x;
    const float* sk = sum_kp + b * 32;
    const float* kv = kptvT + b * 2048;
    const float* qpp = qpT + (size_t)b * 32 * TOK + t;
    float a[64];
#pragma unroll
    for (int i = 0; i < 64; ++i) a[i] = 0.f;
    float D = 0.f;
    for (int m = 0; m < 32; ++m) {
        float q = qpp[(size_t)m * TOK];
        D = fmaf(q, sk[m], D);
        const float* kvr = kv + m * 64;   // uniform
#pragma unroll
        for (int i = 0; i < 64; ++i) a[i] = fmaf(q, kvr[i], a[i]);
    }
    const float rD = 1.f / (D + 1e-8f);
#pragma unroll
    for (int i = 0; i < 64; ++i) a[i] *= rD;

    const float* vb = kqvT + ((size_t)(b * 192 + 128)) * TOK + t;
    float* yb = yattT + (size_t)b * 64 * TOK + t;
    for (int o = 0; o < 64; ++o) {
        const float* pw = projT + o * 64;  // uniform
        float s = proj_b[o];
#pragma unroll
        for (int i = 0; i < 64; ++i) s = fmaf(pw[i], a[i], s);
        s += vb[(size_t)o * TOK];
        yb[(size_t)o * TOK] = s;
    }
}

// ---------------------------------------------------------------------------
// LN2 + MLP + skip. lane = token; ~200 live floats -> (256,1), no spill.
// ---------------------------------------------------------------------------
__global__ __launch_bounds__(256, 1) void k_mlp(
        const float* __restrict__ yattT, const float* __restrict__ g2,
        const float* __restrict__ b2ln, const float* __restrict__ w1T,
        const float* __restrict__ b1, const float* __restrict__ w2m,
        const float* __restrict__ b2, float* __restrict__ out) {
    const int b = blockIdx.y;
    const int tid = threadIdx.x;
    const int lane = tid & 63;
    const int wv = tid >> 6;
    const int t = blockIdx.x * 256 + tid;
    __shared__ float tile[4 * 64 * 65];
    float* tl = tile + wv * 64 * 65;

    const float* yb = yattT + (size_t)b * 64 * TOK + t;
    float y[64];
#pragma unroll
    for (int i = 0; i < 64; ++i) y[i] = yb[(size_t)i * TOK];
    float mu = 0.f;
#pragma unroll
    for (int i = 0; i < 64; ++i) mu += y[i];
    mu *= (1.f / 64.f);
    float var = 0.f;
#pragma unroll
    for (int i = 0; i < 64; ++i) { float d = y[i] - mu; var = fmaf(d, d, var); }
    const float rs = rsqrtf(var * (1.f / 64.f) + 1e-5f);
    float h[64];
#pragma unroll
    for (int i = 0; i < 64; ++i) h[i] = (y[i] - mu) * rs * g2[i] + b2ln[i];
    float o[64];
#pragma unroll
    for (int i = 0; i < 64; ++i) o[i] = y[i] + b2[i];

    for (int i = 0; i < 64; ++i) {        // hidden dim, dynamic
        const float* w1r = w1T + i * 64;  // uniform
        float s = b1[i];
#pragma unroll
        for (int j = 0; j < 64; ++j) s = fmaf(w1r[j], h[j], s);
        const float hg = gelu_exact(s);
        const float* w2r = w2m + i * 64;  // uniform (row-major mlp_w2)
#pragma unroll
        for (int j = 0; j < 64; ++j) o[j] = fmaf(w2r[j], hg, o[j]);
    }

#pragma unroll
    for (int i = 0; i < 64; ++i) tl[lane * 65 + i] = o[i];
    __syncthreads();
    const int t0 = blockIdx.x * 256 + wv * 64;
    float* ob = out + ((size_t)b * TOK + t0) * 64;
    for (int it = 0; it < 16; ++it) {
        int flat = it * 64 + lane;
        int trow = flat >> 4, oq = flat & 15;
        float4 v;
        v.x = tl[trow * 65 + oq * 4 + 0];
        v.y = tl[trow * 65 + oq * 4 + 1];
        v.z = tl[trow * 65 + oq * 4 + 2];
        v.w = tl[trow * 65 + oq * 4 + 3];
        ((float4*)(ob + trow * 64))[oq] = v;
    }
}

// ---------------------------------------------------------------------------
extern "C" void kernel_launch(void* const* d_in, const int* in_sizes, int n_in,
                              void* d_out, int out_size, void* d_ws, size_t ws_size,
                              hipStream_t stream) {
    const float* x      = (const float*)d_in[0];
    const float* conv_w = (const float*)d_in[1];
    const float* conv_b = (const float*)d_in[2];
    const float* ln1_g  = (const float*)d_in[3];
    const float* ln1_b  = (const float*)d_in[4];
    const float* kqv_w  = (const float*)d_in[5];
    const float* kqv_b  = (const float*)d_in[6];
    const float* proj_w = (const float*)d_in[7];
    const float* proj_b = (const float*)d_in[8];
    const float* w_perf = (const float*)d_in[9];
    const float* ln2_g  = (const float*)d_in[10];
    const float* ln2_b  = (const float*)d_in[11];
    const float* mlp_w1 = (const float*)d_in[12];
    const float* mlp_b1 = (const float*)d_in[13];
    const float* mlp_w2 = (const float*)d_in[14];
    const float* mlp_b2 = (const float*)d_in[15];

    float* ws = (float*)d_ws;
    // prep weights
    short* w2    = (short*)ws;         // 110592 bf16 (55296 floats)
    short* kwbf  = (short*)(ws + 110592);  // 36864 bf16 in old kwT slot
    float* projT = ws + 147456;        // 4096
    float* w1T   = ws + 151552;        // 4096
    // big region A
    float* tokens = ws + 155648;       // 25165824 floats
    float* qpT    = tokens;                      // 4194304
    float* kpT    = tokens + 4194304;            // 4194304
    float* skpp   = tokens + 8388608;            // 16384
    float* kvp    = tokens + 8404992;            // 1048576
    float* sum_kp = tokens + 9453568;            // 1024
    float* kptvT  = tokens + 9454592;            // 65536
    float* yattT  = tokens + 9520128;            // 8388608
    // big region B
    float* kqvT   = ws + 155648 + 25165824;      // 25165824
    float* outp   = (float*)d_out;

    k_prep <<<608, 256, 0, stream>>>(conv_w, kqv_w, proj_w, mlp_w1, w2, kwbf, projT, w1T);
    k_conv_mfma<<<dim3(64, 32, 3), 256, 0, stream>>>(x, w2, conv_b, tokens);
    k_lnkqv_mfma<<<dim3(64, 32), 256, 0, stream>>>(tokens, ln1_g, ln1_b, kwbf, kqv_b, kqvT);
    k_perf <<<dim3(16, 32), 256, 0, stream>>>(kqvT, w_perf, kpT, qpT);
    k_kptv <<<dim3(16, 32), 256, 0, stream>>>(kqvT, kpT, kvp, skpp);
    k_reduce<<<261, 256, 0, stream>>>(kvp, skpp, kptvT, sum_kp);
    k_yatt <<<dim3(16, 32), 256, 0, stream>>>(kqvT, qpT, sum_kp, kptvT, projT, proj_b, yattT);
    k_mlp  <<<dim3(16, 32), 256, 0, stream>>>(yattT, ln2_g, ln2_b, w1T, mlp_b1, mlp_w2, mlp_b2, outp);
}

// Round 5
// 425.655 us; speedup vs baseline: 8.2962x; 1.2030x over previous
//
#include <hip/hip_runtime.h>

// ---------------------------------------------------------------------------
// BlockRC2: PRM (3 dilated stride-2 convs + GELU) -> LN1 -> kqv ->
// performer attention -> proj+skip -> LN2 -> MLP -> skip.
// Round 5: (a) conv reads bf16 image directly from L2 (no LDS, no zero-fill,
// no bank conflicts; r4 had 1e7 conflicts + 52KB zero-fill per block);
// (b) yatt+proj+LN2+MLP fused into one MFMA kernel (r4 tail was ~250 us of
// scalar-FMA kernels at 1 wave/SIMD). yattT buffer eliminated.
// ---------------------------------------------------------------------------

#define TOK 4096
#define NB  32

typedef __attribute__((ext_vector_type(8)))  short short8;
typedef __attribute__((ext_vector_type(4)))  short short4v;
typedef __attribute__((ext_vector_type(16))) float f32x16;

__device__ __forceinline__ float gelu_exact(float v) {
    return 0.5f * v * (1.f + erff(v * 0.70710678118654752f));
}

__device__ __forceinline__ short f2bf(float f) {
    union { float f; unsigned u; } x; x.f = f;
    unsigned r = (x.u + 0x7FFFu + ((x.u >> 16) & 1u)) >> 16;
    return (short)r;
}

// ---------------------------------------------------------------------------
// Prep: conv_w -> w2c [br][r][kw][e][c] bf16; kqv_w -> kwbf [o][i] bf16;
// proj_w -> pTbf [o][d] bf16; mlp_w1 -> w1bf [i][j] bf16; mlp_w2 -> w2bf
// [o][i] bf16.
// ---------------------------------------------------------------------------
__global__ __launch_bounds__(256) void k_prep(
        const float* __restrict__ cw, const float* __restrict__ kw,
        const float* __restrict__ pw, const float* __restrict__ w1,
        const float* __restrict__ w2m,
        short* __restrict__ w2c, short* __restrict__ kwbf,
        short* __restrict__ pTbf, short* __restrict__ w1bf,
        short* __restrict__ w2bf) {
    int idx = blockIdx.x * 256 + threadIdx.x;
    if (idx < 110592) {
        int c = idx & 63;
        int t = idx >> 6;
        int e = t & 63;
        int tap = t >> 6;
        int kwi = tap % 3, t2 = tap / 3;
        int r = t2 % 3, brr = t2 / 3;
        w2c[idx] = f2bf(cw[(((brr * 64 + e) * 64 + c) * 3 + r) * 3 + kwi]);
    } else if (idx < 147456) {
        int i2 = idx - 110592;
        int o = i2 / 192, i = i2 % 192;
        kwbf[i2] = f2bf(kw[i * 192 + o]);
    } else if (idx < 151552) {
        int i2 = idx - 147456;
        int o = i2 >> 6, d = i2 & 63;
        pTbf[i2] = f2bf(pw[d * 64 + o]);
    } else if (idx < 155648) {
        int i2 = idx - 151552;
        int i = i2 >> 6, j = i2 & 63;
        w1bf[i2] = f2bf(w1[j * 64 + i]);
    } else if (idx < 159744) {
        int i2 = idx - 155648;
        int o = i2 >> 6, i = i2 & 63;
        w2bf[i2] = f2bf(w2m[i * 64 + o]);
    }
}

// ---------------------------------------------------------------------------
// x fp32 [b][h*128+w][c] -> xbf bf16 (same layout). 196 MB traffic.
// ---------------------------------------------------------------------------
__global__ __launch_bounds__(256) void k_cvt(
        const float* __restrict__ x, short* __restrict__ xbf) {
    size_t i0 = ((size_t)blockIdx.x * 256 + threadIdx.x) * 8;
    float4 a = *(const float4*)(x + i0);
    float4 b = *(const float4*)(x + i0 + 4);
    short8 p;
    p[0] = f2bf(a.x); p[1] = f2bf(a.y); p[2] = f2bf(a.z); p[3] = f2bf(a.w);
    p[4] = f2bf(b.x); p[5] = f2bf(b.y); p[6] = f2bf(b.z); p[7] = f2bf(b.w);
    *(short8*)(xbf + i0) = p;
}

// ---------------------------------------------------------------------------
// Conv via MFMA, A-fragments straight from global (L1/L2 hot). No LDS.
// Block: x = oh*3+br, y = b. 4 waves: wm = ow-tile, wn = e-tile.
// OOB ih rows: block-uniform skip (zero contribution). OOB iw: per-lane
// predicated load (exec-masked), a = 0.
// ---------------------------------------------------------------------------
__global__ __launch_bounds__(256) void k_conv2(
        const short* __restrict__ xbf, const short* __restrict__ w2c,
        const float* __restrict__ cb, float* __restrict__ tokens) {
    const int bx = blockIdx.x;
    const int oh = bx / 3;
    const int br = bx - oh * 3;
    const int b  = blockIdx.y;
    const int d  = br + 1;
    const int tid = threadIdx.x;
    const int lane = tid & 63;
    const int wv = tid >> 6;
    const int wm = wv & 1;
    const int wn = wv >> 1;
    const int cl = lane & 31;
    const int g  = lane >> 5;
    const int ow = wm * 32 + cl;

    f32x16 acc = {0.f, 0.f, 0.f, 0.f, 0.f, 0.f, 0.f, 0.f,
                  0.f, 0.f, 0.f, 0.f, 0.f, 0.f, 0.f, 0.f};
    const short8 z8 = {0, 0, 0, 0, 0, 0, 0, 0};
    const short* wbr = w2c + br * 9 * 4096;

    for (int r = 0; r < 3; ++r) {
        const int ih = 2 * oh + (r - 1) * d;
        if ((unsigned)ih < 128u) {                     // block-uniform
            const short* rowb = xbf + (((size_t)(b * 128 + ih)) << 13);
#pragma unroll
            for (int kwi = 0; kwi < 3; ++kwi) {
                const int iw = 2 * ow + (kwi - 1) * d;
                const bool valid = (unsigned)iw < 128u;
                const short* ap = rowb + iw * 64 + g * 8;
                const short* wtap = wbr + (r * 3 + kwi) * 4096
                                  + (wn * 32 + cl) * 64 + g * 8;
#pragma unroll
                for (int ks = 0; ks < 4; ++ks) {
                    short8 a = z8;
                    if (valid) a = *(const short8*)(ap + ks * 16);
                    short8 bf = *(const short8*)(wtap + ks * 16);
                    acc = __builtin_amdgcn_mfma_f32_32x32x16_bf16(a, bf, acc, 0, 0, 0);
                }
            }
        }
    }

    const int eG = br * 64 + wn * 32 + cl;
    const float bias = cb[eG];
    float* outb = tokens + ((size_t)(b * TOK + oh * 64 + wm * 32)) * 192 + eG;
#pragma unroll
    for (int reg = 0; reg < 16; ++reg) {
        int owl = (reg & 3) + 8 * (reg >> 2) + 4 * g;
        outb[(size_t)owl * 192] = gelu_exact(acc[reg] + bias);
    }
}

// ---------------------------------------------------------------------------
// LN1 + kqv via MFMA (unchanged from round 4).
// ---------------------------------------------------------------------------
__global__ __launch_bounds__(256) void k_lnkqv_mfma(
        const float* __restrict__ tokens, const float* __restrict__ g,
        const float* __restrict__ be, const short* __restrict__ wbf,
        const float* __restrict__ bias, float* __restrict__ kqvT) {
    const int b = blockIdx.y;
    const int t0 = blockIdx.x * 64;
    const int tid = threadIdx.x;

    __shared__ short sB[64 * 192];
    __shared__ float red[64 * 8];

    const int r = tid >> 2, q = tid & 3;
    const float* rowp = tokens + ((size_t)(b * TOK + t0 + r)) * 192 + q * 48;
    float v[48];
    float s1 = 0.f, s2 = 0.f;
#pragma unroll
    for (int i = 0; i < 12; ++i) {
        float4 x4 = ((const float4*)rowp)[i];
        v[4 * i + 0] = x4.x; v[4 * i + 1] = x4.y;
        v[4 * i + 2] = x4.z; v[4 * i + 3] = x4.w;
        s1 += x4.x + x4.y + x4.z + x4.w;
        s2 += x4.x * x4.x + x4.y * x4.y + x4.z * x4.z + x4.w * x4.w;
    }
    red[r * 8 + q] = s1;
    red[r * 8 + 4 + q] = s2;
    __syncthreads();
    const float m1 = red[r * 8 + 0] + red[r * 8 + 1] + red[r * 8 + 2] + red[r * 8 + 3];
    const float m2 = red[r * 8 + 4] + red[r * 8 + 5] + red[r * 8 + 6] + red[r * 8 + 7];
    const float mu = m1 * (1.f / 192.f);
    const float var = m2 * (1.f / 192.f) - mu * mu;
    const float rs = rsqrtf(fmaxf(var, 0.f) + 1e-5f);
    const float4* g4 = (const float4*)(g + q * 48);
    const float4* b4 = (const float4*)(be + q * 48);
    char* rowB = (char*)sB + r * 384;
    const int swz = (r & 7) << 4;
#pragma unroll
    for (int i = 0; i < 12; ++i) {
        float4 gg = g4[i], bb = b4[i];
        short4v pk;
        pk.x = f2bf((v[4 * i + 0] - mu) * rs * gg.x + bb.x);
        pk.y = f2bf((v[4 * i + 1] - mu) * rs * gg.y + bb.y);
        pk.z = f2bf((v[4 * i + 2] - mu) * rs * gg.z + bb.z);
        pk.w = f2bf((v[4 * i + 3] - mu) * rs * gg.w + bb.w);
        *(short4v*)(rowB + (((q * 48 + i * 4) * 2) ^ swz)) = pk;
    }
    __syncthreads();

    const int lane = tid & 63;
    const int wv = tid >> 6;
    const int tt = wv & 1;
    const int wo = wv >> 1;
    const int colL = lane & 31;
    const int gq = lane >> 5;

    f32x16 acc0 = {0.f, 0.f, 0.f, 0.f, 0.f, 0.f, 0.f, 0.f,
                   0.f, 0.f, 0.f, 0.f, 0.f, 0.f, 0.f, 0.f};
    f32x16 acc1 = acc0, acc2 = acc0;
    const char* bbase = (const char*)sB + (tt * 32 + colL) * 384;
    const int bswz = ((tt * 32 + colL) & 7) << 4;
    const short* arow = wbf + (wo * 32 + colL) * 192 + gq * 8;

    for (int kk = 0; kk < 12; ++kk) {
        short8 bf = *(const short8*)(bbase + (((kk * 16 + gq * 8) * 2) ^ bswz));
        short8 a0 = *(const short8*)(arow + kk * 16);
        short8 a1 = *(const short8*)(arow + 64 * 192 + kk * 16);
        short8 a2 = *(const short8*)(arow + 128 * 192 + kk * 16);
        acc0 = __builtin_amdgcn_mfma_f32_32x32x16_bf16(a0, bf, acc0, 0, 0, 0);
        acc1 = __builtin_amdgcn_mfma_f32_32x32x16_bf16(a1, bf, acc1, 0, 0, 0);
        acc2 = __builtin_amdgcn_mfma_f32_32x32x16_bf16(a2, bf, acc2, 0, 0, 0);
    }

    const int tglob = t0 + tt * 32 + colL;
    float* outb = kqvT + (size_t)b * 192 * TOK + tglob;
#pragma unroll
    for (int j = 0; j < 3; ++j) {
        const int obase = (wo + 2 * j) * 32;
        const f32x16 ac = (j == 0 ? acc0 : j == 1 ? acc1 : acc2);
#pragma unroll
        for (int reg = 0; reg < 16; ++reg) {
            int orow = (reg & 3) + 8 * (reg >> 2) + 4 * gq;
            outb[(size_t)(obase + orow) * TOK] = ac[reg] + bias[obase + orow];
        }
    }
}

// ---------------------------------------------------------------------------
// Performer features (unchanged).
// ---------------------------------------------------------------------------
__global__ __launch_bounds__(256) void k_perf(
        const float* __restrict__ kqvT, const float* __restrict__ wperf,
        float* __restrict__ kpT, float* __restrict__ qpT) {
    const int b = blockIdx.y;
    const int t = blockIdx.x * 256 + threadIdx.x;
    const float* basek = kqvT + (size_t)b * 192 * TOK + t;
    for (int pass = 0; pass < 2; ++pass) {
        float kr[64];
        const float* src = basek + (size_t)pass * 64 * TOK;
#pragma unroll
        for (int i = 0; i < 64; ++i) kr[i] = src[(size_t)i * TOK];
        float xd = 0.f;
#pragma unroll
        for (int i = 0; i < 64; ++i) xd = fmaf(kr[i], kr[i], xd);
        xd *= 0.5f;
        float* dst = (pass == 0 ? kpT : qpT) + (size_t)b * 32 * TOK + t;
        for (int m = 0; m < 32; ++m) {
            const float* wr = wperf + m * 64;
            float a = 0.f;
#pragma unroll
            for (int i = 0; i < 64; ++i) a = fmaf(wr[i], kr[i], a);
            dst[(size_t)m * TOK] = expf(a - xd) * 0.17677669529663687f;
        }
    }
}

// ---------------------------------------------------------------------------
// kptv chunk partials (unchanged).
// ---------------------------------------------------------------------------
__global__ __launch_bounds__(256) void k_kptv(
        const float* __restrict__ kqvT, const float* __restrict__ kpT,
        float* __restrict__ kvp, float* __restrict__ skpp) {
    const int b = blockIdx.y, ch = blockIdx.x, tid = threadIdx.x;
    const int t = ch * 256 + tid;
    __shared__ float sv[256 * 65 + 256 * 36];
    float* skp = sv + 256 * 65;
    for (int dd = 0; dd < 64; ++dd)
        sv[tid * 65 + dd] = kqvT[((size_t)(b * 192 + 128 + dd)) * TOK + t];
    for (int m = 0; m < 32; ++m)
        skp[tid * 36 + m] = kpT[((size_t)(b * 32 + m)) * TOK + t];
    __syncthreads();

    const int dd = tid & 63;
    const int mg = __builtin_amdgcn_readfirstlane(tid >> 6);
    float acc[8];
#pragma unroll
    for (int j = 0; j < 8; ++j) acc[j] = 0.f;
    for (int tt = 0; tt < 256; ++tt) {
        float vv = sv[tt * 65 + dd];
        const float4* kq = (const float4*)(skp + tt * 36 + mg * 8);
        float4 a0 = kq[0], a1 = kq[1];
        acc[0] = fmaf(vv, a0.x, acc[0]);
        acc[1] = fmaf(vv, a0.y, acc[1]);
        acc[2] = fmaf(vv, a0.z, acc[2]);
        acc[3] = fmaf(vv, a0.w, acc[3]);
        acc[4] = fmaf(vv, a1.x, acc[4]);
        acc[5] = fmaf(vv, a1.y, acc[5]);
        acc[6] = fmaf(vv, a1.z, acc[6]);
        acc[7] = fmaf(vv, a1.w, acc[7]);
    }
    float* dst = kvp + (((size_t)(b * 16 + ch) * 64 + dd) * 32) + mg * 8;
#pragma unroll
    for (int j = 0; j < 8; ++j) dst[j] = acc[j];

    if (tid < 32) {
        float s = 0.f;
        for (int tt = 0; tt < 256; ++tt) s += skp[tt * 36 + tid];
        skpp[(b * 16 + ch) * 32 + tid] = s;
    }
}

// Reduce partials -> kvbf [b][64 d][32 m] bf16, sum_kp [b][32 m] fp32.
__global__ __launch_bounds__(256) void k_reduce2(
        const float* __restrict__ kvp, const float* __restrict__ skpp,
        short* __restrict__ kvbf, float* __restrict__ sum_kp) {
    int idx = blockIdx.x * 256 + threadIdx.x;
    if (idx < 65536) {
        int b = idx >> 11, rem = idx & 2047, dd = rem >> 5, m = rem & 31;
        float s = 0.f;
        for (int ch = 0; ch < 16; ++ch) s += kvp[((b * 16 + ch) * 64 + dd) * 32 + m];
        kvbf[idx] = f2bf(s);           // idx == (b*64+dd)*32+m
    } else if (idx < 65536 + 1024) {
        int i = idx - 65536;
        int b = i >> 5, m = i & 31;
        float s = 0.f;
        for (int ch = 0; ch < 16; ++ch) s += skpp[(b * 16 + ch) * 32 + m];
        sum_kp[i] = s;
    }
}

// ---------------------------------------------------------------------------
// Fused: yatt = (qp@kv^T)*rD -> proj+v+b -> LN2 -> w1+GELU -> w2 + skip.
// Block = 64 tokens, 4 waves (wr = row-tile, wc = col-tile). All GEMM
// intermediates as bf16 LDS tiles [t][k], rows padded to 72 shorts (bank
// period 8). Fragment maps identical to proven conv/lnkqv kernels.
// ---------------------------------------------------------------------------
__global__ __launch_bounds__(256) void k_fuse(
        const float* __restrict__ kqvT, const float* __restrict__ qpT,
        const short* __restrict__ kvbf, const float* __restrict__ sum_kp,
        const short* __restrict__ pTbf, const float* __restrict__ proj_b,
        const float* __restrict__ g2, const float* __restrict__ b2ln,
        const short* __restrict__ w1bf, const float* __restrict__ b1,
        const short* __restrict__ w2bf, const float* __restrict__ b2,
        float* __restrict__ out) {
    const int b = blockIdx.y;
    const int t0 = blockIdx.x * 64;
    const int tid = threadIdx.x;
    const int lane = tid & 63;
    const int cl = lane & 31;
    const int g  = lane >> 5;
    const int wv = tid >> 6;
    const int wr = wv & 1;
    const int wc = wv >> 1;

    __shared__ __align__(16) char pool[29952];
    short* qpS  = (short*)(pool + 0);        // [64][40]  (dead after G1)
    short* ytS  = (short*)(pool + 5120);     // [64][72]  (dead after G2)
    short* xnS  = (short*)(pool + 14336);    // [64][72]  (dead after G3)
    short* hgS  = (short*)(pool + 0);        // [64][72]  alias qpS/ytS-head
    float* outS = (float*)(pool + 9216);     // [64][68]  alias ytS-tail/xnS
    float* red  = (float*)(pool + 26624);    // [64][4]
    float* stat = (float*)(pool + 27648);    // [2][64][2]
    float* coefS= (float*)(pool + 28672);    // [5][64]

    // ---- phase 0: coefs, qp tile (bf16), per-token D partials ----
    if (tid < 64) {
        coefS[tid]       = proj_b[tid];
        coefS[64 + tid]  = g2[tid];
        coefS[128 + tid] = b2ln[tid];
        coefS[192 + tid] = b1[tid];
        coefS[256 + tid] = b2[tid];
    }
    {
        const int t = tid & 63, q = tid >> 6;
        const float* sk = sum_kp + b * 32;
        float dsum = 0.f;
        short8 pk;
#pragma unroll
        for (int i = 0; i < 8; ++i) {
            int m = q * 8 + i;
            float v = qpT[((size_t)(b * 32 + m)) * TOK + t0 + t];
            dsum = fmaf(v, sk[m], dsum);
            pk[i] = f2bf(v);
        }
        *(short8*)(qpS + t * 40 + q * 8) = pk;
        red[t * 4 + q] = dsum;
    }
    __syncthreads();

    const int tl = wc * 32 + cl;            // local token col for this lane
    const int tg = t0 + tl;                 // global token

    // ---- G1: yatt_d[d][t] = kv[d][m] @ qp[m][t], K=32; scale by rD ----
    f32x16 acc = {0.f, 0.f, 0.f, 0.f, 0.f, 0.f, 0.f, 0.f,
                  0.f, 0.f, 0.f, 0.f, 0.f, 0.f, 0.f, 0.f};
    {
        const short* Ab = kvbf + ((size_t)(b * 64) + wr * 32 + cl) * 32;
        short8 a0 = *(const short8*)(Ab + g * 8);
        short8 a1 = *(const short8*)(Ab + 16 + g * 8);
        short8 b0 = *(const short8*)(qpS + tl * 40 + g * 8);
        short8 b1v = *(const short8*)(qpS + tl * 40 + 16 + g * 8);
        acc = __builtin_amdgcn_mfma_f32_32x32x16_bf16(a0, b0, acc, 0, 0, 0);
        acc = __builtin_amdgcn_mfma_f32_32x32x16_bf16(a1, b1v, acc, 0, 0, 0);
    }
    {
        float Dv = red[tl * 4 + 0] + red[tl * 4 + 1] + red[tl * 4 + 2] + red[tl * 4 + 3];
        float rD = 1.f / (Dv + 1e-8f);
#pragma unroll
        for (int rq = 0; rq < 4; ++rq) {
            int d0 = wr * 32 + 8 * rq + 4 * g;
            short4v p;
            p.x = f2bf(acc[rq * 4 + 0] * rD);
            p.y = f2bf(acc[rq * 4 + 1] * rD);
            p.z = f2bf(acc[rq * 4 + 2] * rD);
            p.w = f2bf(acc[rq * 4 + 3] * rD);
            *(short4v*)(ytS + tl * 72 + d0) = p;
        }
    }
    __syncthreads();

    // ---- G2: proj_out[o][t] = pT[o][d] @ yt[d][t], K=64; + v + proj_b ----
    f32x16 acc2 = {0.f, 0.f, 0.f, 0.f, 0.f, 0.f, 0.f, 0.f,
                   0.f, 0.f, 0.f, 0.f, 0.f, 0.f, 0.f, 0.f};
    {
        const short* Ap = pTbf + (wr * 32 + cl) * 64;
#pragma unroll
        for (int ks = 0; ks < 4; ++ks) {
            short8 a = *(const short8*)(Ap + ks * 16 + g * 8);
            short8 bb = *(const short8*)(ytS + tl * 72 + ks * 16 + g * 8);
            acc2 = __builtin_amdgcn_mfma_f32_32x32x16_bf16(a, bb, acc2, 0, 0, 0);
        }
    }
    float skv[16];
    {
        const float* vb = kqvT + ((size_t)(b * 192 + 128)) * TOK + tg;
#pragma unroll
        for (int reg = 0; reg < 16; ++reg) {
            int o = wr * 32 + (reg & 3) + 8 * (reg >> 2) + 4 * g;
            skv[reg] = acc2[reg] + vb[(size_t)o * TOK] + coefS[o];
        }
    }

    // ---- LN2 over o (cross-wave via stat) ----
    {
        float s1 = 0.f, s2 = 0.f;
#pragma unroll
        for (int reg = 0; reg < 16; ++reg) {
            s1 += skv[reg];
            s2 = fmaf(skv[reg], skv[reg], s2);
        }
        s1 += __shfl_xor(s1, 32, 64);
        s2 += __shfl_xor(s2, 32, 64);
        if (g == 0) {
            stat[(wr * 64 + tl) * 2 + 0] = s1;
            stat[(wr * 64 + tl) * 2 + 1] = s2;
        }
        __syncthreads();
        float S1 = s1 + stat[((wr ^ 1) * 64 + tl) * 2 + 0];
        float S2 = s2 + stat[((wr ^ 1) * 64 + tl) * 2 + 1];
        float mu = S1 * (1.f / 64.f);
        float var = S2 * (1.f / 64.f) - mu * mu;
        float rs = rsqrtf(fmaxf(var, 0.f) + 1e-5f);
#pragma unroll
        for (int rq = 0; rq < 4; ++rq) {
            int o0 = wr * 32 + 8 * rq + 4 * g;
            short4v p;
#pragma unroll
            for (int j = 0; j < 4; ++j) {
                int o = o0 + j;
                float xn = (skv[rq * 4 + j] - mu) * rs * coefS[64 + o] + coefS[128 + o];
                ((short*)&p)[j] = f2bf(xn);
            }
            *(short4v*)(xnS + tl * 72 + o0) = p;
        }
    }
    __syncthreads();

    // ---- G3: h1[i][t] = w1T[i][j] @ xn[j][t], K=64; +b1, GELU ----
    f32x16 acc3 = {0.f, 0.f, 0.f, 0.f, 0.f, 0.f, 0.f, 0.f,
                   0.f, 0.f, 0.f, 0.f, 0.f, 0.f, 0.f, 0.f};
    {
        const short* A1 = w1bf + (wr * 32 + cl) * 64;
#pragma unroll
        for (int ks = 0; ks < 4; ++ks) {
            short8 a = *(const short8*)(A1 + ks * 16 + g * 8);
            short8 bb = *(const short8*)(xnS + tl * 72 + ks * 16 + g * 8);
            acc3 = __builtin_amdgcn_mfma_f32_32x32x16_bf16(a, bb, acc3, 0, 0, 0);
        }
    }
    __syncthreads();        // xnS reads done everywhere before hgS overwrite
    {
#pragma unroll
        for (int rq = 0; rq < 4; ++rq) {
            int i0 = wr * 32 + 8 * rq + 4 * g;
            short4v p;
#pragma unroll
            for (int j = 0; j < 4; ++j) {
                int i = i0 + j;
                float hgv = gelu_exact(acc3[rq * 4 + j] + coefS[192 + i]);
                ((short*)&p)[j] = f2bf(hgv);
            }
            *(short4v*)(hgS + tl * 72 + i0) = p;
        }
    }
    __syncthreads();

    // ---- G4: mlp[o][t] = w2T[o][i] @ hg[i][t], K=64; + skv + b2 ----
    f32x16 acc4 = {0.f, 0.f, 0.f, 0.f, 0.f, 0.f, 0.f, 0.f,
                   0.f, 0.f, 0.f, 0.f, 0.f, 0.f, 0.f, 0.f};
    {
        const short* A2 = w2bf + (wr * 32 + cl) * 64;
#pragma unroll
        for (int ks = 0; ks < 4; ++ks) {
            short8 a = *(const short8*)(A2 + ks * 16 + g * 8);
            short8 bb = *(const short8*)(hgS + tl * 72 + ks * 16 + g * 8);
            acc4 = __builtin_amdgcn_mfma_f32_32x32x16_bf16(a, bb, acc4, 0, 0, 0);
        }
    }
    {
#pragma unroll
        for (int rq = 0; rq < 4; ++rq) {
            int o0 = wr * 32 + 8 * rq + 4 * g;
            float4 f;
#pragma unroll
            for (int j = 0; j < 4; ++j) {
                int o = o0 + j;
                ((float*)&f)[j] = skv[rq * 4 + j] + acc4[rq * 4 + j] + coefS[256 + o];
            }
            *(float4*)(outS + tl * 68 + o0) = f;
        }
    }
    __syncthreads();

    // ---- coalesced store: out[b][t][o] ----
    {
        const int tt = tid >> 2, qq = tid & 3;
        float* ob = out + ((size_t)(b * TOK) + t0 + tt) * 64;
#pragma unroll
        for (int it = 0; it < 4; ++it) {
            *(float4*)(ob + it * 16 + qq * 4) =
                *(float4*)(outS + tt * 68 + it * 16 + qq * 4);
        }
    }
}

// ---------------------------------------------------------------------------
extern "C" void kernel_launch(void* const* d_in, const int* in_sizes, int n_in,
                              void* d_out, int out_size, void* d_ws, size_t ws_size,
                              hipStream_t stream) {
    const float* x      = (const float*)d_in[0];
    const float* conv_w = (const float*)d_in[1];
    const float* conv_b = (const float*)d_in[2];
    const float* ln1_g  = (const float*)d_in[3];
    const float* ln1_b  = (const float*)d_in[4];
    const float* kqv_w  = (const float*)d_in[5];
    const float* kqv_b  = (const float*)d_in[6];
    const float* proj_w = (const float*)d_in[7];
    const float* proj_b = (const float*)d_in[8];
    const float* w_perf = (const float*)d_in[9];
    const float* ln2_g  = (const float*)d_in[10];
    const float* ln2_b  = (const float*)d_in[11];
    const float* mlp_w1 = (const float*)d_in[12];
    const float* mlp_b1 = (const float*)d_in[13];
    const float* mlp_w2 = (const float*)d_in[14];
    const float* mlp_b2 = (const float*)d_in[15];

    float* ws = (float*)d_ws;
    // static weights / small buffers
    short* w2c    = (short*)ws;                 // 110592 sh
    short* kwbf   = (short*)(ws + 55296);       // 36864 sh
    short* pTbf   = (short*)(ws + 73728);       // 4096 sh
    short* w1bf   = (short*)(ws + 75776);       // 4096 sh
    short* w2bf   = (short*)(ws + 77824);       // 4096 sh
    float* sum_kp = ws + 79872;                 // 1024 f
    short* kvbf   = (short*)(ws + 80896);       // 65536 sh -> ends 113664
    // region A (tokens, overlaid by later stages)
    float* tokens = ws + 114688;                // 25165824 f
    float* qpT    = tokens;                     // 4194304
    float* kpT    = tokens + 4194304;           // 4194304
    float* skpp   = tokens + 8388608;           // 16384
    float* kvp    = tokens + 8404992;           // 1048576
    // region B (xbf then kqvT, sequential lifetimes)
    float* regB   = ws + 114688 + 25165824;
    short* xbf    = (short*)regB;               // 33554432 sh
    float* kqvT   = regB;                       // 25165824 f
    float* outp   = (float*)d_out;

    k_prep   <<<624, 256, 0, stream>>>(conv_w, kqv_w, proj_w, mlp_w1, mlp_w2,
                                       w2c, kwbf, pTbf, w1bf, w2bf);
    k_cvt    <<<16384, 256, 0, stream>>>(x, xbf);
    k_conv2  <<<dim3(192, 32), 256, 0, stream>>>(xbf, w2c, conv_b, tokens);
    k_lnkqv_mfma<<<dim3(64, 32), 256, 0, stream>>>(tokens, ln1_g, ln1_b, kwbf, kqv_b, kqvT);
    k_perf   <<<dim3(16, 32), 256, 0, stream>>>(kqvT, w_perf, kpT, qpT);
    k_kptv   <<<dim3(16, 32), 256, 0, stream>>>(kqvT, kpT, kvp, skpp);
    k_reduce2<<<260, 256, 0, stream>>>(kvp, skpp, kvbf, sum_kp);
    k_fuse   <<<dim3(64, 32), 256, 0, stream>>>(kqvT, qpT, kvbf, sum_kp,
                                                pTbf, proj_b, ln2_g, ln2_b,
                                                w1bf, mlp_b1, w2bf, mlp_b2, outp);
}

// Round 6
// 361.013 us; speedup vs baseline: 9.7816x; 1.1791x over previous
//
#include <hip/hip_runtime.h>

// ---------------------------------------------------------------------------
// BlockRC2: PRM (3 dilated stride-2 convs + GELU) -> LN1 -> kqv ->
// performer attention -> proj+skip -> LN2 -> MLP -> skip.
// Round 6: conv back to LDS staging but fixed: reg-staged bf16 rows with
// write-side XOR swizzle keyed (iw4>>1)&7 (stride-2 reads -> 8 distinct
// slots, was 4 -> 8-way conflicts in r4; r5's LDS-free version was
// address-divergence-bound in L1 at 223 us). tokens now bf16 (halves conv
// write + lnkqv read traffic).
// ---------------------------------------------------------------------------

#define TOK 4096
#define NB  32

typedef __attribute__((ext_vector_type(8)))  short short8;
typedef __attribute__((ext_vector_type(4)))  short short4v;
typedef __attribute__((ext_vector_type(16))) float f32x16;

__device__ __forceinline__ float gelu_exact(float v) {
    return 0.5f * v * (1.f + erff(v * 0.70710678118654752f));
}

__device__ __forceinline__ short f2bf(float f) {
    union { float f; unsigned u; } x; x.f = f;
    unsigned r = (x.u + 0x7FFFu + ((x.u >> 16) & 1u)) >> 16;
    return (short)r;
}

__device__ __forceinline__ float bf2f(short s) {
    union { unsigned u; float f; } x;
    x.u = ((unsigned)(unsigned short)s) << 16;
    return x.f;
}

// ---------------------------------------------------------------------------
// Prep: conv_w -> w2c [br][r][kw][e][c] bf16; kqv_w -> kwbf [o][i] bf16;
// proj_w -> pTbf; mlp_w1 -> w1bf; mlp_w2 -> w2bf (all bf16).
// ---------------------------------------------------------------------------
__global__ __launch_bounds__(256) void k_prep(
        const float* __restrict__ cw, const float* __restrict__ kw,
        const float* __restrict__ pw, const float* __restrict__ w1,
        const float* __restrict__ w2m,
        short* __restrict__ w2c, short* __restrict__ kwbf,
        short* __restrict__ pTbf, short* __restrict__ w1bf,
        short* __restrict__ w2bf) {
    int idx = blockIdx.x * 256 + threadIdx.x;
    if (idx < 110592) {
        int c = idx & 63;
        int t = idx >> 6;
        int e = t & 63;
        int tap = t >> 6;
        int kwi = tap % 3, t2 = tap / 3;
        int r = t2 % 3, brr = t2 / 3;
        w2c[idx] = f2bf(cw[(((brr * 64 + e) * 64 + c) * 3 + r) * 3 + kwi]);
    } else if (idx < 147456) {
        int i2 = idx - 110592;
        int o = i2 / 192, i = i2 % 192;
        kwbf[i2] = f2bf(kw[i * 192 + o]);
    } else if (idx < 151552) {
        int i2 = idx - 147456;
        int o = i2 >> 6, d = i2 & 63;
        pTbf[i2] = f2bf(pw[d * 64 + o]);
    } else if (idx < 155648) {
        int i2 = idx - 151552;
        int i = i2 >> 6, j = i2 & 63;
        w1bf[i2] = f2bf(w1[j * 64 + i]);
    } else if (idx < 159744) {
        int i2 = idx - 155648;
        int o = i2 >> 6, i = i2 & 63;
        w2bf[i2] = f2bf(w2m[i * 64 + o]);
    }
}

// ---------------------------------------------------------------------------
// x fp32 [b][h*128+w][c] -> xbf bf16 (same layout).
// ---------------------------------------------------------------------------
__global__ __launch_bounds__(256) void k_cvt(
        const float* __restrict__ x, short* __restrict__ xbf) {
    size_t i0 = ((size_t)blockIdx.x * 256 + threadIdx.x) * 8;
    float4 a = *(const float4*)(x + i0);
    float4 b = *(const float4*)(x + i0 + 4);
    short8 p;
    p[0] = f2bf(a.x); p[1] = f2bf(a.y); p[2] = f2bf(a.z); p[3] = f2bf(a.w);
    p[4] = f2bf(b.x); p[5] = f2bf(b.y); p[6] = f2bf(b.z); p[7] = f2bf(b.w);
    *(short8*)(xbf + i0) = p;
}

// ---------------------------------------------------------------------------
// Conv via MFMA. Block = (oh, br) x b, 256 thr = 4 waves.
// LDS sA[r=3][iw4=136][c=64] bf16, pitch 128B. Staged from xbf with
// write-side XOR swizzle: byte_in_row = (sub*16) ^ (((iw4>>1)&7)<<4).
// Stride-2 A-reads then hit 8 distinct 16B slots across 32 lanes (<=4-way).
// Borders (iw4<4, >=132) and OOB ih rows stay zero from the initial fill.
// Output tokens bf16 [b][t][e].
// ---------------------------------------------------------------------------
__global__ __launch_bounds__(256) void k_conv3(
        const short* __restrict__ xbf, const short* __restrict__ w2c,
        const float* __restrict__ cb, short* __restrict__ tokens) {
    const int bx = blockIdx.x;
    const int oh = bx / 3;
    const int br = bx - oh * 3;
    const int b  = blockIdx.y;
    const int d  = br + 1;
    const int tid = threadIdx.x;
    const int lane = tid & 63;
    const int wv = __builtin_amdgcn_readfirstlane(tid >> 6);
    const int cl = lane & 31;
    const int g  = lane >> 5;
    const int wm = wv & 1;
    const int wn = wv >> 1;

    __shared__ short sA[3 * 136 * 64];   // 52224 B

    // zero-fill (covers borders + OOB rows)
    {
        short8 z = {0, 0, 0, 0, 0, 0, 0, 0};
        short8* p = (short8*)sA;
        for (int i = tid; i < 3264; i += 256) p[i] = z;
    }
    __syncthreads();

    // reg-stage: 48 chunks of 1KB (8 iw4 cols each); wave wv -> chunks
    // [wv*12, wv*12+12). Global loads linear/coalesced; swizzle on ds_write.
    const int sub = lane & 7;
    const int rowoff = lane >> 3;
    for (int it = 0; it < 12; ++it) {
        const int i = wv * 12 + it;
        const int r = i >> 4;             // 0..2
        const int ch = i & 15;            // 0..15
        const int ih = 2 * oh + (r - 1) * d;
        if ((unsigned)ih < 128u) {        // wave-uniform
            const int iw4 = 4 + ch * 8 + rowoff;
            short8 v = *(const short8*)(xbf + (((size_t)(b * 128 + ih)) << 13)
                                        + (iw4 - 4) * 64 + sub * 8);
            char* dst = (char*)sA + (r * 136 + iw4) * 128
                      + ((sub * 16) ^ (((iw4 >> 1) & 7) << 4));
            *(short8*)dst = v;
        }
    }
    __syncthreads();

    f32x16 acc = {0.f, 0.f, 0.f, 0.f, 0.f, 0.f, 0.f, 0.f,
                  0.f, 0.f, 0.f, 0.f, 0.f, 0.f, 0.f, 0.f};
    const short* wbr = w2c + br * 9 * 4096;
    const int ow = wm * 32 + cl;

    for (int r = 0; r < 3; ++r) {
        const int ih = 2 * oh + (r - 1) * d;
        if ((unsigned)ih < 128u) {                 // block-uniform skip
#pragma unroll
            for (int kwi = 0; kwi < 3; ++kwi) {
                const int iw4 = 2 * ow + (kwi - 1) * d + 4;   // in [1,133]
                const char* arow = (const char*)sA + (r * 136 + iw4) * 128;
                const int swz = ((iw4 >> 1) & 7) << 4;
                const short* wtap = wbr + (r * 3 + kwi) * 4096
                                  + (wn * 32 + cl) * 64 + g * 8;
#pragma unroll
                for (int ks = 0; ks < 4; ++ks) {
                    short8 a = *(const short8*)(arow + ((ks * 32 + g * 16) ^ swz));
                    short8 bf = *(const short8*)(wtap + ks * 16);
                    acc = __builtin_amdgcn_mfma_f32_32x32x16_bf16(a, bf, acc, 0, 0, 0);
                }
            }
        }
    }

    // epilogue: bias + GELU -> bf16 tokens; per reg, 32 lanes = 64B segment
    const int eG = br * 64 + wn * 32 + cl;
    const float bias = cb[eG];
    short* outb = tokens + ((size_t)(b * TOK + oh * 64 + wm * 32)) * 192 + eG;
#pragma unroll
    for (int reg = 0; reg < 16; ++reg) {
        int owl = (reg & 3) + 8 * (reg >> 2) + 4 * g;
        outb[(size_t)owl * 192] = f2bf(gelu_exact(acc[reg] + bias));
    }
}

// ---------------------------------------------------------------------------
// LN1 + kqv via MFMA; tokens now bf16 in.
// ---------------------------------------------------------------------------
__global__ __launch_bounds__(256) void k_lnkqv_mfma(
        const short* __restrict__ tokens, const float* __restrict__ g,
        const float* __restrict__ be, const short* __restrict__ wbf,
        const float* __restrict__ bias, float* __restrict__ kqvT) {
    const int b = blockIdx.y;
    const int t0 = blockIdx.x * 64;
    const int tid = threadIdx.x;

    __shared__ short sB[64 * 192];
    __shared__ float red[64 * 8];

    const int r = tid >> 2, q = tid & 3;
    const short* rowp = tokens + ((size_t)(b * TOK + t0 + r)) * 192 + q * 48;
    float v[48];
    float s1 = 0.f, s2 = 0.f;
#pragma unroll
    for (int i = 0; i < 6; ++i) {
        short8 x8 = *(const short8*)(rowp + i * 8);
#pragma unroll
        for (int j = 0; j < 8; ++j) {
            float f = bf2f(x8[j]);
            v[i * 8 + j] = f;
            s1 += f;
            s2 = fmaf(f, f, s2);
        }
    }
    red[r * 8 + q] = s1;
    red[r * 8 + 4 + q] = s2;
    __syncthreads();
    const float m1 = red[r * 8 + 0] + red[r * 8 + 1] + red[r * 8 + 2] + red[r * 8 + 3];
    const float m2 = red[r * 8 + 4] + red[r * 8 + 5] + red[r * 8 + 6] + red[r * 8 + 7];
    const float mu = m1 * (1.f / 192.f);
    const float var = m2 * (1.f / 192.f) - mu * mu;
    const float rs = rsqrtf(fmaxf(var, 0.f) + 1e-5f);
    const float4* g4 = (const float4*)(g + q * 48);
    const float4* b4 = (const float4*)(be + q * 48);
    char* rowB = (char*)sB + r * 384;
    const int swz = (r & 7) << 4;
#pragma unroll
    for (int i = 0; i < 12; ++i) {
        float4 gg = g4[i], bb = b4[i];
        short4v pk;
        pk.x = f2bf((v[4 * i + 0] - mu) * rs * gg.x + bb.x);
        pk.y = f2bf((v[4 * i + 1] - mu) * rs * gg.y + bb.y);
        pk.z = f2bf((v[4 * i + 2] - mu) * rs * gg.z + bb.z);
        pk.w = f2bf((v[4 * i + 3] - mu) * rs * gg.w + bb.w);
        *(short4v*)(rowB + (((q * 48 + i * 4) * 2) ^ swz)) = pk;
    }
    __syncthreads();

    const int lane = tid & 63;
    const int wv = tid >> 6;
    const int tt = wv & 1;
    const int wo = wv >> 1;
    const int colL = lane & 31;
    const int gq = lane >> 5;

    f32x16 acc0 = {0.f, 0.f, 0.f, 0.f, 0.f, 0.f, 0.f, 0.f,
                   0.f, 0.f, 0.f, 0.f, 0.f, 0.f, 0.f, 0.f};
    f32x16 acc1 = acc0, acc2 = acc0;
    const char* bbase = (const char*)sB + (tt * 32 + colL) * 384;
    const int bswz = ((tt * 32 + colL) & 7) << 4;
    const short* arow = wbf + (wo * 32 + colL) * 192 + gq * 8;

    for (int kk = 0; kk < 12; ++kk) {
        short8 bf = *(const short8*)(bbase + (((kk * 16 + gq * 8) * 2) ^ bswz));
        short8 a0 = *(const short8*)(arow + kk * 16);
        short8 a1 = *(const short8*)(arow + 64 * 192 + kk * 16);
        short8 a2 = *(const short8*)(arow + 128 * 192 + kk * 16);
        acc0 = __builtin_amdgcn_mfma_f32_32x32x16_bf16(a0, bf, acc0, 0, 0, 0);
        acc1 = __builtin_amdgcn_mfma_f32_32x32x16_bf16(a1, bf, acc1, 0, 0, 0);
        acc2 = __builtin_amdgcn_mfma_f32_32x32x16_bf16(a2, bf, acc2, 0, 0, 0);
    }

    const int tglob = t0 + tt * 32 + colL;
    float* outb = kqvT + (size_t)b * 192 * TOK + tglob;
#pragma unroll
    for (int j = 0; j < 3; ++j) {
        const int obase = (wo + 2 * j) * 32;
        const f32x16 ac = (j == 0 ? acc0 : j == 1 ? acc1 : acc2);
#pragma unroll
        for (int reg = 0; reg < 16; ++reg) {
            int orow = (reg & 3) + 8 * (reg >> 2) + 4 * gq;
            outb[(size_t)(obase + orow) * TOK] = ac[reg] + bias[obase + orow];
        }
    }
}

// ---------------------------------------------------------------------------
// Performer features (unchanged).
// ---------------------------------------------------------------------------
__global__ __launch_bounds__(256) void k_perf(
        const float* __restrict__ kqvT, const float* __restrict__ wperf,
        float* __restrict__ kpT, float* __restrict__ qpT) {
    const int b = blockIdx.y;
    const int t = blockIdx.x * 256 + threadIdx.x;
    const float* basek = kqvT + (size_t)b * 192 * TOK + t;
    for (int pass = 0; pass < 2; ++pass) {
        float kr[64];
        const float* src = basek + (size_t)pass * 64 * TOK;
#pragma unroll
        for (int i = 0; i < 64; ++i) kr[i] = src[(size_t)i * TOK];
        float xd = 0.f;
#pragma unroll
        for (int i = 0; i < 64; ++i) xd = fmaf(kr[i], kr[i], xd);
        xd *= 0.5f;
        float* dst = (pass == 0 ? kpT : qpT) + (size_t)b * 32 * TOK + t;
        for (int m = 0; m < 32; ++m) {
            const float* wr = wperf + m * 64;
            float a = 0.f;
#pragma unroll
            for (int i = 0; i < 64; ++i) a = fmaf(wr[i], kr[i], a);
            dst[(size_t)m * TOK] = expf(a - xd) * 0.17677669529663687f;
        }
    }
}

// ---------------------------------------------------------------------------
// kptv chunk partials (unchanged).
// ---------------------------------------------------------------------------
__global__ __launch_bounds__(256) void k_kptv(
        const float* __restrict__ kqvT, const float* __restrict__ kpT,
        float* __restrict__ kvp, float* __restrict__ skpp) {
    const int b = blockIdx.y, ch = blockIdx.x, tid = threadIdx.x;
    const int t = ch * 256 + tid;
    __shared__ float sv[256 * 65 + 256 * 36];
    float* skp = sv + 256 * 65;
    for (int dd = 0; dd < 64; ++dd)
        sv[tid * 65 + dd] = kqvT[((size_t)(b * 192 + 128 + dd)) * TOK + t];
    for (int m = 0; m < 32; ++m)
        skp[tid * 36 + m] = kpT[((size_t)(b * 32 + m)) * TOK + t];
    __syncthreads();

    const int dd = tid & 63;
    const int mg = __builtin_amdgcn_readfirstlane(tid >> 6);
    float acc[8];
#pragma unroll
    for (int j = 0; j < 8; ++j) acc[j] = 0.f;
    for (int tt = 0; tt < 256; ++tt) {
        float vv = sv[tt * 65 + dd];
        const float4* kq = (const float4*)(skp + tt * 36 + mg * 8);
        float4 a0 = kq[0], a1 = kq[1];
        acc[0] = fmaf(vv, a0.x, acc[0]);
        acc[1] = fmaf(vv, a0.y, acc[1]);
        acc[2] = fmaf(vv, a0.z, acc[2]);
        acc[3] = fmaf(vv, a0.w, acc[3]);
        acc[4] = fmaf(vv, a1.x, acc[4]);
        acc[5] = fmaf(vv, a1.y, acc[5]);
        acc[6] = fmaf(vv, a1.z, acc[6]);
        acc[7] = fmaf(vv, a1.w, acc[7]);
    }
    float* dst = kvp + (((size_t)(b * 16 + ch) * 64 + dd) * 32) + mg * 8;
#pragma unroll
    for (int j = 0; j < 8; ++j) dst[j] = acc[j];

    if (tid < 32) {
        float s = 0.f;
        for (int tt = 0; tt < 256; ++tt) s += skp[tt * 36 + tid];
        skpp[(b * 16 + ch) * 32 + tid] = s;
    }
}

// Reduce partials -> kvbf [b][64 d][32 m] bf16, sum_kp [b][32 m] fp32.
__global__ __launch_bounds__(256) void k_reduce2(
        const float* __restrict__ kvp, const float* __restrict__ skpp,
        short* __restrict__ kvbf, float* __restrict__ sum_kp) {
    int idx = blockIdx.x * 256 + threadIdx.x;
    if (idx < 65536) {
        int b = idx >> 11, rem = idx & 2047, dd = rem >> 5, m = rem & 31;
        float s = 0.f;
        for (int ch = 0; ch < 16; ++ch) s += kvp[((b * 16 + ch) * 64 + dd) * 32 + m];
        kvbf[idx] = f2bf(s);
    } else if (idx < 65536 + 1024) {
        int i = idx - 65536;
        int b = i >> 5, m = i & 31;
        float s = 0.f;
        for (int ch = 0; ch < 16; ++ch) s += skpp[(b * 16 + ch) * 32 + m];
        sum_kp[i] = s;
    }
}

// ---------------------------------------------------------------------------
// Fused: yatt = (qp@kv^T)*rD -> proj+v+b -> LN2 -> w1+GELU -> w2 + skip.
// (unchanged from round 5)
// ---------------------------------------------------------------------------
__global__ __launch_bounds__(256) void k_fuse(
        const float* __restrict__ kqvT, const float* __restrict__ qpT,
        const short* __restrict__ kvbf, const float* __restrict__ sum_kp,
        const short* __restrict__ pTbf, const float* __restrict__ proj_b,
        const float* __restrict__ g2, const float* __restrict__ b2ln,
        const short* __restrict__ w1bf, const float* __restrict__ b1,
        const short* __restrict__ w2bf, const float* __restrict__ b2,
        float* __restrict__ out) {
    const int b = blockIdx.y;
    const int t0 = blockIdx.x * 64;
    const int tid = threadIdx.x;
    const int lane = tid & 63;
    const int cl = lane & 31;
    const int g  = lane >> 5;
    const int wv = tid >> 6;
    const int wr = wv & 1;
    const int wc = wv >> 1;

    __shared__ __align__(16) char pool[29952];
    short* qpS  = (short*)(pool + 0);
    short* ytS  = (short*)(pool + 5120);
    short* xnS  = (short*)(pool + 14336);
    short* hgS  = (short*)(pool + 0);
    float* outS = (float*)(pool + 9216);
    float* red  = (float*)(pool + 26624);
    float* stat = (float*)(pool + 27648);
    float* coefS= (float*)(pool + 28672);

    if (tid < 64) {
        coefS[tid]       = proj_b[tid];
        coefS[64 + tid]  = g2[tid];
        coefS[128 + tid] = b2ln[tid];
        coefS[192 + tid] = b1[tid];
        coefS[256 + tid] = b2[tid];
    }
    {
        const int t = tid & 63, q = tid >> 6;
        const float* sk = sum_kp + b * 32;
        float dsum = 0.f;
        short8 pk;
#pragma unroll
        for (int i = 0; i < 8; ++i) {
            int m = q * 8 + i;
            float v = qpT[((size_t)(b * 32 + m)) * TOK + t0 + t];
            dsum = fmaf(v, sk[m], dsum);
            pk[i] = f2bf(v);
        }
        *(short8*)(qpS + t * 40 + q * 8) = pk;
        red[t * 4 + q] = dsum;
    }
    __syncthreads();

    const int tl = wc * 32 + cl;
    const int tg = t0 + tl;

    f32x16 acc = {0.f, 0.f, 0.f, 0.f, 0.f, 0.f, 0.f, 0.f,
                  0.f, 0.f, 0.f, 0.f, 0.f, 0.f, 0.f, 0.f};
    {
        const short* Ab = kvbf + ((size_t)(b * 64) + wr * 32 + cl) * 32;
        short8 a0 = *(const short8*)(Ab + g * 8);
        short8 a1 = *(const short8*)(Ab + 16 + g * 8);
        short8 b0 = *(const short8*)(qpS + tl * 40 + g * 8);
        short8 b1v = *(const short8*)(qpS + tl * 40 + 16 + g * 8);
        acc = __builtin_amdgcn_mfma_f32_32x32x16_bf16(a0, b0, acc, 0, 0, 0);
        acc = __builtin_amdgcn_mfma_f32_32x32x16_bf16(a1, b1v, acc, 0, 0, 0);
    }
    {
        float Dv = red[tl * 4 + 0] + red[tl * 4 + 1] + red[tl * 4 + 2] + red[tl * 4 + 3];
        float rD = 1.f / (Dv + 1e-8f);
#pragma unroll
        for (int rq = 0; rq < 4; ++rq) {
            int d0 = wr * 32 + 8 * rq + 4 * g;
            short4v p;
            p.x = f2bf(acc[rq * 4 + 0] * rD);
            p.y = f2bf(acc[rq * 4 + 1] * rD);
            p.z = f2bf(acc[rq * 4 + 2] * rD);
            p.w = f2bf(acc[rq * 4 + 3] * rD);
            *(short4v*)(ytS + tl * 72 + d0) = p;
        }
    }
    __syncthreads();

    f32x16 acc2 = {0.f, 0.f, 0.f, 0.f, 0.f, 0.f, 0.f, 0.f,
                   0.f, 0.f, 0.f, 0.f, 0.f, 0.f, 0.f, 0.f};
    {
        const short* Ap = pTbf + (wr * 32 + cl) * 64;
#pragma unroll
        for (int ks = 0; ks < 4; ++ks) {
            short8 a = *(const short8*)(Ap + ks * 16 + g * 8);
            short8 bb = *(const short8*)(ytS + tl * 72 + ks * 16 + g * 8);
            acc2 = __builtin_amdgcn_mfma_f32_32x32x16_bf16(a, bb, acc2, 0, 0, 0);
        }
    }
    float skv[16];
    {
        const float* vb = kqvT + ((size_t)(b * 192 + 128)) * TOK + tg;
#pragma unroll
        for (int reg = 0; reg < 16; ++reg) {
            int o = wr * 32 + (reg & 3) + 8 * (reg >> 2) + 4 * g;
            skv[reg] = acc2[reg] + vb[(size_t)o * TOK] + coefS[o];
        }
    }

    {
        float s1 = 0.f, s2 = 0.f;
#pragma unroll
        for (int reg = 0; reg < 16; ++reg) {
            s1 += skv[reg];
            s2 = fmaf(skv[reg], skv[reg], s2);
        }
        s1 += __shfl_xor(s1, 32, 64);
        s2 += __shfl_xor(s2, 32, 64);
        if (g == 0) {
            stat[(wr * 64 + tl) * 2 + 0] = s1;
            stat[(wr * 64 + tl) * 2 + 1] = s2;
        }
        __syncthreads();
        float S1 = s1 + stat[((wr ^ 1) * 64 + tl) * 2 + 0];
        float S2 = s2 + stat[((wr ^ 1) * 64 + tl) * 2 + 1];
        float mu = S1 * (1.f / 64.f);
        float var = S2 * (1.f / 64.f) - mu * mu;
        float rs = rsqrtf(fmaxf(var, 0.f) + 1e-5f);
#pragma unroll
        for (int rq = 0; rq < 4; ++rq) {
            int o0 = wr * 32 + 8 * rq + 4 * g;
            short4v p;
#pragma unroll
            for (int j = 0; j < 4; ++j) {
                int o = o0 + j;
                float xn = (skv[rq * 4 + j] - mu) * rs * coefS[64 + o] + coefS[128 + o];
                ((short*)&p)[j] = f2bf(xn);
            }
            *(short4v*)(xnS + tl * 72 + o0) = p;
        }
    }
    __syncthreads();

    f32x16 acc3 = {0.f, 0.f, 0.f, 0.f, 0.f, 0.f, 0.f, 0.f,
                   0.f, 0.f, 0.f, 0.f, 0.f, 0.f, 0.f, 0.f};
    {
        const short* A1 = w1bf + (wr * 32 + cl) * 64;
#pragma unroll
        for (int ks = 0; ks < 4; ++ks) {
            short8 a = *(const short8*)(A1 + ks * 16 + g * 8);
            short8 bb = *(const short8*)(xnS + tl * 72 + ks * 16 + g * 8);
            acc3 = __builtin_amdgcn_mfma_f32_32x32x16_bf16(a, bb, acc3, 0, 0, 0);
        }
    }
    __syncthreads();
    {
#pragma unroll
        for (int rq = 0; rq < 4; ++rq) {
            int i0 = wr * 32 + 8 * rq + 4 * g;
            short4v p;
#pragma unroll
            for (int j = 0; j < 4; ++j) {
                int i = i0 + j;
                float hgv = gelu_exact(acc3[rq * 4 + j] + coefS[192 + i]);
                ((short*)&p)[j] = f2bf(hgv);
            }
            *(short4v*)(hgS + tl * 72 + i0) = p;
        }
    }
    __syncthreads();

    f32x16 acc4 = {0.f, 0.f, 0.f, 0.f, 0.f, 0.f, 0.f, 0.f,
                   0.f, 0.f, 0.f, 0.f, 0.f, 0.f, 0.f, 0.f};
    {
        const short* A2 = w2bf + (wr * 32 + cl) * 64;
#pragma unroll
        for (int ks = 0; ks < 4; ++ks) {
            short8 a = *(const short8*)(A2 + ks * 16 + g * 8);
            short8 bb = *(const short8*)(hgS + tl * 72 + ks * 16 + g * 8);
            acc4 = __builtin_amdgcn_mfma_f32_32x32x16_bf16(a, bb, acc4, 0, 0, 0);
        }
    }
    {
#pragma unroll
        for (int rq = 0; rq < 4; ++rq) {
            int o0 = wr * 32 + 8 * rq + 4 * g;
            float4 f;
#pragma unroll
            for (int j = 0; j < 4; ++j) {
                int o = o0 + j;
                ((float*)&f)[j] = skv[rq * 4 + j] + acc4[rq * 4 + j] + coefS[256 + o];
            }
            *(float4*)(outS + tl * 68 + o0) = f;
        }
    }
    __syncthreads();

    {
        const int tt = tid >> 2, qq = tid & 3;
        float* ob = out + ((size_t)(b * TOK) + t0 + tt) * 64;
#pragma unroll
        for (int it = 0; it < 4; ++it) {
            *(float4*)(ob + it * 16 + qq * 4) =
                *(float4*)(outS + tt * 68 + it * 16 + qq * 4);
        }
    }
}

// ---------------------------------------------------------------------------
extern "C" void kernel_launch(void* const* d_in, const int* in_sizes, int n_in,
                              void* d_out, int out_size, void* d_ws, size_t ws_size,
                              hipStream_t stream) {
    const float* x      = (const float*)d_in[0];
    const float* conv_w = (const float*)d_in[1];
    const float* conv_b = (const float*)d_in[2];
    const float* ln1_g  = (const float*)d_in[3];
    const float* ln1_b  = (const float*)d_in[4];
    const float* kqv_w  = (const float*)d_in[5];
    const float* kqv_b  = (const float*)d_in[6];
    const float* proj_w = (const float*)d_in[7];
    const float* proj_b = (const float*)d_in[8];
    const float* w_perf = (const float*)d_in[9];
    const float* ln2_g  = (const float*)d_in[10];
    const float* ln2_b  = (const float*)d_in[11];
    const float* mlp_w1 = (const float*)d_in[12];
    const float* mlp_b1 = (const float*)d_in[13];
    const float* mlp_w2 = (const float*)d_in[14];
    const float* mlp_b2 = (const float*)d_in[15];

    float* ws = (float*)d_ws;
    // static weights / small buffers
    short* w2c    = (short*)ws;                 // 110592 sh
    short* kwbf   = (short*)(ws + 55296);       // 36864 sh
    short* pTbf   = (short*)(ws + 73728);       // 4096 sh
    short* w1bf   = (short*)(ws + 75776);       // 4096 sh
    short* w2bf   = (short*)(ws + 77824);       // 4096 sh
    float* sum_kp = ws + 79872;                 // 1024 f
    short* kvbf   = (short*)(ws + 80896);       // 65536 sh -> ends 113664
    // region A: tokens bf16, later overlaid by qpT/kpT/kvp (disjoint lifetimes)
    short* tokens = (short*)(ws + 114688);      // 25165824 sh (12.58M f)
    float* qpT    = ws + 114688;                // 4194304 f (after tokens dead)
    float* kpT    = ws + 114688 + 4194304;      // 4194304 f
    float* skpp   = ws + 114688 + 8388608;      // 16384 f
    float* kvp    = ws + 114688 + 8404992;      // 1048576 f
    // region B: xbf then kqvT (sequential lifetimes)
    float* regB   = ws + 114688 + 25165824;
    short* xbf    = (short*)regB;               // 33554432 sh
    float* kqvT   = regB;                       // 25165824 f
    float* outp   = (float*)d_out;

    k_prep   <<<624, 256, 0, stream>>>(conv_w, kqv_w, proj_w, mlp_w1, mlp_w2,
                                       w2c, kwbf, pTbf, w1bf, w2bf);
    k_cvt    <<<16384, 256, 0, stream>>>(x, xbf);
    k_conv3  <<<dim3(192, 32), 256, 0, stream>>>(xbf, w2c, conv_b, tokens);
    k_lnkqv_mfma<<<dim3(64, 32), 256, 0, stream>>>(tokens, ln1_g, ln1_b, kwbf, kqv_b, kqvT);
    k_perf   <<<dim3(16, 32), 256, 0, stream>>>(kqvT, w_perf, kpT, qpT);
    k_kptv   <<<dim3(16, 32), 256, 0, stream>>>(kqvT, kpT, kvp, skpp);
    k_reduce2<<<260, 256, 0, stream>>>(kvp, skpp, kvbf, sum_kp);
    k_fuse   <<<dim3(64, 32), 256, 0, stream>>>(kqvT, qpT, kvbf, sum_kp,
                                                pTbf, proj_b, ln2_g, ln2_b,
                                                w1bf, mlp_b1, w2bf, mlp_b2, outp);
}

// Round 7
// 273.082 us; speedup vs baseline: 12.9313x; 1.3220x over previous
//
#include <hip/hip_runtime.h>

// ---------------------------------------------------------------------------
// BlockRC2: PRM (3 dilated stride-2 convs + GELU) -> LN1 -> kqv ->
// performer attention -> proj+skip -> LN2 -> MLP -> skip.
// Round 7: MFMA-native weight layouts. All fragment loads of weights were
// lane-scattered (stride 128-384B across lanes -> ~64 cache lines per
// instruction, TA-serialized; why conv stuck at ~175-225us across 3 rounds).
// Weights now stored [k-chunk][g][col][8k]: fragment loads are two contiguous
// 512B segments. Applied to conv/kqv/proj/mlp weights + kv matrix.
// ---------------------------------------------------------------------------

#define TOK 4096
#define NB  32

typedef __attribute__((ext_vector_type(8)))  short short8;
typedef __attribute__((ext_vector_type(4)))  short short4v;
typedef __attribute__((ext_vector_type(16))) float f32x16;

__device__ __forceinline__ float gelu_exact(float v) {
    return 0.5f * v * (1.f + erff(v * 0.70710678118654752f));
}

__device__ __forceinline__ short f2bf(float f) {
    union { float f; unsigned u; } x; x.f = f;
    unsigned r = (x.u + 0x7FFFu + ((x.u >> 16) & 1u)) >> 16;
    return (short)r;
}

__device__ __forceinline__ float bf2f(short s) {
    union { unsigned u; float f; } x;
    x.u = ((unsigned)(unsigned short)s) << 16;
    return x.f;
}

// ---------------------------------------------------------------------------
// Prep. MFMA-native layouts: frag element for lane (cl,g), reg j is
// W[col=cl][k = ks*16 + g*8 + j]  ->  stored at ((ks*2+g)*NCOL + col)*8 + j.
// ---------------------------------------------------------------------------
__global__ __launch_bounds__(256) void k_prep(
        const float* __restrict__ cw, const float* __restrict__ kw,
        const float* __restrict__ pw, const float* __restrict__ w1,
        const float* __restrict__ w2m,
        short* __restrict__ w2c, short* __restrict__ kwbf,
        short* __restrict__ pTbf, short* __restrict__ w1bf,
        short* __restrict__ w2bf) {
    int idx = blockIdx.x * 256 + threadIdx.x;
    if (idx < 110592) {
        int c = idx & 63;
        int t = idx >> 6;
        int e = t & 63;
        int tap = t >> 6;
        int kwi = tap % 3, t2 = tap / 3;
        int r = t2 % 3, brr = t2 / 3;
        float v = cw[(((brr * 64 + e) * 64 + c) * 3 + r) * 3 + kwi];
        int dst = ((((brr * 9 + r * 3 + kwi) * 4 + (c >> 4)) * 2 + ((c >> 3) & 1)) * 64 + e) * 8 + (c & 7);
        w2c[dst] = f2bf(v);
    } else if (idx < 147456) {
        int i2 = idx - 110592;
        int o = i2 / 192, i = i2 % 192;
        int dst = (((i >> 4) * 2 + ((i >> 3) & 1)) * 192 + o) * 8 + (i & 7);
        kwbf[dst] = f2bf(kw[i * 192 + o]);
    } else if (idx < 151552) {
        int i2 = idx - 147456;
        int o = i2 >> 6, d = i2 & 63;
        int dst = (((d >> 4) * 2 + ((d >> 3) & 1)) * 64 + o) * 8 + (d & 7);
        pTbf[dst] = f2bf(pw[d * 64 + o]);
    } else if (idx < 155648) {
        int i2 = idx - 151552;
        int i = i2 >> 6, jd = i2 & 63;
        int dst = (((jd >> 4) * 2 + ((jd >> 3) & 1)) * 64 + i) * 8 + (jd & 7);
        w1bf[dst] = f2bf(w1[jd * 64 + i]);
    } else if (idx < 159744) {
        int i2 = idx - 155648;
        int o = i2 >> 6, i = i2 & 63;
        int dst = (((i >> 4) * 2 + ((i >> 3) & 1)) * 64 + o) * 8 + (i & 7);
        w2bf[dst] = f2bf(w2m[i * 64 + o]);
    }
}

// ---------------------------------------------------------------------------
// x fp32 [b][h*128+w][c] -> xbf bf16 (same layout).
// ---------------------------------------------------------------------------
__global__ __launch_bounds__(256) void k_cvt(
        const float* __restrict__ x, short* __restrict__ xbf) {
    size_t i0 = ((size_t)blockIdx.x * 256 + threadIdx.x) * 8;
    float4 a = *(const float4*)(x + i0);
    float4 b = *(const float4*)(x + i0 + 4);
    short8 p;
    p[0] = f2bf(a.x); p[1] = f2bf(a.y); p[2] = f2bf(a.z); p[3] = f2bf(a.w);
    p[4] = f2bf(b.x); p[5] = f2bf(b.y); p[6] = f2bf(b.z); p[7] = f2bf(b.w);
    *(short8*)(xbf + i0) = p;
}

// ---------------------------------------------------------------------------
// Conv via MFMA. Block = (oh, br) x b, 256 thr = 4 waves.
// A: LDS sA[r][iw4][c] bf16 with write-side XOR swizzle ((iw4>>1)&7)<<4.
// B: w2c MFMA-native from L1 (coalesced 512B segments).
// ---------------------------------------------------------------------------
__global__ __launch_bounds__(256) void k_conv3(
        const short* __restrict__ xbf, const short* __restrict__ w2c,
        const float* __restrict__ cb, short* __restrict__ tokens) {
    const int bx = blockIdx.x;
    const int oh = bx / 3;
    const int br = bx - oh * 3;
    const int b  = blockIdx.y;
    const int d  = br + 1;
    const int tid = threadIdx.x;
    const int lane = tid & 63;
    const int wv = __builtin_amdgcn_readfirstlane(tid >> 6);
    const int cl = lane & 31;
    const int g  = lane >> 5;
    const int wm = wv & 1;
    const int wn = wv >> 1;

    __shared__ short sA[3 * 136 * 64];   // 52224 B

    {
        short8 z = {0, 0, 0, 0, 0, 0, 0, 0};
        short8* p = (short8*)sA;
        for (int i = tid; i < 3264; i += 256) p[i] = z;
    }
    __syncthreads();

    const int sub = lane & 7;
    const int rowoff = lane >> 3;
    for (int it = 0; it < 12; ++it) {
        const int i = wv * 12 + it;
        const int r = i >> 4;
        const int ch = i & 15;
        const int ih = 2 * oh + (r - 1) * d;
        if ((unsigned)ih < 128u) {
            const int iw4 = 4 + ch * 8 + rowoff;
            short8 v = *(const short8*)(xbf + (((size_t)(b * 128 + ih)) << 13)
                                        + (iw4 - 4) * 64 + sub * 8);
            char* dst = (char*)sA + (r * 136 + iw4) * 128
                      + ((sub * 16) ^ (((iw4 >> 1) & 7) << 4));
            *(short8*)dst = v;
        }
    }
    __syncthreads();

    f32x16 acc = {0.f, 0.f, 0.f, 0.f, 0.f, 0.f, 0.f, 0.f,
                  0.f, 0.f, 0.f, 0.f, 0.f, 0.f, 0.f, 0.f};
    const short* wbr = w2c + br * 9 * 4096;
    const int ow = wm * 32 + cl;
    const int ecol = wn * 32 + cl;

    for (int r = 0; r < 3; ++r) {
        const int ih = 2 * oh + (r - 1) * d;
        if ((unsigned)ih < 128u) {
#pragma unroll
            for (int kwi = 0; kwi < 3; ++kwi) {
                const int iw4 = 2 * ow + (kwi - 1) * d + 4;
                const char* arow = (const char*)sA + (r * 136 + iw4) * 128;
                const int swz = ((iw4 >> 1) & 7) << 4;
                const short* wt = wbr + (r * 3 + kwi) * 4096;
#pragma unroll
                for (int ks = 0; ks < 4; ++ks) {
                    short8 a = *(const short8*)(arow + ((ks * 32 + g * 16) ^ swz));
                    short8 bf = *(const short8*)(wt + ((ks * 2 + g) * 64 + ecol) * 8);
                    acc = __builtin_amdgcn_mfma_f32_32x32x16_bf16(a, bf, acc, 0, 0, 0);
                }
            }
        }
    }

    const int eG = br * 64 + wn * 32 + cl;
    const float bias = cb[eG];
    short* outb = tokens + ((size_t)(b * TOK + oh * 64 + wm * 32)) * 192 + eG;
#pragma unroll
    for (int reg = 0; reg < 16; ++reg) {
        int owl = (reg & 3) + 8 * (reg >> 2) + 4 * g;
        outb[(size_t)owl * 192] = f2bf(gelu_exact(acc[reg] + bias));
    }
}

// ---------------------------------------------------------------------------
// LN1 + kqv via MFMA; tokens bf16 in; weights MFMA-native.
// ---------------------------------------------------------------------------
__global__ __launch_bounds__(256) void k_lnkqv_mfma(
        const short* __restrict__ tokens, const float* __restrict__ g,
        const float* __restrict__ be, const short* __restrict__ wbf,
        const float* __restrict__ bias, float* __restrict__ kqvT) {
    const int b = blockIdx.y;
    const int t0 = blockIdx.x * 64;
    const int tid = threadIdx.x;

    __shared__ short sB[64 * 192];
    __shared__ float red[64 * 8];

    const int r = tid >> 2, q = tid & 3;
    const short* rowp = tokens + ((size_t)(b * TOK + t0 + r)) * 192 + q * 48;
    float v[48];
    float s1 = 0.f, s2 = 0.f;
#pragma unroll
    for (int i = 0; i < 6; ++i) {
        short8 x8 = *(const short8*)(rowp + i * 8);
#pragma unroll
        for (int j = 0; j < 8; ++j) {
            float f = bf2f(x8[j]);
            v[i * 8 + j] = f;
            s1 += f;
            s2 = fmaf(f, f, s2);
        }
    }
    red[r * 8 + q] = s1;
    red[r * 8 + 4 + q] = s2;
    __syncthreads();
    const float m1 = red[r * 8 + 0] + red[r * 8 + 1] + red[r * 8 + 2] + red[r * 8 + 3];
    const float m2 = red[r * 8 + 4] + red[r * 8 + 5] + red[r * 8 + 6] + red[r * 8 + 7];
    const float mu = m1 * (1.f / 192.f);
    const float var = m2 * (1.f / 192.f) - mu * mu;
    const float rs = rsqrtf(fmaxf(var, 0.f) + 1e-5f);
    const float4* g4 = (const float4*)(g + q * 48);
    const float4* b4 = (const float4*)(be + q * 48);
    char* rowB = (char*)sB + r * 384;
    const int swz = (r & 7) << 4;
#pragma unroll
    for (int i = 0; i < 12; ++i) {
        float4 gg = g4[i], bb = b4[i];
        short4v pk;
        pk.x = f2bf((v[4 * i + 0] - mu) * rs * gg.x + bb.x);
        pk.y = f2bf((v[4 * i + 1] - mu) * rs * gg.y + bb.y);
        pk.z = f2bf((v[4 * i + 2] - mu) * rs * gg.z + bb.z);
        pk.w = f2bf((v[4 * i + 3] - mu) * rs * gg.w + bb.w);
        *(short4v*)(rowB + (((q * 48 + i * 4) * 2) ^ swz)) = pk;
    }
    __syncthreads();

    const int lane = tid & 63;
    const int wv = tid >> 6;
    const int tt = wv & 1;
    const int wo = wv >> 1;
    const int colL = lane & 31;
    const int gq = lane >> 5;

    f32x16 acc0 = {0.f, 0.f, 0.f, 0.f, 0.f, 0.f, 0.f, 0.f,
                   0.f, 0.f, 0.f, 0.f, 0.f, 0.f, 0.f, 0.f};
    f32x16 acc1 = acc0, acc2 = acc0;
    const char* bbase = (const char*)sB + (tt * 32 + colL) * 384;
    const int bswz = ((tt * 32 + colL) & 7) << 4;
    const int ocol = wo * 32 + colL;

    for (int kk = 0; kk < 12; ++kk) {
        short8 bf = *(const short8*)(bbase + (((kk * 16 + gq * 8) * 2) ^ bswz));
        const short* ak = wbf + ((kk * 2 + gq) * 192 + ocol) * 8;
        short8 a0 = *(const short8*)(ak);
        short8 a1 = *(const short8*)(ak + 64 * 8);
        short8 a2 = *(const short8*)(ak + 128 * 8);
        acc0 = __builtin_amdgcn_mfma_f32_32x32x16_bf16(a0, bf, acc0, 0, 0, 0);
        acc1 = __builtin_amdgcn_mfma_f32_32x32x16_bf16(a1, bf, acc1, 0, 0, 0);
        acc2 = __builtin_amdgcn_mfma_f32_32x32x16_bf16(a2, bf, acc2, 0, 0, 0);
    }

    const int tglob = t0 + tt * 32 + colL;
    float* outb = kqvT + (size_t)b * 192 * TOK + tglob;
#pragma unroll
    for (int j = 0; j < 3; ++j) {
        const int obase = (wo + 2 * j) * 32;
        const f32x16 ac = (j == 0 ? acc0 : j == 1 ? acc1 : acc2);
#pragma unroll
        for (int reg = 0; reg < 16; ++reg) {
            int orow = (reg & 3) + 8 * (reg >> 2) + 4 * gq;
            outb[(size_t)(obase + orow) * TOK] = ac[reg] + bias[obase + orow];
        }
    }
}

// ---------------------------------------------------------------------------
// Performer features (unchanged).
// ---------------------------------------------------------------------------
__global__ __launch_bounds__(256) void k_perf(
        const float* __restrict__ kqvT, const float* __restrict__ wperf,
        float* __restrict__ kpT, float* __restrict__ qpT) {
    const int b = blockIdx.y;
    const int t = blockIdx.x * 256 + threadIdx.x;
    const float* basek = kqvT + (size_t)b * 192 * TOK + t;
    for (int pass = 0; pass < 2; ++pass) {
        float kr[64];
        const float* src = basek + (size_t)pass * 64 * TOK;
#pragma unroll
        for (int i = 0; i < 64; ++i) kr[i] = src[(size_t)i * TOK];
        float xd = 0.f;
#pragma unroll
        for (int i = 0; i < 64; ++i) xd = fmaf(kr[i], kr[i], xd);
        xd *= 0.5f;
        float* dst = (pass == 0 ? kpT : qpT) + (size_t)b * 32 * TOK + t;
        for (int m = 0; m < 32; ++m) {
            const float* wr = wperf + m * 64;
            float a = 0.f;
#pragma unroll
            for (int i = 0; i < 64; ++i) a = fmaf(wr[i], kr[i], a);
            dst[(size_t)m * TOK] = expf(a - xd) * 0.17677669529663687f;
        }
    }
}

// ---------------------------------------------------------------------------
// kptv chunk partials (unchanged).
// ---------------------------------------------------------------------------
__global__ __launch_bounds__(256) void k_kptv(
        const float* __restrict__ kqvT, const float* __restrict__ kpT,
        float* __restrict__ kvp, float* __restrict__ skpp) {
    const int b = blockIdx.y, ch = blockIdx.x, tid = threadIdx.x;
    const int t = ch * 256 + tid;
    __shared__ float sv[256 * 65 + 256 * 36];
    float* skp = sv + 256 * 65;
    for (int dd = 0; dd < 64; ++dd)
        sv[tid * 65 + dd] = kqvT[((size_t)(b * 192 + 128 + dd)) * TOK + t];
    for (int m = 0; m < 32; ++m)
        skp[tid * 36 + m] = kpT[((size_t)(b * 32 + m)) * TOK + t];
    __syncthreads();

    const int dd = tid & 63;
    const int mg = __builtin_amdgcn_readfirstlane(tid >> 6);
    float acc[8];
#pragma unroll
    for (int j = 0; j < 8; ++j) acc[j] = 0.f;
    for (int tt = 0; tt < 256; ++tt) {
        float vv = sv[tt * 65 + dd];
        const float4* kq = (const float4*)(skp + tt * 36 + mg * 8);
        float4 a0 = kq[0], a1 = kq[1];
        acc[0] = fmaf(vv, a0.x, acc[0]);
        acc[1] = fmaf(vv, a0.y, acc[1]);
        acc[2] = fmaf(vv, a0.z, acc[2]);
        acc[3] = fmaf(vv, a0.w, acc[3]);
        acc[4] = fmaf(vv, a1.x, acc[4]);
        acc[5] = fmaf(vv, a1.y, acc[5]);
        acc[6] = fmaf(vv, a1.z, acc[6]);
        acc[7] = fmaf(vv, a1.w, acc[7]);
    }
    float* dst = kvp + (((size_t)(b * 16 + ch) * 64 + dd) * 32) + mg * 8;
#pragma unroll
    for (int j = 0; j < 8; ++j) dst[j] = acc[j];

    if (tid < 32) {
        float s = 0.f;
        for (int tt = 0; tt < 256; ++tt) s += skp[tt * 36 + tid];
        skpp[(b * 16 + ch) * 32 + tid] = s;
    }
}

// Reduce partials -> kvbf MFMA-native [b][ms][g][d][8m] bf16, sum_kp fp32.
__global__ __launch_bounds__(256) void k_reduce2(
        const float* __restrict__ kvp, const float* __restrict__ skpp,
        short* __restrict__ kvbf, float* __restrict__ sum_kp) {
    int idx = blockIdx.x * 256 + threadIdx.x;
    if (idx < 65536) {
        int b = idx >> 11, rem = idx & 2047, dd = rem >> 5, m = rem & 31;
        float s = 0.f;
        for (int ch = 0; ch < 16; ++ch) s += kvp[((b * 16 + ch) * 64 + dd) * 32 + m];
        int dst = (((b * 2 + (m >> 4)) * 2 + ((m >> 3) & 1)) * 64 + dd) * 8 + (m & 7);
        kvbf[dst] = f2bf(s);
    } else if (idx < 65536 + 1024) {
        int i = idx - 65536;
        int b = i >> 5, m = i & 31;
        float s = 0.f;
        for (int ch = 0; ch < 16; ++ch) s += skpp[(b * 16 + ch) * 32 + m];
        sum_kp[i] = s;
    }
}

// ---------------------------------------------------------------------------
// Fused: yatt = (qp@kv^T)*rD -> proj+v+b -> LN2 -> w1+GELU -> w2 + skip.
// Weights + kv MFMA-native (coalesced fragment loads).
// ---------------------------------------------------------------------------
__global__ __launch_bounds__(256) void k_fuse(
        const float* __restrict__ kqvT, const float* __restrict__ qpT,
        const short* __restrict__ kvbf, const float* __restrict__ sum_kp,
        const short* __restrict__ pTbf, const float* __restrict__ proj_b,
        const float* __restrict__ g2, const float* __restrict__ b2ln,
        const short* __restrict__ w1bf, const float* __restrict__ b1,
        const short* __restrict__ w2bf, const float* __restrict__ b2,
        float* __restrict__ out) {
    const int b = blockIdx.y;
    const int t0 = blockIdx.x * 64;
    const int tid = threadIdx.x;
    const int lane = tid & 63;
    const int cl = lane & 31;
    const int g  = lane >> 5;
    const int wv = tid >> 6;
    const int wr = wv & 1;
    const int wc = wv >> 1;

    __shared__ __align__(16) char pool[29952];
    short* qpS  = (short*)(pool + 0);
    short* ytS  = (short*)(pool + 5120);
    short* xnS  = (short*)(pool + 14336);
    short* hgS  = (short*)(pool + 0);
    float* outS = (float*)(pool + 9216);
    float* red  = (float*)(pool + 26624);
    float* stat = (float*)(pool + 27648);
    float* coefS= (float*)(pool + 28672);

    if (tid < 64) {
        coefS[tid]       = proj_b[tid];
        coefS[64 + tid]  = g2[tid];
        coefS[128 + tid] = b2ln[tid];
        coefS[192 + tid] = b1[tid];
        coefS[256 + tid] = b2[tid];
    }
    {
        const int t = tid & 63, q = tid >> 6;
        const float* sk = sum_kp + b * 32;
        float dsum = 0.f;
        short8 pk;
#pragma unroll
        for (int i = 0; i < 8; ++i) {
            int m = q * 8 + i;
            float v = qpT[((size_t)(b * 32 + m)) * TOK + t0 + t];
            dsum = fmaf(v, sk[m], dsum);
            pk[i] = f2bf(v);
        }
        *(short8*)(qpS + t * 40 + q * 8) = pk;
        red[t * 4 + q] = dsum;
    }
    __syncthreads();

    const int tl = wc * 32 + cl;
    const int tg = t0 + tl;
    const int rcol = wr * 32 + cl;

    f32x16 acc = {0.f, 0.f, 0.f, 0.f, 0.f, 0.f, 0.f, 0.f,
                  0.f, 0.f, 0.f, 0.f, 0.f, 0.f, 0.f, 0.f};
    {
        const short* Ab = kvbf + (size_t)b * 2048;
        short8 a0 = *(const short8*)(Ab + (g * 64 + rcol) * 8);
        short8 a1 = *(const short8*)(Ab + ((2 + g) * 64 + rcol) * 8);
        short8 b0 = *(const short8*)(qpS + tl * 40 + g * 8);
        short8 b1v = *(const short8*)(qpS + tl * 40 + 16 + g * 8);
        acc = __builtin_amdgcn_mfma_f32_32x32x16_bf16(a0, b0, acc, 0, 0, 0);
        acc = __builtin_amdgcn_mfma_f32_32x32x16_bf16(a1, b1v, acc, 0, 0, 0);
    }
    {
        float Dv = red[tl * 4 + 0] + red[tl * 4 + 1] + red[tl * 4 + 2] + red[tl * 4 + 3];
        float rD = 1.f / (Dv + 1e-8f);
#pragma unroll
        for (int rq = 0; rq < 4; ++rq) {
            int d0 = wr * 32 + 8 * rq + 4 * g;
            short4v p;
            p.x = f2bf(acc[rq * 4 + 0] * rD);
            p.y = f2bf(acc[rq * 4 + 1] * rD);
            p.z = f2bf(acc[rq * 4 + 2] * rD);
            p.w = f2bf(acc[rq * 4 + 3] * rD);
            *(short4v*)(ytS + tl * 72 + d0) = p;
        }
    }
    __syncthreads();

    f32x16 acc2 = {0.f, 0.f, 0.f, 0.f, 0.f, 0.f, 0.f, 0.f,
                   0.f, 0.f, 0.f, 0.f, 0.f, 0.f, 0.f, 0.f};
    {
#pragma unroll
        for (int ks = 0; ks < 4; ++ks) {
            short8 a = *(const short8*)(pTbf + ((ks * 2 + g) * 64 + rcol) * 8);
            short8 bb = *(const short8*)(ytS + tl * 72 + ks * 16 + g * 8);
            acc2 = __builtin_amdgcn_mfma_f32_32x32x16_bf16(a, bb, acc2, 0, 0, 0);
        }
    }
    float skv[16];
    {
        const float* vb = kqvT + ((size_t)(b * 192 + 128)) * TOK + tg;
#pragma unroll
        for (int reg = 0; reg < 16; ++reg) {
            int o = wr * 32 + (reg & 3) + 8 * (reg >> 2) + 4 * g;
            skv[reg] = acc2[reg] + vb[(size_t)o * TOK] + coefS[o];
        }
    }

    {
        float s1 = 0.f, s2 = 0.f;
#pragma unroll
        for (int reg = 0; reg < 16; ++reg) {
            s1 += skv[reg];
            s2 = fmaf(skv[reg], skv[reg], s2);
        }
        s1 += __shfl_xor(s1, 32, 64);
        s2 += __shfl_xor(s2, 32, 64);
        if (g == 0) {
            stat[(wr * 64 + tl) * 2 + 0] = s1;
            stat[(wr * 64 + tl) * 2 + 1] = s2;
        }
        __syncthreads();
        float S1 = s1 + stat[((wr ^ 1) * 64 + tl) * 2 + 0];
        float S2 = s2 + stat[((wr ^ 1) * 64 + tl) * 2 + 1];
        float mu = S1 * (1.f / 64.f);
        float var = S2 * (1.f / 64.f) - mu * mu;
        float rs = rsqrtf(fmaxf(var, 0.f) + 1e-5f);
#pragma unroll
        for (int rq = 0; rq < 4; ++rq) {
            int o0 = wr * 32 + 8 * rq + 4 * g;
            short4v p;
#pragma unroll
            for (int j = 0; j < 4; ++j) {
                int o = o0 + j;
                float xn = (skv[rq * 4 + j] - mu) * rs * coefS[64 + o] + coefS[128 + o];
                ((short*)&p)[j] = f2bf(xn);
            }
            *(short4v*)(xnS + tl * 72 + o0) = p;
        }
    }
    __syncthreads();

    f32x16 acc3 = {0.f, 0.f, 0.f, 0.f, 0.f, 0.f, 0.f, 0.f,
                   0.f, 0.f, 0.f, 0.f, 0.f, 0.f, 0.f, 0.f};
    {
#pragma unroll
        for (int ks = 0; ks < 4; ++ks) {
            short8 a = *(const short8*)(w1bf + ((ks * 2 + g) * 64 + rcol) * 8);
            short8 bb = *(const short8*)(xnS + tl * 72 + ks * 16 + g * 8);
            acc3 = __builtin_amdgcn_mfma_f32_32x32x16_bf16(a, bb, acc3, 0, 0, 0);
        }
    }
    __syncthreads();
    {
#pragma unroll
        for (int rq = 0; rq < 4; ++rq) {
            int i0 = wr * 32 + 8 * rq + 4 * g;
            short4v p;
#pragma unroll
            for (int j = 0; j < 4; ++j) {
                int i = i0 + j;
                float hgv = gelu_exact(acc3[rq * 4 + j] + coefS[192 + i]);
                ((short*)&p)[j] = f2bf(hgv);
            }
            *(short4v*)(hgS + tl * 72 + i0) = p;
        }
    }
    __syncthreads();

    f32x16 acc4 = {0.f, 0.f, 0.f, 0.f, 0.f, 0.f, 0.f, 0.f,
                   0.f, 0.f, 0.f, 0.f, 0.f, 0.f, 0.f, 0.f};
    {
#pragma unroll
        for (int ks = 0; ks < 4; ++ks) {
            short8 a = *(const short8*)(w2bf + ((ks * 2 + g) * 64 + rcol) * 8);
            short8 bb = *(const short8*)(hgS + tl * 72 + ks * 16 + g * 8);
            acc4 = __builtin_amdgcn_mfma_f32_32x32x16_bf16(a, bb, acc4, 0, 0, 0);
        }
    }
    {
#pragma unroll
        for (int rq = 0; rq < 4; ++rq) {
            int o0 = wr * 32 + 8 * rq + 4 * g;
            float4 f;
#pragma unroll
            for (int j = 0; j < 4; ++j) {
                int o = o0 + j;
                ((float*)&f)[j] = skv[rq * 4 + j] + acc4[rq * 4 + j] + coefS[256 + o];
            }
            *(float4*)(outS + tl * 68 + o0) = f;
        }
    }
    __syncthreads();

    {
        const int tt = tid >> 2, qq = tid & 3;
        float* ob = out + ((size_t)(b * TOK) + t0 + tt) * 64;
#pragma unroll
        for (int it = 0; it < 4; ++it) {
            *(float4*)(ob + it * 16 + qq * 4) =
                *(float4*)(outS + tt * 68 + it * 16 + qq * 4);
        }
    }
}

// ---------------------------------------------------------------------------
extern "C" void kernel_launch(void* const* d_in, const int* in_sizes, int n_in,
                              void* d_out, int out_size, void* d_ws, size_t ws_size,
                              hipStream_t stream) {
    const float* x      = (const float*)d_in[0];
    const float* conv_w = (const float*)d_in[1];
    const float* conv_b = (const float*)d_in[2];
    const float* ln1_g  = (const float*)d_in[3];
    const float* ln1_b  = (const float*)d_in[4];
    const float* kqv_w  = (const float*)d_in[5];
    const float* kqv_b  = (const float*)d_in[6];
    const float* proj_w = (const float*)d_in[7];
    const float* proj_b = (const float*)d_in[8];
    const float* w_perf = (const float*)d_in[9];
    const float* ln2_g  = (const float*)d_in[10];
    const float* ln2_b  = (const float*)d_in[11];
    const float* mlp_w1 = (const float*)d_in[12];
    const float* mlp_b1 = (const float*)d_in[13];
    const float* mlp_w2 = (const float*)d_in[14];
    const float* mlp_b2 = (const float*)d_in[15];

    float* ws = (float*)d_ws;
    short* w2c    = (short*)ws;                 // 110592 sh
    short* kwbf   = (short*)(ws + 55296);       // 36864 sh
    short* pTbf   = (short*)(ws + 73728);       // 4096 sh
    short* w1bf   = (short*)(ws + 75776);       // 4096 sh
    short* w2bf   = (short*)(ws + 77824);       // 4096 sh
    float* sum_kp = ws + 79872;                 // 1024 f
    short* kvbf   = (short*)(ws + 80896);       // 65536 sh
    short* tokens = (short*)(ws + 114688);      // 25165824 sh
    float* qpT    = ws + 114688;                // overlay after tokens dead
    float* kpT    = ws + 114688 + 4194304;
    float* skpp   = ws + 114688 + 8388608;
    float* kvp    = ws + 114688 + 8404992;
    float* regB   = ws + 114688 + 25165824;
    short* xbf    = (short*)regB;
    float* kqvT   = regB;
    float* outp   = (float*)d_out;

    k_prep   <<<624, 256, 0, stream>>>(conv_w, kqv_w, proj_w, mlp_w1, mlp_w2,
                                       w2c, kwbf, pTbf, w1bf, w2bf);
    k_cvt    <<<16384, 256, 0, stream>>>(x, xbf);
    k_conv3  <<<dim3(192, 32), 256, 0, stream>>>(xbf, w2c, conv_b, tokens);
    k_lnkqv_mfma<<<dim3(64, 32), 256, 0, stream>>>(tokens, ln1_g, ln1_b, kwbf, kqv_b, kqvT);
    k_perf   <<<dim3(16, 32), 256, 0, stream>>>(kqvT, w_perf, kpT, qpT);
    k_kptv   <<<dim3(16, 32), 256, 0, stream>>>(kqvT, kpT, kvp, skpp);
    k_reduce2<<<260, 256, 0, stream>>>(kvp, skpp, kvbf, sum_kp);
    k_fuse   <<<dim3(64, 32), 256, 0, stream>>>(kqvT, qpT, kvbf, sum_kp,
                                                pTbf, proj_b, ln2_g, ln2_b,
                                                w1bf, mlp_b1, w2bf, mlp_b2, outp);
}

// Round 8
// 259.352 us; speedup vs baseline: 13.6159x; 1.0529x over previous
//
#include <hip/hip_runtime.h>

// ---------------------------------------------------------------------------
// BlockRC2: PRM (3 dilated stride-2 convs + GELU) -> LN1 -> kqv ->
// performer attention -> proj+skip -> LN2 -> MLP -> skip.
// Round 8: (1) k_cvt eliminated -- conv stages fp32 x from L3 and converts
// in-register; (2) erff GELU (~30 VALU ops) -> sigmoid-form tanh GELU
// (~7 ops, max err 3e-4 << bf16 quant); (3) zero-fill only the 8 border
// columns (disjoint from staged cols -> one barrier).
// ---------------------------------------------------------------------------

#define TOK 4096
#define NB  32

typedef __attribute__((ext_vector_type(8)))  short short8;
typedef __attribute__((ext_vector_type(4)))  short short4v;
typedef __attribute__((ext_vector_type(16))) float f32x16;

// gelu(x) = 0.5x(1+tanh(sqrt(2/pi)(x+0.044715x^3))) = x * sigmoid(u),
// u = x*(1.5957691216 + 0.0713548162 x^2). max |err| vs exact erf ~3e-4.
__device__ __forceinline__ float gelu_fast(float v) {
    float u = v * fmaf(0.0713548162f, v * v, 1.5957691216f);
    float e = __expf(-u);
    return v * __builtin_amdgcn_rcpf(1.f + e);
}

__device__ __forceinline__ short f2bf(float f) {
    union { float f; unsigned u; } x; x.f = f;
    unsigned r = (x.u + 0x7FFFu + ((x.u >> 16) & 1u)) >> 16;
    return (short)r;
}

__device__ __forceinline__ float bf2f(short s) {
    union { unsigned u; float f; } x;
    x.u = ((unsigned)(unsigned short)s) << 16;
    return x.f;
}

// ---------------------------------------------------------------------------
// Prep. MFMA-native layouts: frag element for lane (cl,g), reg j is
// W[col=cl][k = ks*16 + g*8 + j]  ->  stored at ((ks*2+g)*NCOL + col)*8 + j.
// ---------------------------------------------------------------------------
__global__ __launch_bounds__(256) void k_prep(
        const float* __restrict__ cw, const float* __restrict__ kw,
        const float* __restrict__ pw, const float* __restrict__ w1,
        const float* __restrict__ w2m,
        short* __restrict__ w2c, short* __restrict__ kwbf,
        short* __restrict__ pTbf, short* __restrict__ w1bf,
        short* __restrict__ w2bf) {
    int idx = blockIdx.x * 256 + threadIdx.x;
    if (idx < 110592) {
        int c = idx & 63;
        int t = idx >> 6;
        int e = t & 63;
        int tap = t >> 6;
        int kwi = tap % 3, t2 = tap / 3;
        int r = t2 % 3, brr = t2 / 3;
        float v = cw[(((brr * 64 + e) * 64 + c) * 3 + r) * 3 + kwi];
        int dst = ((((brr * 9 + r * 3 + kwi) * 4 + (c >> 4)) * 2 + ((c >> 3) & 1)) * 64 + e) * 8 + (c & 7);
        w2c[dst] = f2bf(v);
    } else if (idx < 147456) {
        int i2 = idx - 110592;
        int o = i2 / 192, i = i2 % 192;
        int dst = (((i >> 4) * 2 + ((i >> 3) & 1)) * 192 + o) * 8 + (i & 7);
        kwbf[dst] = f2bf(kw[i * 192 + o]);
    } else if (idx < 151552) {
        int i2 = idx - 147456;
        int o = i2 >> 6, d = i2 & 63;
        int dst = (((d >> 4) * 2 + ((d >> 3) & 1)) * 64 + o) * 8 + (d & 7);
        pTbf[dst] = f2bf(pw[d * 64 + o]);
    } else if (idx < 155648) {
        int i2 = idx - 151552;
        int i = i2 >> 6, jd = i2 & 63;
        int dst = (((jd >> 4) * 2 + ((jd >> 3) & 1)) * 64 + i) * 8 + (jd & 7);
        w1bf[dst] = f2bf(w1[jd * 64 + i]);
    } else if (idx < 159744) {
        int i2 = idx - 155648;
        int o = i2 >> 6, i = i2 & 63;
        int dst = (((i >> 4) * 2 + ((i >> 3) & 1)) * 64 + o) * 8 + (i & 7);
        w2bf[dst] = f2bf(w2m[i * 64 + o]);
    }
}

// ---------------------------------------------------------------------------
// Conv via MFMA. Block = (oh, br) x b, 256 thr = 4 waves.
// A: LDS sA[r][iw4][c] bf16, staged from fp32 x (L3-hot), in-reg f2bf,
//    write-side XOR swizzle ((iw4>>1)&7)<<4.
// B: w2c MFMA-native from L1.
// Zero-fill: border cols only (disjoint from staged cols; 1 barrier).
// ---------------------------------------------------------------------------
__global__ __launch_bounds__(256) void k_conv4(
        const float* __restrict__ x, const short* __restrict__ w2c,
        const float* __restrict__ cb, short* __restrict__ tokens) {
    const int bx = blockIdx.x;
    const int oh = bx / 3;
    const int br = bx - oh * 3;
    const int b  = blockIdx.y;
    const int d  = br + 1;
    const int tid = threadIdx.x;
    const int lane = tid & 63;
    const int wv = __builtin_amdgcn_readfirstlane(tid >> 6);
    const int cl = lane & 31;
    const int g  = lane >> 5;
    const int wm = wv & 1;
    const int wn = wv >> 1;

    __shared__ short sA[3 * 136 * 64];   // 52224 B

    // zero the 8 border columns per row (iw4 in {0..3,132..135}); whole
    // 128B column zeroed so swizzle layout is irrelevant.
    {
        short8 z = {0, 0, 0, 0, 0, 0, 0, 0};
        for (int i = tid; i < 192; i += 256) {
            int sub = i & 7;
            int ci  = (i >> 3) & 7;
            int r   = i >> 6;
            int iw4 = (ci < 4) ? ci : (128 + ci);
            *(short8*)((char*)sA + (r * 136 + iw4) * 128 + sub * 16) = z;
        }
    }

    // stage 3 rows from fp32 x; convert in-register; swizzled ds_write.
    const int sub = lane & 7;
    const int rowoff = lane >> 3;
    for (int it = 0; it < 12; ++it) {
        const int i = wv * 12 + it;
        const int r = i >> 4;
        const int ch = i & 15;
        const int ih = 2 * oh + (r - 1) * d;
        if ((unsigned)ih < 128u) {             // wave-uniform
            const int iw4 = 4 + ch * 8 + rowoff;
            const float* src = x + ((size_t)(b * 16384 + ih * 128 + iw4 - 4)) * 64 + sub * 8;
            float4 f0 = *(const float4*)(src);
            float4 f1 = *(const float4*)(src + 4);
            short8 v;
            v[0] = f2bf(f0.x); v[1] = f2bf(f0.y); v[2] = f2bf(f0.z); v[3] = f2bf(f0.w);
            v[4] = f2bf(f1.x); v[5] = f2bf(f1.y); v[6] = f2bf(f1.z); v[7] = f2bf(f1.w);
            char* dst = (char*)sA + (r * 136 + iw4) * 128
                      + ((sub * 16) ^ (((iw4 >> 1) & 7) << 4));
            *(short8*)dst = v;
        }
    }
    __syncthreads();

    f32x16 acc = {0.f, 0.f, 0.f, 0.f, 0.f, 0.f, 0.f, 0.f,
                  0.f, 0.f, 0.f, 0.f, 0.f, 0.f, 0.f, 0.f};
    const short* wbr = w2c + br * 9 * 4096;
    const int ow = wm * 32 + cl;
    const int ecol = wn * 32 + cl;

    for (int r = 0; r < 3; ++r) {
        const int ih = 2 * oh + (r - 1) * d;
        if ((unsigned)ih < 128u) {
#pragma unroll
            for (int kwi = 0; kwi < 3; ++kwi) {
                const int iw4 = 2 * ow + (kwi - 1) * d + 4;
                const char* arow = (const char*)sA + (r * 136 + iw4) * 128;
                const int swz = ((iw4 >> 1) & 7) << 4;
                const short* wt = wbr + (r * 3 + kwi) * 4096;
#pragma unroll
                for (int ks = 0; ks < 4; ++ks) {
                    short8 a = *(const short8*)(arow + ((ks * 32 + g * 16) ^ swz));
                    short8 bf = *(const short8*)(wt + ((ks * 2 + g) * 64 + ecol) * 8);
                    acc = __builtin_amdgcn_mfma_f32_32x32x16_bf16(a, bf, acc, 0, 0, 0);
                }
            }
        }
    }

    const int eG = br * 64 + wn * 32 + cl;
    const float bias = cb[eG];
    short* outb = tokens + ((size_t)(b * TOK + oh * 64 + wm * 32)) * 192 + eG;
#pragma unroll
    for (int reg = 0; reg < 16; ++reg) {
        int owl = (reg & 3) + 8 * (reg >> 2) + 4 * g;
        outb[(size_t)owl * 192] = f2bf(gelu_fast(acc[reg] + bias));
    }
}

// ---------------------------------------------------------------------------
// LN1 + kqv via MFMA; tokens bf16 in; weights MFMA-native.
// ---------------------------------------------------------------------------
__global__ __launch_bounds__(256) void k_lnkqv_mfma(
        const short* __restrict__ tokens, const float* __restrict__ g,
        const float* __restrict__ be, const short* __restrict__ wbf,
        const float* __restrict__ bias, float* __restrict__ kqvT) {
    const int b = blockIdx.y;
    const int t0 = blockIdx.x * 64;
    const int tid = threadIdx.x;

    __shared__ short sB[64 * 192];
    __shared__ float red[64 * 8];

    const int r = tid >> 2, q = tid & 3;
    const short* rowp = tokens + ((size_t)(b * TOK + t0 + r)) * 192 + q * 48;
    float v[48];
    float s1 = 0.f, s2 = 0.f;
#pragma unroll
    for (int i = 0; i < 6; ++i) {
        short8 x8 = *(const short8*)(rowp + i * 8);
#pragma unroll
        for (int j = 0; j < 8; ++j) {
            float f = bf2f(x8[j]);
            v[i * 8 + j] = f;
            s1 += f;
            s2 = fmaf(f, f, s2);
        }
    }
    red[r * 8 + q] = s1;
    red[r * 8 + 4 + q] = s2;
    __syncthreads();
    const float m1 = red[r * 8 + 0] + red[r * 8 + 1] + red[r * 8 + 2] + red[r * 8 + 3];
    const float m2 = red[r * 8 + 4] + red[r * 8 + 5] + red[r * 8 + 6] + red[r * 8 + 7];
    const float mu = m1 * (1.f / 192.f);
    const float var = m2 * (1.f / 192.f) - mu * mu;
    const float rs = rsqrtf(fmaxf(var, 0.f) + 1e-5f);
    const float4* g4 = (const float4*)(g + q * 48);
    const float4* b4 = (const float4*)(be + q * 48);
    char* rowB = (char*)sB + r * 384;
    const int swz = (r & 7) << 4;
#pragma unroll
    for (int i = 0; i < 12; ++i) {
        float4 gg = g4[i], bb = b4[i];
        short4v pk;
        pk.x = f2bf((v[4 * i + 0] - mu) * rs * gg.x + bb.x);
        pk.y = f2bf((v[4 * i + 1] - mu) * rs * gg.y + bb.y);
        pk.z = f2bf((v[4 * i + 2] - mu) * rs * gg.z + bb.z);
        pk.w = f2bf((v[4 * i + 3] - mu) * rs * gg.w + bb.w);
        *(short4v*)(rowB + (((q * 48 + i * 4) * 2) ^ swz)) = pk;
    }
    __syncthreads();

    const int lane = tid & 63;
    const int wv = tid >> 6;
    const int tt = wv & 1;
    const int wo = wv >> 1;
    const int colL = lane & 31;
    const int gq = lane >> 5;

    f32x16 acc0 = {0.f, 0.f, 0.f, 0.f, 0.f, 0.f, 0.f, 0.f,
                   0.f, 0.f, 0.f, 0.f, 0.f, 0.f, 0.f, 0.f};
    f32x16 acc1 = acc0, acc2 = acc0;
    const char* bbase = (const char*)sB + (tt * 32 + colL) * 384;
    const int bswz = ((tt * 32 + colL) & 7) << 4;
    const int ocol = wo * 32 + colL;

    for (int kk = 0; kk < 12; ++kk) {
        short8 bf = *(const short8*)(bbase + (((kk * 16 + gq * 8) * 2) ^ bswz));
        const short* ak = wbf + ((kk * 2 + gq) * 192 + ocol) * 8;
        short8 a0 = *(const short8*)(ak);
        short8 a1 = *(const short8*)(ak + 64 * 8);
        short8 a2 = *(const short8*)(ak + 128 * 8);
        acc0 = __builtin_amdgcn_mfma_f32_32x32x16_bf16(a0, bf, acc0, 0, 0, 0);
        acc1 = __builtin_amdgcn_mfma_f32_32x32x16_bf16(a1, bf, acc1, 0, 0, 0);
        acc2 = __builtin_amdgcn_mfma_f32_32x32x16_bf16(a2, bf, acc2, 0, 0, 0);
    }

    const int tglob = t0 + tt * 32 + colL;
    float* outb = kqvT + (size_t)b * 192 * TOK + tglob;
#pragma unroll
    for (int j = 0; j < 3; ++j) {
        const int obase = (wo + 2 * j) * 32;
        const f32x16 ac = (j == 0 ? acc0 : j == 1 ? acc1 : acc2);
#pragma unroll
        for (int reg = 0; reg < 16; ++reg) {
            int orow = (reg & 3) + 8 * (reg >> 2) + 4 * gq;
            outb[(size_t)(obase + orow) * TOK] = ac[reg] + bias[obase + orow];
        }
    }
}

// ---------------------------------------------------------------------------
// Performer features (unchanged).
// ---------------------------------------------------------------------------
__global__ __launch_bounds__(256) void k_perf(
        const float* __restrict__ kqvT, const float* __restrict__ wperf,
        float* __restrict__ kpT, float* __restrict__ qpT) {
    const int b = blockIdx.y;
    const int t = blockIdx.x * 256 + threadIdx.x;
    const float* basek = kqvT + (size_t)b * 192 * TOK + t;
    for (int pass = 0; pass < 2; ++pass) {
        float kr[64];
        const float* src = basek + (size_t)pass * 64 * TOK;
#pragma unroll
        for (int i = 0; i < 64; ++i) kr[i] = src[(size_t)i * TOK];
        float xd = 0.f;
#pragma unroll
        for (int i = 0; i < 64; ++i) xd = fmaf(kr[i], kr[i], xd);
        xd *= 0.5f;
        float* dst = (pass == 0 ? kpT : qpT) + (size_t)b * 32 * TOK + t;
        for (int m = 0; m < 32; ++m) {
            const float* wr = wperf + m * 64;
            float a = 0.f;
#pragma unroll
            for (int i = 0; i < 64; ++i) a = fmaf(wr[i], kr[i], a);
            dst[(size_t)m * TOK] = expf(a - xd) * 0.17677669529663687f;
        }
    }
}

// ---------------------------------------------------------------------------
// kptv chunk partials (unchanged).
// ---------------------------------------------------------------------------
__global__ __launch_bounds__(256) void k_kptv(
        const float* __restrict__ kqvT, const float* __restrict__ kpT,
        float* __restrict__ kvp, float* __restrict__ skpp) {
    const int b = blockIdx.y, ch = blockIdx.x, tid = threadIdx.x;
    const int t = ch * 256 + tid;
    __shared__ float sv[256 * 65 + 256 * 36];
    float* skp = sv + 256 * 65;
    for (int dd = 0; dd < 64; ++dd)
        sv[tid * 65 + dd] = kqvT[((size_t)(b * 192 + 128 + dd)) * TOK + t];
    for (int m = 0; m < 32; ++m)
        skp[tid * 36 + m] = kpT[((size_t)(b * 32 + m)) * TOK + t];
    __syncthreads();

    const int dd = tid & 63;
    const int mg = __builtin_amdgcn_readfirstlane(tid >> 6);
    float acc[8];
#pragma unroll
    for (int j = 0; j < 8; ++j) acc[j] = 0.f;
    for (int tt = 0; tt < 256; ++tt) {
        float vv = sv[tt * 65 + dd];
        const float4* kq = (const float4*)(skp + tt * 36 + mg * 8);
        float4 a0 = kq[0], a1 = kq[1];
        acc[0] = fmaf(vv, a0.x, acc[0]);
        acc[1] = fmaf(vv, a0.y, acc[1]);
        acc[2] = fmaf(vv, a0.z, acc[2]);
        acc[3] = fmaf(vv, a0.w, acc[3]);
        acc[4] = fmaf(vv, a1.x, acc[4]);
        acc[5] = fmaf(vv, a1.y, acc[5]);
        acc[6] = fmaf(vv, a1.z, acc[6]);
        acc[7] = fmaf(vv, a1.w, acc[7]);
    }
    float* dst = kvp + (((size_t)(b * 16 + ch) * 64 + dd) * 32) + mg * 8;
#pragma unroll
    for (int j = 0; j < 8; ++j) dst[j] = acc[j];

    if (tid < 32) {
        float s = 0.f;
        for (int tt = 0; tt < 256; ++tt) s += skp[tt * 36 + tid];
        skpp[(b * 16 + ch) * 32 + tid] = s;
    }
}

// Reduce partials -> kvbf MFMA-native [b][ms][g][d][8m] bf16, sum_kp fp32.
__global__ __launch_bounds__(256) void k_reduce2(
        const float* __restrict__ kvp, const float* __restrict__ skpp,
        short* __restrict__ kvbf, float* __restrict__ sum_kp) {
    int idx = blockIdx.x * 256 + threadIdx.x;
    if (idx < 65536) {
        int b = idx >> 11, rem = idx & 2047, dd = rem >> 5, m = rem & 31;
        float s = 0.f;
        for (int ch = 0; ch < 16; ++ch) s += kvp[((b * 16 + ch) * 64 + dd) * 32 + m];
        int dst = (((b * 2 + (m >> 4)) * 2 + ((m >> 3) & 1)) * 64 + dd) * 8 + (m & 7);
        kvbf[dst] = f2bf(s);
    } else if (idx < 65536 + 1024) {
        int i = idx - 65536;
        int b = i >> 5, m = i & 31;
        float s = 0.f;
        for (int ch = 0; ch < 16; ++ch) s += skpp[(b * 16 + ch) * 32 + m];
        sum_kp[i] = s;
    }
}

// ---------------------------------------------------------------------------
// Fused: yatt = (qp@kv^T)*rD -> proj+v+b -> LN2 -> w1+GELU -> w2 + skip.
// ---------------------------------------------------------------------------
__global__ __launch_bounds__(256) void k_fuse(
        const float* __restrict__ kqvT, const float* __restrict__ qpT,
        const short* __restrict__ kvbf, const float* __restrict__ sum_kp,
        const short* __restrict__ pTbf, const float* __restrict__ proj_b,
        const float* __restrict__ g2, const float* __restrict__ b2ln,
        const short* __restrict__ w1bf, const float* __restrict__ b1,
        const short* __restrict__ w2bf, const float* __restrict__ b2,
        float* __restrict__ out) {
    const int b = blockIdx.y;
    const int t0 = blockIdx.x * 64;
    const int tid = threadIdx.x;
    const int lane = tid & 63;
    const int cl = lane & 31;
    const int g  = lane >> 5;
    const int wv = tid >> 6;
    const int wr = wv & 1;
    const int wc = wv >> 1;

    __shared__ __align__(16) char pool[29952];
    short* qpS  = (short*)(pool + 0);
    short* ytS  = (short*)(pool + 5120);
    short* xnS  = (short*)(pool + 14336);
    short* hgS  = (short*)(pool + 0);
    float* outS = (float*)(pool + 9216);
    float* red  = (float*)(pool + 26624);
    float* stat = (float*)(pool + 27648);
    float* coefS= (float*)(pool + 28672);

    if (tid < 64) {
        coefS[tid]       = proj_b[tid];
        coefS[64 + tid]  = g2[tid];
        coefS[128 + tid] = b2ln[tid];
        coefS[192 + tid] = b1[tid];
        coefS[256 + tid] = b2[tid];
    }
    {
        const int t = tid & 63, q = tid >> 6;
        const float* sk = sum_kp + b * 32;
        float dsum = 0.f;
        short8 pk;
#pragma unroll
        for (int i = 0; i < 8; ++i) {
            int m = q * 8 + i;
            float v = qpT[((size_t)(b * 32 + m)) * TOK + t0 + t];
            dsum = fmaf(v, sk[m], dsum);
            pk[i] = f2bf(v);
        }
        *(short8*)(qpS + t * 40 + q * 8) = pk;
        red[t * 4 + q] = dsum;
    }
    __syncthreads();

    const int tl = wc * 32 + cl;
    const int tg = t0 + tl;
    const int rcol = wr * 32 + cl;

    f32x16 acc = {0.f, 0.f, 0.f, 0.f, 0.f, 0.f, 0.f, 0.f,
                  0.f, 0.f, 0.f, 0.f, 0.f, 0.f, 0.f, 0.f};
    {
        const short* Ab = kvbf + (size_t)b * 2048;
        short8 a0 = *(const short8*)(Ab + (g * 64 + rcol) * 8);
        short8 a1 = *(const short8*)(Ab + ((2 + g) * 64 + rcol) * 8);
        short8 b0 = *(const short8*)(qpS + tl * 40 + g * 8);
        short8 b1v = *(const short8*)(qpS + tl * 40 + 16 + g * 8);
        acc = __builtin_amdgcn_mfma_f32_32x32x16_bf16(a0, b0, acc, 0, 0, 0);
        acc = __builtin_amdgcn_mfma_f32_32x32x16_bf16(a1, b1v, acc, 0, 0, 0);
    }
    {
        float Dv = red[tl * 4 + 0] + red[tl * 4 + 1] + red[tl * 4 + 2] + red[tl * 4 + 3];
        float rD = 1.f / (Dv + 1e-8f);
#pragma unroll
        for (int rq = 0; rq < 4; ++rq) {
            int d0 = wr * 32 + 8 * rq + 4 * g;
            short4v p;
            p.x = f2bf(acc[rq * 4 + 0] * rD);
            p.y = f2bf(acc[rq * 4 + 1] * rD);
            p.z = f2bf(acc[rq * 4 + 2] * rD);
            p.w = f2bf(acc[rq * 4 + 3] * rD);
            *(short4v*)(ytS + tl * 72 + d0) = p;
        }
    }
    __syncthreads();

    f32x16 acc2 = {0.f, 0.f, 0.f, 0.f, 0.f, 0.f, 0.f, 0.f,
                   0.f, 0.f, 0.f, 0.f, 0.f, 0.f, 0.f, 0.f};
    {
#pragma unroll
        for (int ks = 0; ks < 4; ++ks) {
            short8 a = *(const short8*)(pTbf + ((ks * 2 + g) * 64 + rcol) * 8);
            short8 bb = *(const short8*)(ytS + tl * 72 + ks * 16 + g * 8);
            acc2 = __builtin_amdgcn_mfma_f32_32x32x16_bf16(a, bb, acc2, 0, 0, 0);
        }
    }
    float skv[16];
    {
        const float* vb = kqvT + ((size_t)(b * 192 + 128)) * TOK + tg;
#pragma unroll
        for (int reg = 0; reg < 16; ++reg) {
            int o = wr * 32 + (reg & 3) + 8 * (reg >> 2) + 4 * g;
            skv[reg] = acc2[reg] + vb[(size_t)o * TOK] + coefS[o];
        }
    }

    {
        float s1 = 0.f, s2 = 0.f;
#pragma unroll
        for (int reg = 0; reg < 16; ++reg) {
            s1 += skv[reg];
            s2 = fmaf(skv[reg], skv[reg], s2);
        }
        s1 += __shfl_xor(s1, 32, 64);
        s2 += __shfl_xor(s2, 32, 64);
        if (g == 0) {
            stat[(wr * 64 + tl) * 2 + 0] = s1;
            stat[(wr * 64 + tl) * 2 + 1] = s2;
        }
        __syncthreads();
        float S1 = s1 + stat[((wr ^ 1) * 64 + tl) * 2 + 0];
        float S2 = s2 + stat[((wr ^ 1) * 64 + tl) * 2 + 1];
        float mu = S1 * (1.f / 64.f);
        float var = S2 * (1.f / 64.f) - mu * mu;
        float rs = rsqrtf(fmaxf(var, 0.f) + 1e-5f);
#pragma unroll
        for (int rq = 0; rq < 4; ++rq) {
            int o0 = wr * 32 + 8 * rq + 4 * g;
            short4v p;
#pragma unroll
            for (int j = 0; j < 4; ++j) {
                int o = o0 + j;
                float xn = (skv[rq * 4 + j] - mu) * rs * coefS[64 + o] + coefS[128 + o];
                ((short*)&p)[j] = f2bf(xn);
            }
            *(short4v*)(xnS + tl * 72 + o0) = p;
        }
    }
    __syncthreads();

    f32x16 acc3 = {0.f, 0.f, 0.f, 0.f, 0.f, 0.f, 0.f, 0.f,
                   0.f, 0.f, 0.f, 0.f, 0.f, 0.f, 0.f, 0.f};
    {
#pragma unroll
        for (int ks = 0; ks < 4; ++ks) {
            short8 a = *(const short8*)(w1bf + ((ks * 2 + g) * 64 + rcol) * 8);
            short8 bb = *(const short8*)(xnS + tl * 72 + ks * 16 + g * 8);
            acc3 = __builtin_amdgcn_mfma_f32_32x32x16_bf16(a, bb, acc3, 0, 0, 0);
        }
    }
    __syncthreads();
    {
#pragma unroll
        for (int rq = 0; rq < 4; ++rq) {
            int i0 = wr * 32 + 8 * rq + 4 * g;
            short4v p;
#pragma unroll
            for (int j = 0; j < 4; ++j) {
                int i = i0 + j;
                float hgv = gelu_fast(acc3[rq * 4 + j] + coefS[192 + i]);
                ((short*)&p)[j] = f2bf(hgv);
            }
            *(short4v*)(hgS + tl * 72 + i0) = p;
        }
    }
    __syncthreads();

    f32x16 acc4 = {0.f, 0.f, 0.f, 0.f, 0.f, 0.f, 0.f, 0.f,
                   0.f, 0.f, 0.f, 0.f, 0.f, 0.f, 0.f, 0.f};
    {
#pragma unroll
        for (int ks = 0; ks < 4; ++ks) {
            short8 a = *(const short8*)(w2bf + ((ks * 2 + g) * 64 + rcol) * 8);
            short8 bb = *(const short8*)(hgS + tl * 72 + ks * 16 + g * 8);
            acc4 = __builtin_amdgcn_mfma_f32_32x32x16_bf16(a, bb, acc4, 0, 0, 0);
        }
    }
    {
#pragma unroll
        for (int rq = 0; rq < 4; ++rq) {
            int o0 = wr * 32 + 8 * rq + 4 * g;
            float4 f;
#pragma unroll
            for (int j = 0; j < 4; ++j) {
                int o = o0 + j;
                ((float*)&f)[j] = skv[rq * 4 + j] + acc4[rq * 4 + j] + coefS[256 + o];
            }
            *(float4*)(outS + tl * 68 + o0) = f;
        }
    }
    __syncthreads();

    {
        const int tt = tid >> 2, qq = tid & 3;
        float* ob = out + ((size_t)(b * TOK) + t0 + tt) * 64;
#pragma unroll
        for (int it = 0; it < 4; ++it) {
            *(float4*)(ob + it * 16 + qq * 4) =
                *(float4*)(outS + tt * 68 + it * 16 + qq * 4);
        }
    }
}

// ---------------------------------------------------------------------------
extern "C" void kernel_launch(void* const* d_in, const int* in_sizes, int n_in,
                              void* d_out, int out_size, void* d_ws, size_t ws_size,
                              hipStream_t stream) {
    const float* x      = (const float*)d_in[0];
    const float* conv_w = (const float*)d_in[1];
    const float* conv_b = (const float*)d_in[2];
    const float* ln1_g  = (const float*)d_in[3];
    const float* ln1_b  = (const float*)d_in[4];
    const float* kqv_w  = (const float*)d_in[5];
    const float* kqv_b  = (const float*)d_in[6];
    const float* proj_w = (const float*)d_in[7];
    const float* proj_b = (const float*)d_in[8];
    const float* w_perf = (const float*)d_in[9];
    const float* ln2_g  = (const float*)d_in[10];
    const float* ln2_b  = (const float*)d_in[11];
    const float* mlp_w1 = (const float*)d_in[12];
    const float* mlp_b1 = (const float*)d_in[13];
    const float* mlp_w2 = (const float*)d_in[14];
    const float* mlp_b2 = (const float*)d_in[15];

    float* ws = (float*)d_ws;
    short* w2c    = (short*)ws;                 // 110592 sh
    short* kwbf   = (short*)(ws + 55296);       // 36864 sh
    short* pTbf   = (short*)(ws + 73728);       // 4096 sh
    short* w1bf   = (short*)(ws + 75776);       // 4096 sh
    short* w2bf   = (short*)(ws + 77824);       // 4096 sh
    float* sum_kp = ws + 79872;                 // 1024 f
    short* kvbf   = (short*)(ws + 80896);       // 65536 sh
    short* tokens = (short*)(ws + 114688);      // 25165824 sh
    float* qpT    = ws + 114688;                // overlay after tokens dead
    float* kpT    = ws + 114688 + 4194304;
    float* skpp   = ws + 114688 + 8388608;
    float* kvp    = ws + 114688 + 8404992;
    float* kqvT   = ws + 114688 + 25165824;
    float* outp   = (float*)d_out;

    k_prep   <<<624, 256, 0, stream>>>(conv_w, kqv_w, proj_w, mlp_w1, mlp_w2,
                                       w2c, kwbf, pTbf, w1bf, w2bf);
    k_conv4  <<<dim3(192, 32), 256, 0, stream>>>(x, w2c, conv_b, tokens);
    k_lnkqv_mfma<<<dim3(64, 32), 256, 0, stream>>>(tokens, ln1_g, ln1_b, kwbf, kqv_b, kqvT);
    k_perf   <<<dim3(16, 32), 256, 0, stream>>>(kqvT, w_perf, kpT, qpT);
    k_kptv   <<<dim3(16, 32), 256, 0, stream>>>(kqvT, kpT, kvp, skpp);
    k_reduce2<<<260, 256, 0, stream>>>(kvp, skpp, kvbf, sum_kp);
    k_fuse   <<<dim3(64, 32), 256, 0, stream>>>(kqvT, qpT, kvbf, sum_kp,
                                                pTbf, proj_b, ln2_g, ln2_b,
                                                w1bf, mlp_b1, w2bf, mlp_b2, outp);
}

// Round 9
// 249.320 us; speedup vs baseline: 14.1637x; 1.0402x over previous
//
#include <hip/hip_runtime.h>

// ---------------------------------------------------------------------------
// BlockRC2: PRM (3 dilated stride-2 convs + GELU) -> LN1 -> kqv ->
// performer attention -> proj+skip -> LN2 -> MLP -> skip.
// Round 9: XCD-aware swizzle on conv grid. r8 showed conv fetch-bound
// (FETCH 280MB = 2.2x image; 9x row-reuse missing L2 because co-resident
// blocks span 4 batch slices x 8 XCDs). Swizzle maps each XCD to whole
// b-slices (4MB = one XCD L2) in oh order -> row re-reads become L2 hits.
// ---------------------------------------------------------------------------

#define TOK 4096
#define NB  32

typedef __attribute__((ext_vector_type(8)))  short short8;
typedef __attribute__((ext_vector_type(4)))  short short4v;
typedef __attribute__((ext_vector_type(16))) float f32x16;

// gelu(x) = x * sigmoid(x*(1.5957691216 + 0.0713548162 x^2)), max err ~3e-4.
__device__ __forceinline__ float gelu_fast(float v) {
    float u = v * fmaf(0.0713548162f, v * v, 1.5957691216f);
    float e = __expf(-u);
    return v * __builtin_amdgcn_rcpf(1.f + e);
}

__device__ __forceinline__ short f2bf(float f) {
    union { float f; unsigned u; } x; x.f = f;
    unsigned r = (x.u + 0x7FFFu + ((x.u >> 16) & 1u)) >> 16;
    return (short)r;
}

__device__ __forceinline__ float bf2f(short s) {
    union { unsigned u; float f; } x;
    x.u = ((unsigned)(unsigned short)s) << 16;
    return x.f;
}

// ---------------------------------------------------------------------------
// Prep. MFMA-native layouts: frag element for lane (cl,g), reg j is
// W[col=cl][k = ks*16 + g*8 + j]  ->  stored at ((ks*2+g)*NCOL + col)*8 + j.
// ---------------------------------------------------------------------------
__global__ __launch_bounds__(256) void k_prep(
        const float* __restrict__ cw, const float* __restrict__ kw,
        const float* __restrict__ pw, const float* __restrict__ w1,
        const float* __restrict__ w2m,
        short* __restrict__ w2c, short* __restrict__ kwbf,
        short* __restrict__ pTbf, short* __restrict__ w1bf,
        short* __restrict__ w2bf) {
    int idx = blockIdx.x * 256 + threadIdx.x;
    if (idx < 110592) {
        int c = idx & 63;
        int t = idx >> 6;
        int e = t & 63;
        int tap = t >> 6;
        int kwi = tap % 3, t2 = tap / 3;
        int r = t2 % 3, brr = t2 / 3;
        float v = cw[(((brr * 64 + e) * 64 + c) * 3 + r) * 3 + kwi];
        int dst = ((((brr * 9 + r * 3 + kwi) * 4 + (c >> 4)) * 2 + ((c >> 3) & 1)) * 64 + e) * 8 + (c & 7);
        w2c[dst] = f2bf(v);
    } else if (idx < 147456) {
        int i2 = idx - 110592;
        int o = i2 / 192, i = i2 % 192;
        int dst = (((i >> 4) * 2 + ((i >> 3) & 1)) * 192 + o) * 8 + (i & 7);
        kwbf[dst] = f2bf(kw[i * 192 + o]);
    } else if (idx < 151552) {
        int i2 = idx - 147456;
        int o = i2 >> 6, d = i2 & 63;
        int dst = (((d >> 4) * 2 + ((d >> 3) & 1)) * 64 + o) * 8 + (d & 7);
        pTbf[dst] = f2bf(pw[d * 64 + o]);
    } else if (idx < 155648) {
        int i2 = idx - 151552;
        int i = i2 >> 6, jd = i2 & 63;
        int dst = (((jd >> 4) * 2 + ((jd >> 3) & 1)) * 64 + i) * 8 + (jd & 7);
        w1bf[dst] = f2bf(w1[jd * 64 + i]);
    } else if (idx < 159744) {
        int i2 = idx - 155648;
        int o = i2 >> 6, i = i2 & 63;
        int dst = (((i >> 4) * 2 + ((i >> 3) & 1)) * 64 + o) * 8 + (i & 7);
        w2bf[dst] = f2bf(w2m[i * 64 + o]);
    }
}

// ---------------------------------------------------------------------------
// Conv via MFMA. 6144 blocks 1D, XCD-swizzled: swz=(wg&7)*768+(wg>>3);
// b = swz/192, rem=(oh,br). Each XCD owns whole b-slices -> 9x row reuse
// hits local L2. A: LDS bf16 swizzled tile staged from fp32 x in-register.
// B: w2c MFMA-native from L1.
// ---------------------------------------------------------------------------
__global__ __launch_bounds__(256) void k_conv4(
        const float* __restrict__ x, const short* __restrict__ w2c,
        const float* __restrict__ cb, short* __restrict__ tokens) {
    const int wg  = blockIdx.x;
    const int swz_id = (wg & 7) * 768 + (wg >> 3);   // 6144 = 8*768, bijective
    const int b   = swz_id / 192;
    const int rem = swz_id - b * 192;
    const int oh  = rem / 3;
    const int br  = rem - oh * 3;
    const int d  = br + 1;
    const int tid = threadIdx.x;
    const int lane = tid & 63;
    const int wv = __builtin_amdgcn_readfirstlane(tid >> 6);
    const int cl = lane & 31;
    const int g  = lane >> 5;
    const int wm = wv & 1;
    const int wn = wv >> 1;

    __shared__ short sA[3 * 136 * 64];   // 52224 B

    // zero the 8 border columns per row (iw4 in {0..3,132..135}).
    {
        short8 z = {0, 0, 0, 0, 0, 0, 0, 0};
        for (int i = tid; i < 192; i += 256) {
            int sub = i & 7;
            int ci  = (i >> 3) & 7;
            int r   = i >> 6;
            int iw4 = (ci < 4) ? ci : (128 + ci);
            *(short8*)((char*)sA + (r * 136 + iw4) * 128 + sub * 16) = z;
        }
    }

    // stage 3 rows from fp32 x; convert in-register; swizzled ds_write.
    const int sub = lane & 7;
    const int rowoff = lane >> 3;
    for (int it = 0; it < 12; ++it) {
        const int i = wv * 12 + it;
        const int r = i >> 4;
        const int ch = i & 15;
        const int ih = 2 * oh + (r - 1) * d;
        if ((unsigned)ih < 128u) {             // wave-uniform
            const int iw4 = 4 + ch * 8 + rowoff;
            const float* src = x + ((size_t)(b * 16384 + ih * 128 + iw4 - 4)) * 64 + sub * 8;
            float4 f0 = *(const float4*)(src);
            float4 f1 = *(const float4*)(src + 4);
            short8 v;
            v[0] = f2bf(f0.x); v[1] = f2bf(f0.y); v[2] = f2bf(f0.z); v[3] = f2bf(f0.w);
            v[4] = f2bf(f1.x); v[5] = f2bf(f1.y); v[6] = f2bf(f1.z); v[7] = f2bf(f1.w);
            char* dst = (char*)sA + (r * 136 + iw4) * 128
                      + ((sub * 16) ^ (((iw4 >> 1) & 7) << 4));
            *(short8*)dst = v;
        }
    }
    __syncthreads();

    f32x16 acc = {0.f, 0.f, 0.f, 0.f, 0.f, 0.f, 0.f, 0.f,
                  0.f, 0.f, 0.f, 0.f, 0.f, 0.f, 0.f, 0.f};
    const short* wbr = w2c + br * 9 * 4096;
    const int ow = wm * 32 + cl;
    const int ecol = wn * 32 + cl;

    for (int r = 0; r < 3; ++r) {
        const int ih = 2 * oh + (r - 1) * d;
        if ((unsigned)ih < 128u) {
#pragma unroll
            for (int kwi = 0; kwi < 3; ++kwi) {
                const int iw4 = 2 * ow + (kwi - 1) * d + 4;
                const char* arow = (const char*)sA + (r * 136 + iw4) * 128;
                const int swz = ((iw4 >> 1) & 7) << 4;
                const short* wt = wbr + (r * 3 + kwi) * 4096;
#pragma unroll
                for (int ks = 0; ks < 4; ++ks) {
                    short8 a = *(const short8*)(arow + ((ks * 32 + g * 16) ^ swz));
                    short8 bf = *(const short8*)(wt + ((ks * 2 + g) * 64 + ecol) * 8);
                    acc = __builtin_amdgcn_mfma_f32_32x32x16_bf16(a, bf, acc, 0, 0, 0);
                }
            }
        }
    }

    const int eG = br * 64 + wn * 32 + cl;
    const float bias = cb[eG];
    short* outb = tokens + ((size_t)(b * TOK + oh * 64 + wm * 32)) * 192 + eG;
#pragma unroll
    for (int reg = 0; reg < 16; ++reg) {
        int owl = (reg & 3) + 8 * (reg >> 2) + 4 * g;
        outb[(size_t)owl * 192] = f2bf(gelu_fast(acc[reg] + bias));
    }
}

// ---------------------------------------------------------------------------
// LN1 + kqv via MFMA; tokens bf16 in; weights MFMA-native.
// ---------------------------------------------------------------------------
__global__ __launch_bounds__(256) void k_lnkqv_mfma(
        const short* __restrict__ tokens, const float* __restrict__ g,
        const float* __restrict__ be, const short* __restrict__ wbf,
        const float* __restrict__ bias, float* __restrict__ kqvT) {
    const int b = blockIdx.y;
    const int t0 = blockIdx.x * 64;
    const int tid = threadIdx.x;

    __shared__ short sB[64 * 192];
    __shared__ float red[64 * 8];

    const int r = tid >> 2, q = tid & 3;
    const short* rowp = tokens + ((size_t)(b * TOK + t0 + r)) * 192 + q * 48;
    float v[48];
    float s1 = 0.f, s2 = 0.f;
#pragma unroll
    for (int i = 0; i < 6; ++i) {
        short8 x8 = *(const short8*)(rowp + i * 8);
#pragma unroll
        for (int j = 0; j < 8; ++j) {
            float f = bf2f(x8[j]);
            v[i * 8 + j] = f;
            s1 += f;
            s2 = fmaf(f, f, s2);
        }
    }
    red[r * 8 + q] = s1;
    red[r * 8 + 4 + q] = s2;
    __syncthreads();
    const float m1 = red[r * 8 + 0] + red[r * 8 + 1] + red[r * 8 + 2] + red[r * 8 + 3];
    const float m2 = red[r * 8 + 4] + red[r * 8 + 5] + red[r * 8 + 6] + red[r * 8 + 7];
    const float mu = m1 * (1.f / 192.f);
    const float var = m2 * (1.f / 192.f) - mu * mu;
    const float rs = rsqrtf(fmaxf(var, 0.f) + 1e-5f);
    const float4* g4 = (const float4*)(g + q * 48);
    const float4* b4 = (const float4*)(be + q * 48);
    char* rowB = (char*)sB + r * 384;
    const int swz = (r & 7) << 4;
#pragma unroll
    for (int i = 0; i < 12; ++i) {
        float4 gg = g4[i], bb = b4[i];
        short4v pk;
        pk.x = f2bf((v[4 * i + 0] - mu) * rs * gg.x + bb.x);
        pk.y = f2bf((v[4 * i + 1] - mu) * rs * gg.y + bb.y);
        pk.z = f2bf((v[4 * i + 2] - mu) * rs * gg.z + bb.z);
        pk.w = f2bf((v[4 * i + 3] - mu) * rs * gg.w + bb.w);
        *(short4v*)(rowB + (((q * 48 + i * 4) * 2) ^ swz)) = pk;
    }
    __syncthreads();

    const int lane = tid & 63;
    const int wv = tid >> 6;
    const int tt = wv & 1;
    const int wo = wv >> 1;
    const int colL = lane & 31;
    const int gq = lane >> 5;

    f32x16 acc0 = {0.f, 0.f, 0.f, 0.f, 0.f, 0.f, 0.f, 0.f,
                   0.f, 0.f, 0.f, 0.f, 0.f, 0.f, 0.f, 0.f};
    f32x16 acc1 = acc0, acc2 = acc0;
    const char* bbase = (const char*)sB + (tt * 32 + colL) * 384;
    const int bswz = ((tt * 32 + colL) & 7) << 4;
    const int ocol = wo * 32 + colL;

    for (int kk = 0; kk < 12; ++kk) {
        short8 bf = *(const short8*)(bbase + (((kk * 16 + gq * 8) * 2) ^ bswz));
        const short* ak = wbf + ((kk * 2 + gq) * 192 + ocol) * 8;
        short8 a0 = *(const short8*)(ak);
        short8 a1 = *(const short8*)(ak + 64 * 8);
        short8 a2 = *(const short8*)(ak + 128 * 8);
        acc0 = __builtin_amdgcn_mfma_f32_32x32x16_bf16(a0, bf, acc0, 0, 0, 0);
        acc1 = __builtin_amdgcn_mfma_f32_32x32x16_bf16(a1, bf, acc1, 0, 0, 0);
        acc2 = __builtin_amdgcn_mfma_f32_32x32x16_bf16(a2, bf, acc2, 0, 0, 0);
    }

    const int tglob = t0 + tt * 32 + colL;
    float* outb = kqvT + (size_t)b * 192 * TOK + tglob;
#pragma unroll
    for (int j = 0; j < 3; ++j) {
        const int obase = (wo + 2 * j) * 32;
        const f32x16 ac = (j == 0 ? acc0 : j == 1 ? acc1 : acc2);
#pragma unroll
        for (int reg = 0; reg < 16; ++reg) {
            int orow = (reg & 3) + 8 * (reg >> 2) + 4 * gq;
            outb[(size_t)(obase + orow) * TOK] = ac[reg] + bias[obase + orow];
        }
    }
}

// ---------------------------------------------------------------------------
// Performer features (unchanged).
// ---------------------------------------------------------------------------
__global__ __launch_bounds__(256) void k_perf(
        const float* __restrict__ kqvT, const float* __restrict__ wperf,
        float* __restrict__ kpT, float* __restrict__ qpT) {
    const int b = blockIdx.y;
    const int t = blockIdx.x * 256 + threadIdx.x;
    const float* basek = kqvT + (size_t)b * 192 * TOK + t;
    for (int pass = 0; pass < 2; ++pass) {
        float kr[64];
        const float* src = basek + (size_t)pass * 64 * TOK;
#pragma unroll
        for (int i = 0; i < 64; ++i) kr[i] = src[(size_t)i * TOK];
        float xd = 0.f;
#pragma unroll
        for (int i = 0; i < 64; ++i) xd = fmaf(kr[i], kr[i], xd);
        xd *= 0.5f;
        float* dst = (pass == 0 ? kpT : qpT) + (size_t)b * 32 * TOK + t;
        for (int m = 0; m < 32; ++m) {
            const float* wr = wperf + m * 64;
            float a = 0.f;
#pragma unroll
            for (int i = 0; i < 64; ++i) a = fmaf(wr[i], kr[i], a);
            dst[(size_t)m * TOK] = expf(a - xd) * 0.17677669529663687f;
        }
    }
}

// ---------------------------------------------------------------------------
// kptv chunk partials (unchanged).
// ---------------------------------------------------------------------------
__global__ __launch_bounds__(256) void k_kptv(
        const float* __restrict__ kqvT, const float* __restrict__ kpT,
        float* __restrict__ kvp, float* __restrict__ skpp) {
    const int b = blockIdx.y, ch = blockIdx.x, tid = threadIdx.x;
    const int t = ch * 256 + tid;
    __shared__ float sv[256 * 65 + 256 * 36];
    float* skp = sv + 256 * 65;
    for (int dd = 0; dd < 64; ++dd)
        sv[tid * 65 + dd] = kqvT[((size_t)(b * 192 + 128 + dd)) * TOK + t];
    for (int m = 0; m < 32; ++m)
        skp[tid * 36 + m] = kpT[((size_t)(b * 32 + m)) * TOK + t];
    __syncthreads();

    const int dd = tid & 63;
    const int mg = __builtin_amdgcn_readfirstlane(tid >> 6);
    float acc[8];
#pragma unroll
    for (int j = 0; j < 8; ++j) acc[j] = 0.f;
    for (int tt = 0; tt < 256; ++tt) {
        float vv = sv[tt * 65 + dd];
        const float4* kq = (const float4*)(skp + tt * 36 + mg * 8);
        float4 a0 = kq[0], a1 = kq[1];
        acc[0] = fmaf(vv, a0.x, acc[0]);
        acc[1] = fmaf(vv, a0.y, acc[1]);
        acc[2] = fmaf(vv, a0.z, acc[2]);
        acc[3] = fmaf(vv, a0.w, acc[3]);
        acc[4] = fmaf(vv, a1.x, acc[4]);
        acc[5] = fmaf(vv, a1.y, acc[5]);
        acc[6] = fmaf(vv, a1.z, acc[6]);
        acc[7] = fmaf(vv, a1.w, acc[7]);
    }
    float* dst = kvp + (((size_t)(b * 16 + ch) * 64 + dd) * 32) + mg * 8;
#pragma unroll
    for (int j = 0; j < 8; ++j) dst[j] = acc[j];

    if (tid < 32) {
        float s = 0.f;
        for (int tt = 0; tt < 256; ++tt) s += skp[tt * 36 + tid];
        skpp[(b * 16 + ch) * 32 + tid] = s;
    }
}

// Reduce partials -> kvbf MFMA-native [b][ms][g][d][8m] bf16, sum_kp fp32.
__global__ __launch_bounds__(256) void k_reduce2(
        const float* __restrict__ kvp, const float* __restrict__ skpp,
        short* __restrict__ kvbf, float* __restrict__ sum_kp) {
    int idx = blockIdx.x * 256 + threadIdx.x;
    if (idx < 65536) {
        int b = idx >> 11, rem = idx & 2047, dd = rem >> 5, m = rem & 31;
        float s = 0.f;
        for (int ch = 0; ch < 16; ++ch) s += kvp[((b * 16 + ch) * 64 + dd) * 32 + m];
        int dst = (((b * 2 + (m >> 4)) * 2 + ((m >> 3) & 1)) * 64 + dd) * 8 + (m & 7);
        kvbf[dst] = f2bf(s);
    } else if (idx < 65536 + 1024) {
        int i = idx - 65536;
        int b = i >> 5, m = i & 31;
        float s = 0.f;
        for (int ch = 0; ch < 16; ++ch) s += skpp[(b * 16 + ch) * 32 + m];
        sum_kp[i] = s;
    }
}

// ---------------------------------------------------------------------------
// Fused: yatt = (qp@kv^T)*rD -> proj+v+b -> LN2 -> w1+GELU -> w2 + skip.
// ---------------------------------------------------------------------------
__global__ __launch_bounds__(256) void k_fuse(
        const float* __restrict__ kqvT, const float* __restrict__ qpT,
        const short* __restrict__ kvbf, const float* __restrict__ sum_kp,
        const short* __restrict__ pTbf, const float* __restrict__ proj_b,
        const float* __restrict__ g2, const float* __restrict__ b2ln,
        const short* __restrict__ w1bf, const float* __restrict__ b1,
        const short* __restrict__ w2bf, const float* __restrict__ b2,
        float* __restrict__ out) {
    const int b = blockIdx.y;
    const int t0 = blockIdx.x * 64;
    const int tid = threadIdx.x;
    const int lane = tid & 63;
    const int cl = lane & 31;
    const int g  = lane >> 5;
    const int wv = tid >> 6;
    const int wr = wv & 1;
    const int wc = wv >> 1;

    __shared__ __align__(16) char pool[29952];
    short* qpS  = (short*)(pool + 0);
    short* ytS  = (short*)(pool + 5120);
    short* xnS  = (short*)(pool + 14336);
    short* hgS  = (short*)(pool + 0);
    float* outS = (float*)(pool + 9216);
    float* red  = (float*)(pool + 26624);
    float* stat = (float*)(pool + 27648);
    float* coefS= (float*)(pool + 28672);

    if (tid < 64) {
        coefS[tid]       = proj_b[tid];
        coefS[64 + tid]  = g2[tid];
        coefS[128 + tid] = b2ln[tid];
        coefS[192 + tid] = b1[tid];
        coefS[256 + tid] = b2[tid];
    }
    {
        const int t = tid & 63, q = tid >> 6;
        const float* sk = sum_kp + b * 32;
        float dsum = 0.f;
        short8 pk;
#pragma unroll
        for (int i = 0; i < 8; ++i) {
            int m = q * 8 + i;
            float v = qpT[((size_t)(b * 32 + m)) * TOK + t0 + t];
            dsum = fmaf(v, sk[m], dsum);
            pk[i] = f2bf(v);
        }
        *(short8*)(qpS + t * 40 + q * 8) = pk;
        red[t * 4 + q] = dsum;
    }
    __syncthreads();

    const int tl = wc * 32 + cl;
    const int tg = t0 + tl;
    const int rcol = wr * 32 + cl;

    f32x16 acc = {0.f, 0.f, 0.f, 0.f, 0.f, 0.f, 0.f, 0.f,
                  0.f, 0.f, 0.f, 0.f, 0.f, 0.f, 0.f, 0.f};
    {
        const short* Ab = kvbf + (size_t)b * 2048;
        short8 a0 = *(const short8*)(Ab + (g * 64 + rcol) * 8);
        short8 a1 = *(const short8*)(Ab + ((2 + g) * 64 + rcol) * 8);
        short8 b0 = *(const short8*)(qpS + tl * 40 + g * 8);
        short8 b1v = *(const short8*)(qpS + tl * 40 + 16 + g * 8);
        acc = __builtin_amdgcn_mfma_f32_32x32x16_bf16(a0, b0, acc, 0, 0, 0);
        acc = __builtin_amdgcn_mfma_f32_32x32x16_bf16(a1, b1v, acc, 0, 0, 0);
    }
    {
        float Dv = red[tl * 4 + 0] + red[tl * 4 + 1] + red[tl * 4 + 2] + red[tl * 4 + 3];
        float rD = 1.f / (Dv + 1e-8f);
#pragma unroll
        for (int rq = 0; rq < 4; ++rq) {
            int d0 = wr * 32 + 8 * rq + 4 * g;
            short4v p;
            p.x = f2bf(acc[rq * 4 + 0] * rD);
            p.y = f2bf(acc[rq * 4 + 1] * rD);
            p.z = f2bf(acc[rq * 4 + 2] * rD);
            p.w = f2bf(acc[rq * 4 + 3] * rD);
            *(short4v*)(ytS + tl * 72 + d0) = p;
        }
    }
    __syncthreads();

    f32x16 acc2 = {0.f, 0.f, 0.f, 0.f, 0.f, 0.f, 0.f, 0.f,
                   0.f, 0.f, 0.f, 0.f, 0.f, 0.f, 0.f, 0.f};
    {
#pragma unroll
        for (int ks = 0; ks < 4; ++ks) {
            short8 a = *(const short8*)(pTbf + ((ks * 2 + g) * 64 + rcol) * 8);
            short8 bb = *(const short8*)(ytS + tl * 72 + ks * 16 + g * 8);
            acc2 = __builtin_amdgcn_mfma_f32_32x32x16_bf16(a, bb, acc2, 0, 0, 0);
        }
    }
    float skv[16];
    {
        const float* vb = kqvT + ((size_t)(b * 192 + 128)) * TOK + tg;
#pragma unroll
        for (int reg = 0; reg < 16; ++reg) {
            int o = wr * 32 + (reg & 3) + 8 * (reg >> 2) + 4 * g;
            skv[reg] = acc2[reg] + vb[(size_t)o * TOK] + coefS[o];
        }
    }

    {
        float s1 = 0.f, s2 = 0.f;
#pragma unroll
        for (int reg = 0; reg < 16; ++reg) {
            s1 += skv[reg];
            s2 = fmaf(skv[reg], skv[reg], s2);
        }
        s1 += __shfl_xor(s1, 32, 64);
        s2 += __shfl_xor(s2, 32, 64);
        if (g == 0) {
            stat[(wr * 64 + tl) * 2 + 0] = s1;
            stat[(wr * 64 + tl) * 2 + 1] = s2;
        }
        __syncthreads();
        float S1 = s1 + stat[((wr ^ 1) * 64 + tl) * 2 + 0];
        float S2 = s2 + stat[((wr ^ 1) * 64 + tl) * 2 + 1];
        float mu = S1 * (1.f / 64.f);
        float var = S2 * (1.f / 64.f) - mu * mu;
        float rs = rsqrtf(fmaxf(var, 0.f) + 1e-5f);
#pragma unroll
        for (int rq = 0; rq < 4; ++rq) {
            int o0 = wr * 32 + 8 * rq + 4 * g;
            short4v p;
#pragma unroll
            for (int j = 0; j < 4; ++j) {
                int o = o0 + j;
                float xn = (skv[rq * 4 + j] - mu) * rs * coefS[64 + o] + coefS[128 + o];
                ((short*)&p)[j] = f2bf(xn);
            }
            *(short4v*)(xnS + tl * 72 + o0) = p;
        }
    }
    __syncthreads();

    f32x16 acc3 = {0.f, 0.f, 0.f, 0.f, 0.f, 0.f, 0.f, 0.f,
                   0.f, 0.f, 0.f, 0.f, 0.f, 0.f, 0.f, 0.f};
    {
#pragma unroll
        for (int ks = 0; ks < 4; ++ks) {
            short8 a = *(const short8*)(w1bf + ((ks * 2 + g) * 64 + rcol) * 8);
            short8 bb = *(const short8*)(xnS + tl * 72 + ks * 16 + g * 8);
            acc3 = __builtin_amdgcn_mfma_f32_32x32x16_bf16(a, bb, acc3, 0, 0, 0);
        }
    }
    __syncthreads();
    {
#pragma unroll
        for (int rq = 0; rq < 4; ++rq) {
            int i0 = wr * 32 + 8 * rq + 4 * g;
            short4v p;
#pragma unroll
            for (int j = 0; j < 4; ++j) {
                int i = i0 + j;
                float hgv = gelu_fast(acc3[rq * 4 + j] + coefS[192 + i]);
                ((short*)&p)[j] = f2bf(hgv);
            }
            *(short4v*)(hgS + tl * 72 + i0) = p;
        }
    }
    __syncthreads();

    f32x16 acc4 = {0.f, 0.f, 0.f, 0.f, 0.f, 0.f, 0.f, 0.f,
                   0.f, 0.f, 0.f, 0.f, 0.f, 0.f, 0.f, 0.f};
    {
#pragma unroll
        for (int ks = 0; ks < 4; ++ks) {
            short8 a = *(const short8*)(w2bf + ((ks * 2 + g) * 64 + rcol) * 8);
            short8 bb = *(const short8*)(hgS + tl * 72 + ks * 16 + g * 8);
            acc4 = __builtin_amdgcn_mfma_f32_32x32x16_bf16(a, bb, acc4, 0, 0, 0);
        }
    }
    {
#pragma unroll
        for (int rq = 0; rq < 4; ++rq) {
            int o0 = wr * 32 + 8 * rq + 4 * g;
            float4 f;
#pragma unroll
            for (int j = 0; j < 4; ++j) {
                int o = o0 + j;
                ((float*)&f)[j] = skv[rq * 4 + j] + acc4[rq * 4 + j] + coefS[256 + o];
            }
            *(float4*)(outS + tl * 68 + o0) = f;
        }
    }
    __syncthreads();

    {
        const int tt = tid >> 2, qq = tid & 3;
        float* ob = out + ((size_t)(b * TOK) + t0 + tt) * 64;
#pragma unroll
        for (int it = 0; it < 4; ++it) {
            *(float4*)(ob + it * 16 + qq * 4) =
                *(float4*)(outS + tt * 68 + it * 16 + qq * 4);
        }
    }
}

// ---------------------------------------------------------------------------
extern "C" void kernel_launch(void* const* d_in, const int* in_sizes, int n_in,
                              void* d_out, int out_size, void* d_ws, size_t ws_size,
                              hipStream_t stream) {
    const float* x      = (const float*)d_in[0];
    const float* conv_w = (const float*)d_in[1];
    const float* conv_b = (const float*)d_in[2];
    const float* ln1_g  = (const float*)d_in[3];
    const float* ln1_b  = (const float*)d_in[4];
    const float* kqv_w  = (const float*)d_in[5];
    const float* kqv_b  = (const float*)d_in[6];
    const float* proj_w = (const float*)d_in[7];
    const float* proj_b = (const float*)d_in[8];
    const float* w_perf = (const float*)d_in[9];
    const float* ln2_g  = (const float*)d_in[10];
    const float* ln2_b  = (const float*)d_in[11];
    const float* mlp_w1 = (const float*)d_in[12];
    const float* mlp_b1 = (const float*)d_in[13];
    const float* mlp_w2 = (const float*)d_in[14];
    const float* mlp_b2 = (const float*)d_in[15];

    float* ws = (float*)d_ws;
    short* w2c    = (short*)ws;                 // 110592 sh
    short* kwbf   = (short*)(ws + 55296);       // 36864 sh
    short* pTbf   = (short*)(ws + 73728);       // 4096 sh
    short* w1bf   = (short*)(ws + 75776);       // 4096 sh
    short* w2bf   = (short*)(ws + 77824);       // 4096 sh
    float* sum_kp = ws + 79872;                 // 1024 f
    short* kvbf   = (short*)(ws + 80896);       // 65536 sh
    short* tokens = (short*)(ws + 114688);      // 25165824 sh
    float* qpT    = ws + 114688;                // overlay after tokens dead
    float* kpT    = ws + 114688 + 4194304;
    float* skpp   = ws + 114688 + 8388608;
    float* kvp    = ws + 114688 + 8404992;
    float* kqvT   = ws + 114688 + 25165824;
    float* outp   = (float*)d_out;

    k_prep   <<<624, 256, 0, stream>>>(conv_w, kqv_w, proj_w, mlp_w1, mlp_w2,
                                       w2c, kwbf, pTbf, w1bf, w2bf);
    k_conv4  <<<6144, 256, 0, stream>>>(x, w2c, conv_b, tokens);
    k_lnkqv_mfma<<<dim3(64, 32), 256, 0, stream>>>(tokens, ln1_g, ln1_b, kwbf, kqv_b, kqvT);
    k_perf   <<<dim3(16, 32), 256, 0, stream>>>(kqvT, w_perf, kpT, qpT);
    k_kptv   <<<dim3(16, 32), 256, 0, stream>>>(kqvT, kpT, kvp, skpp);
    k_reduce2<<<260, 256, 0, stream>>>(kvp, skpp, kvbf, sum_kp);
    k_fuse   <<<dim3(64, 32), 256, 0, stream>>>(kqvT, qpT, kvbf, sum_kp,
                                                pTbf, proj_b, ln2_g, ln2_b,
                                                w1bf, mlp_b1, w2bf, mlp_b2, outp);
}

// Round 10
// 213.240 us; speedup vs baseline: 16.5602x; 1.1692x over previous
//
#include <hip/hip_runtime.h>
#include <hip/hip_bf16.h>

// ---------------------------------------------------------------------------
// BlockRC2: PRM (3 dilated stride-2 convs + GELU) -> LN1 -> kqv ->
// performer attention -> proj+skip -> LN2 -> MLP -> skip.
// Round 10: (1) conv K-loop branch-free (invalid rows staged as zeros) so the
// 36-MFMA loop fully unrolls and pipelines -- r9 showed latency-bound (all
// pipes <35%, occupancy 31%); (2) f2bf via __float2bfloat16 (HW cvt_pk)
// instead of integer bit-twiddle; (3) kqvT/qpT/kpT in bf16 (-110MB traffic).
// ---------------------------------------------------------------------------

#define TOK 4096
#define NB  32

typedef __attribute__((ext_vector_type(8)))  short short8;
typedef __attribute__((ext_vector_type(4)))  short short4v;
typedef __attribute__((ext_vector_type(16))) float f32x16;

// gelu(x) = x * sigmoid(x*(1.5957691216 + 0.0713548162 x^2)), max err ~3e-4.
__device__ __forceinline__ float gelu_fast(float v) {
    float u = v * fmaf(0.0713548162f, v * v, 1.5957691216f);
    float e = __expf(-u);
    return v * __builtin_amdgcn_rcpf(1.f + e);
}

__device__ __forceinline__ short f2bf(float f) {
    __hip_bfloat16 h = __float2bfloat16(f);   // RNE; HW v_cvt_pk on gfx950
    return *reinterpret_cast<short*>(&h);
}

__device__ __forceinline__ float bf2f(short s) {
    union { unsigned u; float f; } x;
    x.u = ((unsigned)(unsigned short)s) << 16;
    return x.f;
}

// ---------------------------------------------------------------------------
// Prep. MFMA-native layouts: frag element for lane (cl,g), reg j is
// W[col=cl][k = ks*16 + g*8 + j]  ->  stored at ((ks*2+g)*NCOL + col)*8 + j.
// ---------------------------------------------------------------------------
__global__ __launch_bounds__(256) void k_prep(
        const float* __restrict__ cw, const float* __restrict__ kw,
        const float* __restrict__ pw, const float* __restrict__ w1,
        const float* __restrict__ w2m,
        short* __restrict__ w2c, short* __restrict__ kwbf,
        short* __restrict__ pTbf, short* __restrict__ w1bf,
        short* __restrict__ w2bf) {
    int idx = blockIdx.x * 256 + threadIdx.x;
    if (idx < 110592) {
        int c = idx & 63;
        int t = idx >> 6;
        int e = t & 63;
        int tap = t >> 6;
        int kwi = tap % 3, t2 = tap / 3;
        int r = t2 % 3, brr = t2 / 3;
        float v = cw[(((brr * 64 + e) * 64 + c) * 3 + r) * 3 + kwi];
        int dst = ((((brr * 9 + r * 3 + kwi) * 4 + (c >> 4)) * 2 + ((c >> 3) & 1)) * 64 + e) * 8 + (c & 7);
        w2c[dst] = f2bf(v);
    } else if (idx < 147456) {
        int i2 = idx - 110592;
        int o = i2 / 192, i = i2 % 192;
        int dst = (((i >> 4) * 2 + ((i >> 3) & 1)) * 192 + o) * 8 + (i & 7);
        kwbf[dst] = f2bf(kw[i * 192 + o]);
    } else if (idx < 151552) {
        int i2 = idx - 147456;
        int o = i2 >> 6, d = i2 & 63;
        int dst = (((d >> 4) * 2 + ((d >> 3) & 1)) * 64 + o) * 8 + (d & 7);
        pTbf[dst] = f2bf(pw[d * 64 + o]);
    } else if (idx < 155648) {
        int i2 = idx - 151552;
        int i = i2 >> 6, jd = i2 & 63;
        int dst = (((jd >> 4) * 2 + ((jd >> 3) & 1)) * 64 + i) * 8 + (jd & 7);
        w1bf[dst] = f2bf(w1[jd * 64 + i]);
    } else if (idx < 159744) {
        int i2 = idx - 155648;
        int o = i2 >> 6, i = i2 & 63;
        int dst = (((i >> 4) * 2 + ((i >> 3) & 1)) * 64 + o) * 8 + (i & 7);
        w2bf[dst] = f2bf(w2m[i * 64 + o]);
    }
}

// ---------------------------------------------------------------------------
// Conv via MFMA. 6144 blocks 1D, XCD-swizzled (keeps FETCH at ~1.05x image).
// A: LDS bf16 swizzled tile; invalid ih rows staged as ZEROS so the K-loop
// is fully branch-free (36 MFMA straight-line -> compiler pipelines B loads
// and ds_reads). B: w2c MFMA-native from L1.
// ---------------------------------------------------------------------------
__global__ __launch_bounds__(256) void k_conv5(
        const float* __restrict__ x, const short* __restrict__ w2c,
        const float* __restrict__ cb, short* __restrict__ tokens) {
    const int wg  = blockIdx.x;
    const int swz_id = (wg & 7) * 768 + (wg >> 3);   // 6144 = 8*768, bijective
    const int b   = swz_id / 192;
    const int rem = swz_id - b * 192;
    const int oh  = rem / 3;
    const int br  = rem - oh * 3;
    const int d  = br + 1;
    const int tid = threadIdx.x;
    const int lane = tid & 63;
    const int wv = __builtin_amdgcn_readfirstlane(tid >> 6);
    const int cl = lane & 31;
    const int g  = lane >> 5;
    const int wm = wv & 1;
    const int wn = wv >> 1;

    __shared__ short sA[3 * 136 * 64];   // 52224 B

    // zero the 8 border columns per row (iw4 in {0..3,132..135}).
    {
        short8 z = {0, 0, 0, 0, 0, 0, 0, 0};
        for (int i = tid; i < 192; i += 256) {
            int sub = i & 7;
            int ci  = (i >> 3) & 7;
            int r   = i >> 6;
            int iw4 = (ci < 4) ? ci : (128 + ci);
            *(short8*)((char*)sA + (r * 136 + iw4) * 128 + sub * 16) = z;
        }
    }

    // stage 3 rows; invalid ih -> zero chunk (keeps K-loop branch-free).
    const int sub = lane & 7;
    const int rowoff = lane >> 3;
    for (int it = 0; it < 12; ++it) {
        const int i = wv * 12 + it;
        const int r = i >> 4;
        const int ch = i & 15;
        const int ih = 2 * oh + (r - 1) * d;
        const int iw4 = 4 + ch * 8 + rowoff;
        char* dst = (char*)sA + (r * 136 + iw4) * 128
                  + ((sub * 16) ^ (((iw4 >> 1) & 7) << 4));
        if ((unsigned)ih < 128u) {             // wave-uniform
            const float* src = x + ((size_t)(b * 16384 + ih * 128 + iw4 - 4)) * 64 + sub * 8;
            float4 f0 = *(const float4*)(src);
            float4 f1 = *(const float4*)(src + 4);
            short8 v;
            v[0] = f2bf(f0.x); v[1] = f2bf(f0.y); v[2] = f2bf(f0.z); v[3] = f2bf(f0.w);
            v[4] = f2bf(f1.x); v[5] = f2bf(f1.y); v[6] = f2bf(f1.z); v[7] = f2bf(f1.w);
            *(short8*)dst = v;
        } else {
            short8 z = {0, 0, 0, 0, 0, 0, 0, 0};
            *(short8*)dst = z;
        }
    }
    __syncthreads();

    f32x16 acc = {0.f, 0.f, 0.f, 0.f, 0.f, 0.f, 0.f, 0.f,
                  0.f, 0.f, 0.f, 0.f, 0.f, 0.f, 0.f, 0.f};
    const short* wbr = w2c + br * 9 * 4096;
    const int ow = wm * 32 + cl;
    const int ecol = wn * 32 + cl;

#pragma unroll
    for (int r = 0; r < 3; ++r) {
#pragma unroll
        for (int kwi = 0; kwi < 3; ++kwi) {
            const int iw4 = 2 * ow + (kwi - 1) * d + 4;   // in [1,133]
            const char* arow = (const char*)sA + (r * 136 + iw4) * 128;
            const int swz = ((iw4 >> 1) & 7) << 4;
            const short* wt = wbr + (r * 3 + kwi) * 4096;
#pragma unroll
            for (int ks = 0; ks < 4; ++ks) {
                short8 a = *(const short8*)(arow + ((ks * 32 + g * 16) ^ swz));
                short8 bf = *(const short8*)(wt + ((ks * 2 + g) * 64 + ecol) * 8);
                acc = __builtin_amdgcn_mfma_f32_32x32x16_bf16(a, bf, acc, 0, 0, 0);
            }
        }
    }

    const int eG = br * 64 + wn * 32 + cl;
    const float bias = cb[eG];
    short* outb = tokens + ((size_t)(b * TOK + oh * 64 + wm * 32)) * 192 + eG;
#pragma unroll
    for (int reg = 0; reg < 16; ++reg) {
        int owl = (reg & 3) + 8 * (reg >> 2) + 4 * g;
        outb[(size_t)owl * 192] = f2bf(gelu_fast(acc[reg] + bias));
    }
}

// ---------------------------------------------------------------------------
// LN1 + kqv via MFMA; tokens bf16 in; kqvT bf16 out.
// ---------------------------------------------------------------------------
__global__ __launch_bounds__(256) void k_lnkqv_mfma(
        const short* __restrict__ tokens, const float* __restrict__ g,
        const float* __restrict__ be, const short* __restrict__ wbf,
        const float* __restrict__ bias, short* __restrict__ kqvT) {
    const int b = blockIdx.y;
    const int t0 = blockIdx.x * 64;
    const int tid = threadIdx.x;

    __shared__ short sB[64 * 192];
    __shared__ float red[64 * 8];

    const int r = tid >> 2, q = tid & 3;
    const short* rowp = tokens + ((size_t)(b * TOK + t0 + r)) * 192 + q * 48;
    float v[48];
    float s1 = 0.f, s2 = 0.f;
#pragma unroll
    for (int i = 0; i < 6; ++i) {
        short8 x8 = *(const short8*)(rowp + i * 8);
#pragma unroll
        for (int j = 0; j < 8; ++j) {
            float f = bf2f(x8[j]);
            v[i * 8 + j] = f;
            s1 += f;
            s2 = fmaf(f, f, s2);
        }
    }
    red[r * 8 + q] = s1;
    red[r * 8 + 4 + q] = s2;
    __syncthreads();
    const float m1 = red[r * 8 + 0] + red[r * 8 + 1] + red[r * 8 + 2] + red[r * 8 + 3];
    const float m2 = red[r * 8 + 4] + red[r * 8 + 5] + red[r * 8 + 6] + red[r * 8 + 7];
    const float mu = m1 * (1.f / 192.f);
    const float var = m2 * (1.f / 192.f) - mu * mu;
    const float rs = rsqrtf(fmaxf(var, 0.f) + 1e-5f);
    const float4* g4 = (const float4*)(g + q * 48);
    const float4* b4 = (const float4*)(be + q * 48);
    char* rowB = (char*)sB + r * 384;
    const int swz = (r & 7) << 4;
#pragma unroll
    for (int i = 0; i < 12; ++i) {
        float4 gg = g4[i], bb = b4[i];
        short4v pk;
        pk.x = f2bf((v[4 * i + 0] - mu) * rs * gg.x + bb.x);
        pk.y = f2bf((v[4 * i + 1] - mu) * rs * gg.y + bb.y);
        pk.z = f2bf((v[4 * i + 2] - mu) * rs * gg.z + bb.z);
        pk.w = f2bf((v[4 * i + 3] - mu) * rs * gg.w + bb.w);
        *(short4v*)(rowB + (((q * 48 + i * 4) * 2) ^ swz)) = pk;
    }
    __syncthreads();

    const int lane = tid & 63;
    const int wv = tid >> 6;
    const int tt = wv & 1;
    const int wo = wv >> 1;
    const int colL = lane & 31;
    const int gq = lane >> 5;

    f32x16 acc0 = {0.f, 0.f, 0.f, 0.f, 0.f, 0.f, 0.f, 0.f,
                   0.f, 0.f, 0.f, 0.f, 0.f, 0.f, 0.f, 0.f};
    f32x16 acc1 = acc0, acc2 = acc0;
    const char* bbase = (const char*)sB + (tt * 32 + colL) * 384;
    const int bswz = ((tt * 32 + colL) & 7) << 4;
    const int ocol = wo * 32 + colL;

    for (int kk = 0; kk < 12; ++kk) {
        short8 bf = *(const short8*)(bbase + (((kk * 16 + gq * 8) * 2) ^ bswz));
        const short* ak = wbf + ((kk * 2 + gq) * 192 + ocol) * 8;
        short8 a0 = *(const short8*)(ak);
        short8 a1 = *(const short8*)(ak + 64 * 8);
        short8 a2 = *(const short8*)(ak + 128 * 8);
        acc0 = __builtin_amdgcn_mfma_f32_32x32x16_bf16(a0, bf, acc0, 0, 0, 0);
        acc1 = __builtin_amdgcn_mfma_f32_32x32x16_bf16(a1, bf, acc1, 0, 0, 0);
        acc2 = __builtin_amdgcn_mfma_f32_32x32x16_bf16(a2, bf, acc2, 0, 0, 0);
    }

    const int tglob = t0 + tt * 32 + colL;
    short* outb = kqvT + (size_t)b * 192 * TOK + tglob;
#pragma unroll
    for (int j = 0; j < 3; ++j) {
        const int obase = (wo + 2 * j) * 32;
        const f32x16 ac = (j == 0 ? acc0 : j == 1 ? acc1 : acc2);
#pragma unroll
        for (int reg = 0; reg < 16; ++reg) {
            int orow = (reg & 3) + 8 * (reg >> 2) + 4 * gq;
            outb[(size_t)(obase + orow) * TOK] = f2bf(ac[reg] + bias[obase + orow]);
        }
    }
}

// ---------------------------------------------------------------------------
// Performer features; kqvT bf16 in, kpT/qpT bf16 out.
// ---------------------------------------------------------------------------
__global__ __launch_bounds__(256) void k_perf(
        const short* __restrict__ kqvT, const float* __restrict__ wperf,
        short* __restrict__ kpT, short* __restrict__ qpT) {
    const int b = blockIdx.y;
    const int t = blockIdx.x * 256 + threadIdx.x;
    const short* basek = kqvT + (size_t)b * 192 * TOK + t;
    for (int pass = 0; pass < 2; ++pass) {
        float kr[64];
        const short* src = basek + (size_t)pass * 64 * TOK;
#pragma unroll
        for (int i = 0; i < 64; ++i) kr[i] = bf2f(src[(size_t)i * TOK]);
        float xd = 0.f;
#pragma unroll
        for (int i = 0; i < 64; ++i) xd = fmaf(kr[i], kr[i], xd);
        xd *= 0.5f;
        short* dst = (pass == 0 ? kpT : qpT) + (size_t)b * 32 * TOK + t;
        for (int m = 0; m < 32; ++m) {
            const float* wr = wperf + m * 64;
            float a = 0.f;
#pragma unroll
            for (int i = 0; i < 64; ++i) a = fmaf(wr[i], kr[i], a);
            dst[(size_t)m * TOK] = f2bf(expf(a - xd) * 0.17677669529663687f);
        }
    }
}

// ---------------------------------------------------------------------------
// kptv chunk partials; kqvT/kpT bf16 in (converted on LDS stage).
// ---------------------------------------------------------------------------
__global__ __launch_bounds__(256) void k_kptv(
        const short* __restrict__ kqvT, const short* __restrict__ kpT,
        float* __restrict__ kvp, float* __restrict__ skpp) {
    const int b = blockIdx.y, ch = blockIdx.x, tid = threadIdx.x;
    const int t = ch * 256 + tid;
    __shared__ float sv[256 * 65 + 256 * 36];
    float* skp = sv + 256 * 65;
    for (int dd = 0; dd < 64; ++dd)
        sv[tid * 65 + dd] = bf2f(kqvT[((size_t)(b * 192 + 128 + dd)) * TOK + t]);
    for (int m = 0; m < 32; ++m)
        skp[tid * 36 + m] = bf2f(kpT[((size_t)(b * 32 + m)) * TOK + t]);
    __syncthreads();

    const int dd = tid & 63;
    const int mg = __builtin_amdgcn_readfirstlane(tid >> 6);
    float acc[8];
#pragma unroll
    for (int j = 0; j < 8; ++j) acc[j] = 0.f;
    for (int tt = 0; tt < 256; ++tt) {
        float vv = sv[tt * 65 + dd];
        const float4* kq = (const float4*)(skp + tt * 36 + mg * 8);
        float4 a0 = kq[0], a1 = kq[1];
        acc[0] = fmaf(vv, a0.x, acc[0]);
        acc[1] = fmaf(vv, a0.y, acc[1]);
        acc[2] = fmaf(vv, a0.z, acc[2]);
        acc[3] = fmaf(vv, a0.w, acc[3]);
        acc[4] = fmaf(vv, a1.x, acc[4]);
        acc[5] = fmaf(vv, a1.y, acc[5]);
        acc[6] = fmaf(vv, a1.z, acc[6]);
        acc[7] = fmaf(vv, a1.w, acc[7]);
    }
    float* dst = kvp + (((size_t)(b * 16 + ch) * 64 + dd) * 32) + mg * 8;
#pragma unroll
    for (int j = 0; j < 8; ++j) dst[j] = acc[j];

    if (tid < 32) {
        float s = 0.f;
        for (int tt = 0; tt < 256; ++tt) s += skp[tt * 36 + tid];
        skpp[(b * 16 + ch) * 32 + tid] = s;
    }
}

// Reduce partials -> kvbf MFMA-native [b][ms][g][d][8m] bf16, sum_kp fp32.
__global__ __launch_bounds__(256) void k_reduce2(
        const float* __restrict__ kvp, const float* __restrict__ skpp,
        short* __restrict__ kvbf, float* __restrict__ sum_kp) {
    int idx = blockIdx.x * 256 + threadIdx.x;
    if (idx < 65536) {
        int b = idx >> 11, rem = idx & 2047, dd = rem >> 5, m = rem & 31;
        float s = 0.f;
        for (int ch = 0; ch < 16; ++ch) s += kvp[((b * 16 + ch) * 64 + dd) * 32 + m];
        int dst = (((b * 2 + (m >> 4)) * 2 + ((m >> 3) & 1)) * 64 + dd) * 8 + (m & 7);
        kvbf[dst] = f2bf(s);
    } else if (idx < 65536 + 1024) {
        int i = idx - 65536;
        int b = i >> 5, m = i & 31;
        float s = 0.f;
        for (int ch = 0; ch < 16; ++ch) s += skpp[(b * 16 + ch) * 32 + m];
        sum_kp[i] = s;
    }
}

// ---------------------------------------------------------------------------
// Fused: yatt = (qp@kv^T)*rD -> proj+v+b -> LN2 -> w1+GELU -> w2 + skip.
// kqvT/qpT bf16 in (qp now loads raw bf16 straight into LDS - no convert).
// ---------------------------------------------------------------------------
__global__ __launch_bounds__(256) void k_fuse(
        const short* __restrict__ kqvT, const short* __restrict__ qpT,
        const short* __restrict__ kvbf, const float* __restrict__ sum_kp,
        const short* __restrict__ pTbf, const float* __restrict__ proj_b,
        const float* __restrict__ g2, const float* __restrict__ b2ln,
        const short* __restrict__ w1bf, const float* __restrict__ b1,
        const short* __restrict__ w2bf, const float* __restrict__ b2,
        float* __restrict__ out) {
    const int b = blockIdx.y;
    const int t0 = blockIdx.x * 64;
    const int tid = threadIdx.x;
    const int lane = tid & 63;
    const int cl = lane & 31;
    const int g  = lane >> 5;
    const int wv = tid >> 6;
    const int wr = wv & 1;
    const int wc = wv >> 1;

    __shared__ __align__(16) char pool[29952];
    short* qpS  = (short*)(pool + 0);
    short* ytS  = (short*)(pool + 5120);
    short* xnS  = (short*)(pool + 14336);
    short* hgS  = (short*)(pool + 0);
    float* outS = (float*)(pool + 9216);
    float* red  = (float*)(pool + 26624);
    float* stat = (float*)(pool + 27648);
    float* coefS= (float*)(pool + 28672);

    if (tid < 64) {
        coefS[tid]       = proj_b[tid];
        coefS[64 + tid]  = g2[tid];
        coefS[128 + tid] = b2ln[tid];
        coefS[192 + tid] = b1[tid];
        coefS[256 + tid] = b2[tid];
    }
    {
        const int t = tid & 63, q = tid >> 6;
        const float* sk = sum_kp + b * 32;
        float dsum = 0.f;
        short8 pk;
#pragma unroll
        for (int i = 0; i < 8; ++i) {
            int m = q * 8 + i;
            short s = qpT[((size_t)(b * 32 + m)) * TOK + t0 + t];
            dsum = fmaf(bf2f(s), sk[m], dsum);
            pk[i] = s;
        }
        *(short8*)(qpS + t * 40 + q * 8) = pk;
        red[t * 4 + q] = dsum;
    }
    __syncthreads();

    const int tl = wc * 32 + cl;
    const int tg = t0 + tl;
    const int rcol = wr * 32 + cl;

    f32x16 acc = {0.f, 0.f, 0.f, 0.f, 0.f, 0.f, 0.f, 0.f,
                  0.f, 0.f, 0.f, 0.f, 0.f, 0.f, 0.f, 0.f};
    {
        const short* Ab = kvbf + (size_t)b * 2048;
        short8 a0 = *(const short8*)(Ab + (g * 64 + rcol) * 8);
        short8 a1 = *(const short8*)(Ab + ((2 + g) * 64 + rcol) * 8);
        short8 b0 = *(const short8*)(qpS + tl * 40 + g * 8);
        short8 b1v = *(const short8*)(qpS + tl * 40 + 16 + g * 8);
        acc = __builtin_amdgcn_mfma_f32_32x32x16_bf16(a0, b0, acc, 0, 0, 0);
        acc = __builtin_amdgcn_mfma_f32_32x32x16_bf16(a1, b1v, acc, 0, 0, 0);
    }
    {
        float Dv = red[tl * 4 + 0] + red[tl * 4 + 1] + red[tl * 4 + 2] + red[tl * 4 + 3];
        float rD = 1.f / (Dv + 1e-8f);
#pragma unroll
        for (int rq = 0; rq < 4; ++rq) {
            int d0 = wr * 32 + 8 * rq + 4 * g;
            short4v p;
            p.x = f2bf(acc[rq * 4 + 0] * rD);
            p.y = f2bf(acc[rq * 4 + 1] * rD);
            p.z = f2bf(acc[rq * 4 + 2] * rD);
            p.w = f2bf(acc[rq * 4 + 3] * rD);
            *(short4v*)(ytS + tl * 72 + d0) = p;
        }
    }
    __syncthreads();

    f32x16 acc2 = {0.f, 0.f, 0.f, 0.f, 0.f, 0.f, 0.f, 0.f,
                   0.f, 0.f, 0.f, 0.f, 0.f, 0.f, 0.f, 0.f};
    {
#pragma unroll
        for (int ks = 0; ks < 4; ++ks) {
            short8 a = *(const short8*)(pTbf + ((ks * 2 + g) * 64 + rcol) * 8);
            short8 bb = *(const short8*)(ytS + tl * 72 + ks * 16 + g * 8);
            acc2 = __builtin_amdgcn_mfma_f32_32x32x16_bf16(a, bb, acc2, 0, 0, 0);
        }
    }
    float skv[16];
    {
        const short* vb = kqvT + ((size_t)(b * 192 + 128)) * TOK + tg;
#pragma unroll
        for (int reg = 0; reg < 16; ++reg) {
            int o = wr * 32 + (reg & 3) + 8 * (reg >> 2) + 4 * g;
            skv[reg] = acc2[reg] + bf2f(vb[(size_t)o * TOK]) + coefS[o];
        }
    }

    {
        float s1 = 0.f, s2 = 0.f;
#pragma unroll
        for (int reg = 0; reg < 16; ++reg) {
            s1 += skv[reg];
            s2 = fmaf(skv[reg], skv[reg], s2);
        }
        s1 += __shfl_xor(s1, 32, 64);
        s2 += __shfl_xor(s2, 32, 64);
        if (g == 0) {
            stat[(wr * 64 + tl) * 2 + 0] = s1;
            stat[(wr * 64 + tl) * 2 + 1] = s2;
        }
        __syncthreads();
        float S1 = s1 + stat[((wr ^ 1) * 64 + tl) * 2 + 0];
        float S2 = s2 + stat[((wr ^ 1) * 64 + tl) * 2 + 1];
        float mu = S1 * (1.f / 64.f);
        float var = S2 * (1.f / 64.f) - mu * mu;
        float rs = rsqrtf(fmaxf(var, 0.f) + 1e-5f);
#pragma unroll
        for (int rq = 0; rq < 4; ++rq) {
            int o0 = wr * 32 + 8 * rq + 4 * g;
            short4v p;
#pragma unroll
            for (int j = 0; j < 4; ++j) {
                int o = o0 + j;
                float xn = (skv[rq * 4 + j] - mu) * rs * coefS[64 + o] + coefS[128 + o];
                ((short*)&p)[j] = f2bf(xn);
            }
            *(short4v*)(xnS + tl * 72 + o0) = p;
        }
    }
    __syncthreads();

    f32x16 acc3 = {0.f, 0.f, 0.f, 0.f, 0.f, 0.f, 0.f, 0.f,
                   0.f, 0.f, 0.f, 0.f, 0.f, 0.f, 0.f, 0.f};
    {
#pragma unroll
        for (int ks = 0; ks < 4; ++ks) {
            short8 a = *(const short8*)(w1bf + ((ks * 2 + g) * 64 + rcol) * 8);
            short8 bb = *(const short8*)(xnS + tl * 72 + ks * 16 + g * 8);
            acc3 = __builtin_amdgcn_mfma_f32_32x32x16_bf16(a, bb, acc3, 0, 0, 0);
        }
    }
    __syncthreads();
    {
#pragma unroll
        for (int rq = 0; rq < 4; ++rq) {
            int i0 = wr * 32 + 8 * rq + 4 * g;
            short4v p;
#pragma unroll
            for (int j = 0; j < 4; ++j) {
                int i = i0 + j;
                float hgv = gelu_fast(acc3[rq * 4 + j] + coefS[192 + i]);
                ((short*)&p)[j] = f2bf(hgv);
            }
            *(short4v*)(hgS + tl * 72 + i0) = p;
        }
    }
    __syncthreads();

    f32x16 acc4 = {0.f, 0.f, 0.f, 0.f, 0.f, 0.f, 0.f, 0.f,
                   0.f, 0.f, 0.f, 0.f, 0.f, 0.f, 0.f, 0.f};
    {
#pragma unroll
        for (int ks = 0; ks < 4; ++ks) {
            short8 a = *(const short8*)(w2bf + ((ks * 2 + g) * 64 + rcol) * 8);
            short8 bb = *(const short8*)(hgS + tl * 72 + ks * 16 + g * 8);
            acc4 = __builtin_amdgcn_mfma_f32_32x32x16_bf16(a, bb, acc4, 0, 0, 0);
        }
    }
    {
#pragma unroll
        for (int rq = 0; rq < 4; ++rq) {
            int o0 = wr * 32 + 8 * rq + 4 * g;
            float4 f;
#pragma unroll
            for (int j = 0; j < 4; ++j) {
                int o = o0 + j;
                ((float*)&f)[j] = skv[rq * 4 + j] + acc4[rq * 4 + j] + coefS[256 + o];
            }
            *(float4*)(outS + tl * 68 + o0) = f;
        }
    }
    __syncthreads();

    {
        const int tt = tid >> 2, qq = tid & 3;
        float* ob = out + ((size_t)(b * TOK) + t0 + tt) * 64;
#pragma unroll
        for (int it = 0; it < 4; ++it) {
            *(float4*)(ob + it * 16 + qq * 4) =
                *(float4*)(outS + tt * 68 + it * 16 + qq * 4);
        }
    }
}

// ---------------------------------------------------------------------------
extern "C" void kernel_launch(void* const* d_in, const int* in_sizes, int n_in,
                              void* d_out, int out_size, void* d_ws, size_t ws_size,
                              hipStream_t stream) {
    const float* x      = (const float*)d_in[0];
    const float* conv_w = (const float*)d_in[1];
    const float* conv_b = (const float*)d_in[2];
    const float* ln1_g  = (const float*)d_in[3];
    const float* ln1_b  = (const float*)d_in[4];
    const float* kqv_w  = (const float*)d_in[5];
    const float* kqv_b  = (const float*)d_in[6];
    const float* proj_w = (const float*)d_in[7];
    const float* proj_b = (const float*)d_in[8];
    const float* w_perf = (const float*)d_in[9];
    const float* ln2_g  = (const float*)d_in[10];
    const float* ln2_b  = (const float*)d_in[11];
    const float* mlp_w1 = (const float*)d_in[12];
    const float* mlp_b1 = (const float*)d_in[13];
    const float* mlp_w2 = (const float*)d_in[14];
    const float* mlp_b2 = (const float*)d_in[15];

    float* ws = (float*)d_ws;
    short* w2c    = (short*)ws;                 // 110592 sh
    short* kwbf   = (short*)(ws + 55296);       // 36864 sh
    short* pTbf   = (short*)(ws + 73728);       // 4096 sh
    short* w1bf   = (short*)(ws + 75776);       // 4096 sh
    short* w2bf   = (short*)(ws + 77824);       // 4096 sh
    float* sum_kp = ws + 79872;                 // 1024 f
    short* kvbf   = (short*)(ws + 80896);       // 65536 sh -> ends 113664
    // region A: tokens bf16 (dead after lnkqv), overlaid by qpT/kpT/kvp
    short* tokens = (short*)(ws + 114688);      // 25165824 sh (12582912 f)
    short* qpT    = (short*)(ws + 114688);      // 4194304 sh (overlay)
    short* kpT    = (short*)(ws + 114688 + 2097152);   // 4194304 sh
    float* skpp   = ws + 114688 + 4194304;      // 16384 f
    float* kvp    = ws + 114688 + 4210688;      // 1048576 f
    // region B: kqvT bf16 (after tokens region)
    short* kqvT   = (short*)(ws + 12697600);    // 25165824 sh
    float* outp   = (float*)d_out;

    k_prep   <<<624, 256, 0, stream>>>(conv_w, kqv_w, proj_w, mlp_w1, mlp_w2,
                                       w2c, kwbf, pTbf, w1bf, w2bf);
    k_conv5  <<<6144, 256, 0, stream>>>(x, w2c, conv_b, tokens);
    k_lnkqv_mfma<<<dim3(64, 32), 256, 0, stream>>>(tokens, ln1_g, ln1_b, kwbf, kqv_b, kqvT);
    k_perf   <<<dim3(16, 32), 256, 0, stream>>>(kqvT, w_perf, kpT, qpT);
    k_kptv   <<<dim3(16, 32), 256, 0, stream>>>(kqvT, kpT, kvp, skpp);
    k_reduce2<<<260, 256, 0, stream>>>(kvp, skpp, kvbf, sum_kp);
    k_fuse   <<<dim3(64, 32), 256, 0, stream>>>(kqvT, qpT, kvbf, sum_kp,
                                                pTbf, proj_b, ln2_g, ln2_b,
                                                w1bf, mlp_b1, w2bf, mlp_b2, outp);
}

// Round 11
// 206.569 us; speedup vs baseline: 17.0950x; 1.0323x over previous
//
#include <hip/hip_runtime.h>
#include <hip/hip_bf16.h>

// ---------------------------------------------------------------------------
// BlockRC2: PRM (3 dilated stride-2 convs + GELU) -> LN1 -> kqv ->
// performer attention -> proj+skip -> LN2 -> MLP -> skip.
// Round 11: conv LDS tile halved via c-split 2-phase K-loop (26112 B ->
// 6 blocks/CU = 24 waves, was 52224 B -> 3 blocks/CU = 12 waves). r10 showed
// conv latency-bound: all pipes <20% busy at 31% occupancy. Same swizzle
// structure ([r][i][p][32c], XOR (i&7)<<4 within 128B rows), same staging
// coalescing, 2 extra barriers.
// ---------------------------------------------------------------------------

#define TOK 4096
#define NB  32

typedef __attribute__((ext_vector_type(8)))  short short8;
typedef __attribute__((ext_vector_type(4)))  short short4v;
typedef __attribute__((ext_vector_type(16))) float f32x16;

// gelu(x) = x * sigmoid(x*(1.5957691216 + 0.0713548162 x^2)), max err ~3e-4.
__device__ __forceinline__ float gelu_fast(float v) {
    float u = v * fmaf(0.0713548162f, v * v, 1.5957691216f);
    float e = __expf(-u);
    return v * __builtin_amdgcn_rcpf(1.f + e);
}

__device__ __forceinline__ short f2bf(float f) {
    __hip_bfloat16 h = __float2bfloat16(f);   // RNE; HW cvt on gfx950
    return *reinterpret_cast<short*>(&h);
}

__device__ __forceinline__ float bf2f(short s) {
    union { unsigned u; float f; } x;
    x.u = ((unsigned)(unsigned short)s) << 16;
    return x.f;
}

// ---------------------------------------------------------------------------
// Prep. MFMA-native layouts: frag element for lane (cl,g), reg j is
// W[col=cl][k = ks*16 + g*8 + j]  ->  stored at ((ks*2+g)*NCOL + col)*8 + j.
// ---------------------------------------------------------------------------
__global__ __launch_bounds__(256) void k_prep(
        const float* __restrict__ cw, const float* __restrict__ kw,
        const float* __restrict__ pw, const float* __restrict__ w1,
        const float* __restrict__ w2m,
        short* __restrict__ w2c, short* __restrict__ kwbf,
        short* __restrict__ pTbf, short* __restrict__ w1bf,
        short* __restrict__ w2bf) {
    int idx = blockIdx.x * 256 + threadIdx.x;
    if (idx < 110592) {
        int c = idx & 63;
        int t = idx >> 6;
        int e = t & 63;
        int tap = t >> 6;
        int kwi = tap % 3, t2 = tap / 3;
        int r = t2 % 3, brr = t2 / 3;
        float v = cw[(((brr * 64 + e) * 64 + c) * 3 + r) * 3 + kwi];
        int dst = ((((brr * 9 + r * 3 + kwi) * 4 + (c >> 4)) * 2 + ((c >> 3) & 1)) * 64 + e) * 8 + (c & 7);
        w2c[dst] = f2bf(v);
    } else if (idx < 147456) {
        int i2 = idx - 110592;
        int o = i2 / 192, i = i2 % 192;
        int dst = (((i >> 4) * 2 + ((i >> 3) & 1)) * 192 + o) * 8 + (i & 7);
        kwbf[dst] = f2bf(kw[i * 192 + o]);
    } else if (idx < 151552) {
        int i2 = idx - 147456;
        int o = i2 >> 6, d = i2 & 63;
        int dst = (((d >> 4) * 2 + ((d >> 3) & 1)) * 64 + o) * 8 + (d & 7);
        pTbf[dst] = f2bf(pw[d * 64 + o]);
    } else if (idx < 155648) {
        int i2 = idx - 151552;
        int i = i2 >> 6, jd = i2 & 63;
        int dst = (((jd >> 4) * 2 + ((jd >> 3) & 1)) * 64 + i) * 8 + (jd & 7);
        w1bf[dst] = f2bf(w1[jd * 64 + i]);
    } else if (idx < 159744) {
        int i2 = idx - 155648;
        int o = i2 >> 6, i = i2 & 63;
        int dst = (((i >> 4) * 2 + ((i >> 3) & 1)) * 64 + o) * 8 + (i & 7);
        w2bf[dst] = f2bf(w2m[i * 64 + o]);
    }
}

// ---------------------------------------------------------------------------
// Conv via MFMA, c-split 2-phase. 6144 blocks XCD-swizzled, 4 waves.
// LDS sA[r=3][i=68][p=2][32c] bf16 = 26112 B -> 6 blocks/CU (24 waves).
// Row = 128B (i-index); XOR swizzle ((i&7)<<4) across the 8 16B slots.
// iw4 = iw+4; i = iw4>>1, p = iw4&1 (tap parity is constant per tap).
// Phase h: stage c in [32h,32h+32), 18 MFMA (ks=2h,2h+1), barrier.
// ---------------------------------------------------------------------------
__global__ __launch_bounds__(256) void k_conv6(
        const float* __restrict__ x, const short* __restrict__ w2c,
        const float* __restrict__ cb, short* __restrict__ tokens) {
    const int wg  = blockIdx.x;
    const int swz_id = (wg & 7) * 768 + (wg >> 3);   // 6144 = 8*768, bijective
    const int b   = swz_id / 192;
    const int rem = swz_id - b * 192;
    const int oh  = rem / 3;
    const int br  = rem - oh * 3;
    const int d   = br + 1;
    const int tid = threadIdx.x;
    const int lane = tid & 63;
    const int wv = tid >> 6;
    const int cl = lane & 31;
    const int g  = lane >> 5;
    const int wm = wv & 1;
    const int wn = wv >> 1;

    __shared__ short sA[3 * 68 * 2 * 32];   // 26112 B

    const int ow = wm * 32 + cl;
    const int ecol = wn * 32 + cl;
    const short* wbr = w2c + br * 9 * 4096;

    f32x16 acc = {0.f, 0.f, 0.f, 0.f, 0.f, 0.f, 0.f, 0.f,
                  0.f, 0.f, 0.f, 0.f, 0.f, 0.f, 0.f, 0.f};

    for (int h = 0; h < 2; ++h) {
        // border zero (once): i in {0,1,66,67}, all 8 slots, 3 rows = 96x16B
        if (h == 0 && tid < 96) {
            int s16 = tid & 7;
            int ii  = (tid >> 3) & 3;
            int r   = tid >> 5;
            int i   = (ii < 2) ? ii : (64 + ii);
            short8 z = {0, 0, 0, 0, 0, 0, 0, 0};
            *(short8*)((char*)sA + (r * 68 + i) * 128 + s16 * 16) = z;
        }
        // stage: [r(3)][iw(128)][c8l(4)] = 1536 dsts, 6 iters/thread.
        // src 128B-contiguous per iw (4 consecutive c8l), aligned (h*128B).
        for (int it = 0; it < 6; ++it) {
            int flat = it * 256 + tid;
            int c8l = flat & 3;
            int iw  = (flat >> 2) & 127;
            int r   = flat >> 9;
            int ih  = 2 * oh + (r - 1) * d;
            int iw4 = iw + 4;
            int i   = iw4 >> 1;
            int p   = iw4 & 1;
            char* dst = (char*)sA + (r * 68 + i) * 128
                      + ((((p * 4 + c8l) * 16)) ^ ((i & 7) << 4));
            if ((unsigned)ih < 128u) {             // wave-varying ok (exec mask)
                const float* src = x + ((size_t)(b * 16384 + ih * 128 + iw)) * 64
                                 + h * 32 + c8l * 8;
                float4 f0 = *(const float4*)(src);
                float4 f1 = *(const float4*)(src + 4);
                short8 v;
                v[0] = f2bf(f0.x); v[1] = f2bf(f0.y); v[2] = f2bf(f0.z); v[3] = f2bf(f0.w);
                v[4] = f2bf(f1.x); v[5] = f2bf(f1.y); v[6] = f2bf(f1.z); v[7] = f2bf(f1.w);
                *(short8*)dst = v;
            } else {
                short8 z = {0, 0, 0, 0, 0, 0, 0, 0};
                *(short8*)dst = z;
            }
        }
        __syncthreads();

        // compute: 9 taps x 2 ks (K = 32 c of this half), branch-free
#pragma unroll
        for (int r = 0; r < 3; ++r) {
#pragma unroll
            for (int kwi = 0; kwi < 3; ++kwi) {
                const int iw4 = 2 * ow + (kwi - 1) * d + 4;   // in [1,133]
                const int i   = iw4 >> 1;
                const int p   = iw4 & 1;
                const char* arow = (const char*)sA + (r * 68 + i) * 128;
                const int swzk = (i & 7) << 4;
                const short* wt = wbr + (r * 3 + kwi) * 4096;
#pragma unroll
                for (int kk = 0; kk < 2; ++kk) {
                    const int ks = h * 2 + kk;
                    short8 a = *(const short8*)(arow + ((((p * 4 + kk * 2 + g) * 16)) ^ swzk));
                    short8 bf = *(const short8*)(wt + ((ks * 2 + g) * 64 + ecol) * 8);
                    acc = __builtin_amdgcn_mfma_f32_32x32x16_bf16(a, bf, acc, 0, 0, 0);
                }
            }
        }
        __syncthreads();
    }

    const int eG = br * 64 + wn * 32 + cl;
    const float bias = cb[eG];
    short* outb = tokens + ((size_t)(b * TOK + oh * 64 + wm * 32)) * 192 + eG;
#pragma unroll
    for (int reg = 0; reg < 16; ++reg) {
        int owl = (reg & 3) + 8 * (reg >> 2) + 4 * g;
        outb[(size_t)owl * 192] = f2bf(gelu_fast(acc[reg] + bias));
    }
}

// ---------------------------------------------------------------------------
// LN1 + kqv via MFMA; tokens bf16 in; kqvT bf16 out.
// ---------------------------------------------------------------------------
__global__ __launch_bounds__(256) void k_lnkqv_mfma(
        const short* __restrict__ tokens, const float* __restrict__ g,
        const float* __restrict__ be, const short* __restrict__ wbf,
        const float* __restrict__ bias, short* __restrict__ kqvT) {
    const int b = blockIdx.y;
    const int t0 = blockIdx.x * 64;
    const int tid = threadIdx.x;

    __shared__ short sB[64 * 192];
    __shared__ float red[64 * 8];

    const int r = tid >> 2, q = tid & 3;
    const short* rowp = tokens + ((size_t)(b * TOK + t0 + r)) * 192 + q * 48;
    float v[48];
    float s1 = 0.f, s2 = 0.f;
#pragma unroll
    for (int i = 0; i < 6; ++i) {
        short8 x8 = *(const short8*)(rowp + i * 8);
#pragma unroll
        for (int j = 0; j < 8; ++j) {
            float f = bf2f(x8[j]);
            v[i * 8 + j] = f;
            s1 += f;
            s2 = fmaf(f, f, s2);
        }
    }
    red[r * 8 + q] = s1;
    red[r * 8 + 4 + q] = s2;
    __syncthreads();
    const float m1 = red[r * 8 + 0] + red[r * 8 + 1] + red[r * 8 + 2] + red[r * 8 + 3];
    const float m2 = red[r * 8 + 4] + red[r * 8 + 5] + red[r * 8 + 6] + red[r * 8 + 7];
    const float mu = m1 * (1.f / 192.f);
    const float var = m2 * (1.f / 192.f) - mu * mu;
    const float rs = rsqrtf(fmaxf(var, 0.f) + 1e-5f);
    const float4* g4 = (const float4*)(g + q * 48);
    const float4* b4 = (const float4*)(be + q * 48);
    char* rowB = (char*)sB + r * 384;
    const int swz = (r & 7) << 4;
#pragma unroll
    for (int i = 0; i < 12; ++i) {
        float4 gg = g4[i], bb = b4[i];
        short4v pk;
        pk.x = f2bf((v[4 * i + 0] - mu) * rs * gg.x + bb.x);
        pk.y = f2bf((v[4 * i + 1] - mu) * rs * gg.y + bb.y);
        pk.z = f2bf((v[4 * i + 2] - mu) * rs * gg.z + bb.z);
        pk.w = f2bf((v[4 * i + 3] - mu) * rs * gg.w + bb.w);
        *(short4v*)(rowB + (((q * 48 + i * 4) * 2) ^ swz)) = pk;
    }
    __syncthreads();

    const int lane = tid & 63;
    const int wv = tid >> 6;
    const int tt = wv & 1;
    const int wo = wv >> 1;
    const int colL = lane & 31;
    const int gq = lane >> 5;

    f32x16 acc0 = {0.f, 0.f, 0.f, 0.f, 0.f, 0.f, 0.f, 0.f,
                   0.f, 0.f, 0.f, 0.f, 0.f, 0.f, 0.f, 0.f};
    f32x16 acc1 = acc0, acc2 = acc0;
    const char* bbase = (const char*)sB + (tt * 32 + colL) * 384;
    const int bswz = ((tt * 32 + colL) & 7) << 4;
    const int ocol = wo * 32 + colL;

    for (int kk = 0; kk < 12; ++kk) {
        short8 bf = *(const short8*)(bbase + (((kk * 16 + gq * 8) * 2) ^ bswz));
        const short* ak = wbf + ((kk * 2 + gq) * 192 + ocol) * 8;
        short8 a0 = *(const short8*)(ak);
        short8 a1 = *(const short8*)(ak + 64 * 8);
        short8 a2 = *(const short8*)(ak + 128 * 8);
        acc0 = __builtin_amdgcn_mfma_f32_32x32x16_bf16(a0, bf, acc0, 0, 0, 0);
        acc1 = __builtin_amdgcn_mfma_f32_32x32x16_bf16(a1, bf, acc1, 0, 0, 0);
        acc2 = __builtin_amdgcn_mfma_f32_32x32x16_bf16(a2, bf, acc2, 0, 0, 0);
    }

    const int tglob = t0 + tt * 32 + colL;
    short* outb = kqvT + (size_t)b * 192 * TOK + tglob;
#pragma unroll
    for (int j = 0; j < 3; ++j) {
        const int obase = (wo + 2 * j) * 32;
        const f32x16 ac = (j == 0 ? acc0 : j == 1 ? acc1 : acc2);
#pragma unroll
        for (int reg = 0; reg < 16; ++reg) {
            int orow = (reg & 3) + 8 * (reg >> 2) + 4 * gq;
            outb[(size_t)(obase + orow) * TOK] = f2bf(ac[reg] + bias[obase + orow]);
        }
    }
}

// ---------------------------------------------------------------------------
// Performer features; kqvT bf16 in, kpT/qpT bf16 out.
// ---------------------------------------------------------------------------
__global__ __launch_bounds__(256) void k_perf(
        const short* __restrict__ kqvT, const float* __restrict__ wperf,
        short* __restrict__ kpT, short* __restrict__ qpT) {
    const int b = blockIdx.y;
    const int t = blockIdx.x * 256 + threadIdx.x;
    const short* basek = kqvT + (size_t)b * 192 * TOK + t;
    for (int pass = 0; pass < 2; ++pass) {
        float kr[64];
        const short* src = basek + (size_t)pass * 64 * TOK;
#pragma unroll
        for (int i = 0; i < 64; ++i) kr[i] = bf2f(src[(size_t)i * TOK]);
        float xd = 0.f;
#pragma unroll
        for (int i = 0; i < 64; ++i) xd = fmaf(kr[i], kr[i], xd);
        xd *= 0.5f;
        short* dst = (pass == 0 ? kpT : qpT) + (size_t)b * 32 * TOK + t;
        for (int m = 0; m < 32; ++m) {
            const float* wr = wperf + m * 64;
            float a = 0.f;
#pragma unroll
            for (int i = 0; i < 64; ++i) a = fmaf(wr[i], kr[i], a);
            dst[(size_t)m * TOK] = f2bf(expf(a - xd) * 0.17677669529663687f);
        }
    }
}

// ---------------------------------------------------------------------------
// kptv chunk partials; kqvT/kpT bf16 in (converted on LDS stage).
// ---------------------------------------------------------------------------
__global__ __launch_bounds__(256) void k_kptv(
        const short* __restrict__ kqvT, const short* __restrict__ kpT,
        float* __restrict__ kvp, float* __restrict__ skpp) {
    const int b = blockIdx.y, ch = blockIdx.x, tid = threadIdx.x;
    const int t = ch * 256 + tid;
    __shared__ float sv[256 * 65 + 256 * 36];
    float* skp = sv + 256 * 65;
    for (int dd = 0; dd < 64; ++dd)
        sv[tid * 65 + dd] = bf2f(kqvT[((size_t)(b * 192 + 128 + dd)) * TOK + t]);
    for (int m = 0; m < 32; ++m)
        skp[tid * 36 + m] = bf2f(kpT[((size_t)(b * 32 + m)) * TOK + t]);
    __syncthreads();

    const int dd = tid & 63;
    const int mg = __builtin_amdgcn_readfirstlane(tid >> 6);
    float acc[8];
#pragma unroll
    for (int j = 0; j < 8; ++j) acc[j] = 0.f;
    for (int tt = 0; tt < 256; ++tt) {
        float vv = sv[tt * 65 + dd];
        const float4* kq = (const float4*)(skp + tt * 36 + mg * 8);
        float4 a0 = kq[0], a1 = kq[1];
        acc[0] = fmaf(vv, a0.x, acc[0]);
        acc[1] = fmaf(vv, a0.y, acc[1]);
        acc[2] = fmaf(vv, a0.z, acc[2]);
        acc[3] = fmaf(vv, a0.w, acc[3]);
        acc[4] = fmaf(vv, a1.x, acc[4]);
        acc[5] = fmaf(vv, a1.y, acc[5]);
        acc[6] = fmaf(vv, a1.z, acc[6]);
        acc[7] = fmaf(vv, a1.w, acc[7]);
    }
    float* dst = kvp + (((size_t)(b * 16 + ch) * 64 + dd) * 32) + mg * 8;
#pragma unroll
    for (int j = 0; j < 8; ++j) dst[j] = acc[j];

    if (tid < 32) {
        float s = 0.f;
        for (int tt = 0; tt < 256; ++tt) s += skp[tt * 36 + tid];
        skpp[(b * 16 + ch) * 32 + tid] = s;
    }
}

// Reduce partials -> kvbf MFMA-native [b][ms][g][d][8m] bf16, sum_kp fp32.
__global__ __launch_bounds__(256) void k_reduce2(
        const float* __restrict__ kvp, const float* __restrict__ skpp,
        short* __restrict__ kvbf, float* __restrict__ sum_kp) {
    int idx = blockIdx.x * 256 + threadIdx.x;
    if (idx < 65536) {
        int b = idx >> 11, rem = idx & 2047, dd = rem >> 5, m = rem & 31;
        float s = 0.f;
        for (int ch = 0; ch < 16; ++ch) s += kvp[((b * 16 + ch) * 64 + dd) * 32 + m];
        int dst = (((b * 2 + (m >> 4)) * 2 + ((m >> 3) & 1)) * 64 + dd) * 8 + (m & 7);
        kvbf[dst] = f2bf(s);
    } else if (idx < 65536 + 1024) {
        int i = idx - 65536;
        int b = i >> 5, m = i & 31;
        float s = 0.f;
        for (int ch = 0; ch < 16; ++ch) s += skpp[(b * 16 + ch) * 32 + m];
        sum_kp[i] = s;
    }
}

// ---------------------------------------------------------------------------
// Fused: yatt = (qp@kv^T)*rD -> proj+v+b -> LN2 -> w1+GELU -> w2 + skip.
// ---------------------------------------------------------------------------
__global__ __launch_bounds__(256) void k_fuse(
        const short* __restrict__ kqvT, const short* __restrict__ qpT,
        const short* __restrict__ kvbf, const float* __restrict__ sum_kp,
        const short* __restrict__ pTbf, const float* __restrict__ proj_b,
        const float* __restrict__ g2, const float* __restrict__ b2ln,
        const short* __restrict__ w1bf, const float* __restrict__ b1,
        const short* __restrict__ w2bf, const float* __restrict__ b2,
        float* __restrict__ out) {
    const int b = blockIdx.y;
    const int t0 = blockIdx.x * 64;
    const int tid = threadIdx.x;
    const int lane = tid & 63;
    const int cl = lane & 31;
    const int g  = lane >> 5;
    const int wv = tid >> 6;
    const int wr = wv & 1;
    const int wc = wv >> 1;

    __shared__ __align__(16) char pool[29952];
    short* qpS  = (short*)(pool + 0);
    short* ytS  = (short*)(pool + 5120);
    short* xnS  = (short*)(pool + 14336);
    short* hgS  = (short*)(pool + 0);
    float* outS = (float*)(pool + 9216);
    float* red  = (float*)(pool + 26624);
    float* stat = (float*)(pool + 27648);
    float* coefS= (float*)(pool + 28672);

    if (tid < 64) {
        coefS[tid]       = proj_b[tid];
        coefS[64 + tid]  = g2[tid];
        coefS[128 + tid] = b2ln[tid];
        coefS[192 + tid] = b1[tid];
        coefS[256 + tid] = b2[tid];
    }
    {
        const int t = tid & 63, q = tid >> 6;
        const float* sk = sum_kp + b * 32;
        float dsum = 0.f;
        short8 pk;
#pragma unroll
        for (int i = 0; i < 8; ++i) {
            int m = q * 8 + i;
            short s = qpT[((size_t)(b * 32 + m)) * TOK + t0 + t];
            dsum = fmaf(bf2f(s), sk[m], dsum);
            pk[i] = s;
        }
        *(short8*)(qpS + t * 40 + q * 8) = pk;
        red[t * 4 + q] = dsum;
    }
    __syncthreads();

    const int tl = wc * 32 + cl;
    const int tg = t0 + tl;
    const int rcol = wr * 32 + cl;

    f32x16 acc = {0.f, 0.f, 0.f, 0.f, 0.f, 0.f, 0.f, 0.f,
                  0.f, 0.f, 0.f, 0.f, 0.f, 0.f, 0.f, 0.f};
    {
        const short* Ab = kvbf + (size_t)b * 2048;
        short8 a0 = *(const short8*)(Ab + (g * 64 + rcol) * 8);
        short8 a1 = *(const short8*)(Ab + ((2 + g) * 64 + rcol) * 8);
        short8 b0 = *(const short8*)(qpS + tl * 40 + g * 8);
        short8 b1v = *(const short8*)(qpS + tl * 40 + 16 + g * 8);
        acc = __builtin_amdgcn_mfma_f32_32x32x16_bf16(a0, b0, acc, 0, 0, 0);
        acc = __builtin_amdgcn_mfma_f32_32x32x16_bf16(a1, b1v, acc, 0, 0, 0);
    }
    {
        float Dv = red[tl * 4 + 0] + red[tl * 4 + 1] + red[tl * 4 + 2] + red[tl * 4 + 3];
        float rD = 1.f / (Dv + 1e-8f);
#pragma unroll
        for (int rq = 0; rq < 4; ++rq) {
            int d0 = wr * 32 + 8 * rq + 4 * g;
            short4v p;
            p.x = f2bf(acc[rq * 4 + 0] * rD);
            p.y = f2bf(acc[rq * 4 + 1] * rD);
            p.z = f2bf(acc[rq * 4 + 2] * rD);
            p.w = f2bf(acc[rq * 4 + 3] * rD);
            *(short4v*)(ytS + tl * 72 + d0) = p;
        }
    }
    __syncthreads();

    f32x16 acc2 = {0.f, 0.f, 0.f, 0.f, 0.f, 0.f, 0.f, 0.f,
                   0.f, 0.f, 0.f, 0.f, 0.f, 0.f, 0.f, 0.f};
    {
#pragma unroll
        for (int ks = 0; ks < 4; ++ks) {
            short8 a = *(const short8*)(pTbf + ((ks * 2 + g) * 64 + rcol) * 8);
            short8 bb = *(const short8*)(ytS + tl * 72 + ks * 16 + g * 8);
            acc2 = __builtin_amdgcn_mfma_f32_32x32x16_bf16(a, bb, acc2, 0, 0, 0);
        }
    }
    float skv[16];
    {
        const short* vb = kqvT + ((size_t)(b * 192 + 128)) * TOK + tg;
#pragma unroll
        for (int reg = 0; reg < 16; ++reg) {
            int o = wr * 32 + (reg & 3) + 8 * (reg >> 2) + 4 * g;
            skv[reg] = acc2[reg] + bf2f(vb[(size_t)o * TOK]) + coefS[o];
        }
    }

    {
        float s1 = 0.f, s2 = 0.f;
#pragma unroll
        for (int reg = 0; reg < 16; ++reg) {
            s1 += skv[reg];
            s2 = fmaf(skv[reg], skv[reg], s2);
        }
        s1 += __shfl_xor(s1, 32, 64);
        s2 += __shfl_xor(s2, 32, 64);
        if (g == 0) {
            stat[(wr * 64 + tl) * 2 + 0] = s1;
            stat[(wr * 64 + tl) * 2 + 1] = s2;
        }
        __syncthreads();
        float S1 = s1 + stat[((wr ^ 1) * 64 + tl) * 2 + 0];
        float S2 = s2 + stat[((wr ^ 1) * 64 + tl) * 2 + 1];
        float mu = S1 * (1.f / 64.f);
        float var = S2 * (1.f / 64.f) - mu * mu;
        float rs = rsqrtf(fmaxf(var, 0.f) + 1e-5f);
#pragma unroll
        for (int rq = 0; rq < 4; ++rq) {
            int o0 = wr * 32 + 8 * rq + 4 * g;
            short4v p;
#pragma unroll
            for (int j = 0; j < 4; ++j) {
                int o = o0 + j;
                float xn = (skv[rq * 4 + j] - mu) * rs * coefS[64 + o] + coefS[128 + o];
                ((short*)&p)[j] = f2bf(xn);
            }
            *(short4v*)(xnS + tl * 72 + o0) = p;
        }
    }
    __syncthreads();

    f32x16 acc3 = {0.f, 0.f, 0.f, 0.f, 0.f, 0.f, 0.f, 0.f,
                   0.f, 0.f, 0.f, 0.f, 0.f, 0.f, 0.f, 0.f};
    {
#pragma unroll
        for (int ks = 0; ks < 4; ++ks) {
            short8 a = *(const short8*)(w1bf + ((ks * 2 + g) * 64 + rcol) * 8);
            short8 bb = *(const short8*)(xnS + tl * 72 + ks * 16 + g * 8);
            acc3 = __builtin_amdgcn_mfma_f32_32x32x16_bf16(a, bb, acc3, 0, 0, 0);
        }
    }
    __syncthreads();
    {
#pragma unroll
        for (int rq = 0; rq < 4; ++rq) {
            int i0 = wr * 32 + 8 * rq + 4 * g;
            short4v p;
#pragma unroll
            for (int j = 0; j < 4; ++j) {
                int i = i0 + j;
                float hgv = gelu_fast(acc3[rq * 4 + j] + coefS[192 + i]);
                ((short*)&p)[j] = f2bf(hgv);
            }
            *(short4v*)(hgS + tl * 72 + i0) = p;
        }
    }
    __syncthreads();

    f32x16 acc4 = {0.f, 0.f, 0.f, 0.f, 0.f, 0.f, 0.f, 0.f,
                   0.f, 0.f, 0.f, 0.f, 0.f, 0.f, 0.f, 0.f};
    {
#pragma unroll
        for (int ks = 0; ks < 4; ++ks) {
            short8 a = *(const short8*)(w2bf + ((ks * 2 + g) * 64 + rcol) * 8);
            short8 bb = *(const short8*)(hgS + tl * 72 + ks * 16 + g * 8);
            acc4 = __builtin_amdgcn_mfma_f32_32x32x16_bf16(a, bb, acc4, 0, 0, 0);
        }
    }
    {
#pragma unroll
        for (int rq = 0; rq < 4; ++rq) {
            int o0 = wr * 32 + 8 * rq + 4 * g;
            float4 f;
#pragma unroll
            for (int j = 0; j < 4; ++j) {
                int o = o0 + j;
                ((float*)&f)[j] = skv[rq * 4 + j] + acc4[rq * 4 + j] + coefS[256 + o];
            }
            *(float4*)(outS + tl * 68 + o0) = f;
        }
    }
    __syncthreads();

    {
        const int tt = tid >> 2, qq = tid & 3;
        float* ob = out + ((size_t)(b * TOK) + t0 + tt) * 64;
#pragma unroll
        for (int it = 0; it < 4; ++it) {
            *(float4*)(ob + it * 16 + qq * 4) =
                *(float4*)(outS + tt * 68 + it * 16 + qq * 4);
        }
    }
}

// ---------------------------------------------------------------------------
extern "C" void kernel_launch(void* const* d_in, const int* in_sizes, int n_in,
                              void* d_out, int out_size, void* d_ws, size_t ws_size,
                              hipStream_t stream) {
    const float* x      = (const float*)d_in[0];
    const float* conv_w = (const float*)d_in[1];
    const float* conv_b = (const float*)d_in[2];
    const float* ln1_g  = (const float*)d_in[3];
    const float* ln1_b  = (const float*)d_in[4];
    const float* kqv_w  = (const float*)d_in[5];
    const float* kqv_b  = (const float*)d_in[6];
    const float* proj_w = (const float*)d_in[7];
    const float* proj_b = (const float*)d_in[8];
    const float* w_perf = (const float*)d_in[9];
    const float* ln2_g  = (const float*)d_in[10];
    const float* ln2_b  = (const float*)d_in[11];
    const float* mlp_w1 = (const float*)d_in[12];
    const float* mlp_b1 = (const float*)d_in[13];
    const float* mlp_w2 = (const float*)d_in[14];
    const float* mlp_b2 = (const float*)d_in[15];

    float* ws = (float*)d_ws;
    short* w2c    = (short*)ws;                 // 110592 sh
    short* kwbf   = (short*)(ws + 55296);       // 36864 sh
    short* pTbf   = (short*)(ws + 73728);       // 4096 sh
    short* w1bf   = (short*)(ws + 75776);       // 4096 sh
    short* w2bf   = (short*)(ws + 77824);       // 4096 sh
    float* sum_kp = ws + 79872;                 // 1024 f
    short* kvbf   = (short*)(ws + 80896);       // 65536 sh -> ends 113664
    // region A: tokens bf16 (dead after lnkqv), overlaid by qpT/kpT/kvp
    short* tokens = (short*)(ws + 114688);      // 25165824 sh
    short* qpT    = (short*)(ws + 114688);      // 4194304 sh (overlay)
    short* kpT    = (short*)(ws + 114688 + 2097152);   // 4194304 sh
    float* skpp   = ws + 114688 + 4194304;      // 16384 f
    float* kvp    = ws + 114688 + 4210688;      // 1048576 f
    // region B: kqvT bf16 (after tokens region)
    short* kqvT   = (short*)(ws + 12697600);    // 25165824 sh
    float* outp   = (float*)d_out;

    k_prep   <<<624, 256, 0, stream>>>(conv_w, kqv_w, proj_w, mlp_w1, mlp_w2,
                                       w2c, kwbf, pTbf, w1bf, w2bf);
    k_conv6  <<<6144, 256, 0, stream>>>(x, w2c, conv_b, tokens);
    k_lnkqv_mfma<<<dim3(64, 32), 256, 0, stream>>>(tokens, ln1_g, ln1_b, kwbf, kqv_b, kqvT);
    k_perf   <<<dim3(16, 32), 256, 0, stream>>>(kqvT, w_perf, kpT, qpT);
    k_kptv   <<<dim3(16, 32), 256, 0, stream>>>(kqvT, kpT, kvp, skpp);
    k_reduce2<<<260, 256, 0, stream>>>(kvp, skpp, kvbf, sum_kp);
    k_fuse   <<<dim3(64, 32), 256, 0, stream>>>(kqvT, qpT, kvbf, sum_kp,
                                                pTbf, proj_b, ln2_g, ln2_b,
                                                w1bf, mlp_b1, w2bf, mlp_b2, outp);
}

// Round 12
// 154.640 us; speedup vs baseline: 22.8356x; 1.3358x over previous
//
#include <hip/hip_runtime.h>
#include <hip/hip_bf16.h>

// ---------------------------------------------------------------------------
// BlockRC2: PRM (3 dilated stride-2 convs + GELU) -> LN1 -> kqv ->
// performer attention -> proj+skip -> LN2 -> MLP -> skip.
// Round 12: k_perf folded into k_lnkqv as MFMA (was ~27us of scalar FMA --
// two [131072x64]@[64x32] GEMMs). k,q never leave the block: |k|^2/|q|^2
// accumulated from accumulator fragments, k/q staged bf16 into the dead
// token LDS tile, w_perf (MFMA-native) matmul + exp in-fragment, kp/qp
// stored m-major. Only v is written globally (vT, 8MB vs old 50MB kqvT).
// Conv unchanged from r11 (control).
// ---------------------------------------------------------------------------

#define TOK 4096
#define NB  32

typedef __attribute__((ext_vector_type(8)))  short short8;
typedef __attribute__((ext_vector_type(4)))  short short4v;
typedef __attribute__((ext_vector_type(16))) float f32x16;

// gelu(x) = x * sigmoid(x*(1.5957691216 + 0.0713548162 x^2)), max err ~3e-4.
__device__ __forceinline__ float gelu_fast(float v) {
    float u = v * fmaf(0.0713548162f, v * v, 1.5957691216f);
    float e = __expf(-u);
    return v * __builtin_amdgcn_rcpf(1.f + e);
}

__device__ __forceinline__ short f2bf(float f) {
    __hip_bfloat16 h = __float2bfloat16(f);   // RNE; HW cvt on gfx950
    return *reinterpret_cast<short*>(&h);
}

__device__ __forceinline__ float bf2f(short s) {
    union { unsigned u; float f; } x;
    x.u = ((unsigned)(unsigned short)s) << 16;
    return x.f;
}

// ---------------------------------------------------------------------------
// Prep. MFMA-native layouts: frag element for lane (cl,g), reg j is
// W[col=cl][k = ks*16 + g*8 + j]  ->  stored at ((ks*2+g)*NCOL + col)*8 + j.
// ---------------------------------------------------------------------------
__global__ __launch_bounds__(256) void k_prep(
        const float* __restrict__ cw, const float* __restrict__ kw,
        const float* __restrict__ pw, const float* __restrict__ w1,
        const float* __restrict__ w2m, const float* __restrict__ wperf,
        short* __restrict__ w2c, short* __restrict__ kwbf,
        short* __restrict__ pTbf, short* __restrict__ w1bf,
        short* __restrict__ w2bf, short* __restrict__ wpbf) {
    int idx = blockIdx.x * 256 + threadIdx.x;
    if (idx < 110592) {
        int c = idx & 63;
        int t = idx >> 6;
        int e = t & 63;
        int tap = t >> 6;
        int kwi = tap % 3, t2 = tap / 3;
        int r = t2 % 3, brr = t2 / 3;
        float v = cw[(((brr * 64 + e) * 64 + c) * 3 + r) * 3 + kwi];
        int dst = ((((brr * 9 + r * 3 + kwi) * 4 + (c >> 4)) * 2 + ((c >> 3) & 1)) * 64 + e) * 8 + (c & 7);
        w2c[dst] = f2bf(v);
    } else if (idx < 147456) {
        int i2 = idx - 110592;
        int o = i2 / 192, i = i2 % 192;
        int dst = (((i >> 4) * 2 + ((i >> 3) & 1)) * 192 + o) * 8 + (i & 7);
        kwbf[dst] = f2bf(kw[i * 192 + o]);
    } else if (idx < 151552) {
        int i2 = idx - 147456;
        int o = i2 >> 6, d = i2 & 63;
        int dst = (((d >> 4) * 2 + ((d >> 3) & 1)) * 64 + o) * 8 + (d & 7);
        pTbf[dst] = f2bf(pw[d * 64 + o]);
    } else if (idx < 155648) {
        int i2 = idx - 151552;
        int i = i2 >> 6, jd = i2 & 63;
        int dst = (((jd >> 4) * 2 + ((jd >> 3) & 1)) * 64 + i) * 8 + (jd & 7);
        w1bf[dst] = f2bf(w1[jd * 64 + i]);
    } else if (idx < 159744) {
        int i2 = idx - 155648;
        int o = i2 >> 6, i = i2 & 63;
        int dst = (((i >> 4) * 2 + ((i >> 3) & 1)) * 64 + o) * 8 + (i & 7);
        w2bf[dst] = f2bf(w2m[i * 64 + o]);
    } else if (idx < 161792) {
        int i2 = idx - 159744;
        int m = i2 >> 6, d = i2 & 63;       // w_perf [m=32][d=64]
        int dst = (((d >> 4) * 2 + ((d >> 3) & 1)) * 32 + m) * 8 + (d & 7);
        wpbf[dst] = f2bf(wperf[m * 64 + d]);
    }
}

// ---------------------------------------------------------------------------
// Conv via MFMA, c-split 2-phase (unchanged from round 11).
// ---------------------------------------------------------------------------
__global__ __launch_bounds__(256) void k_conv6(
        const float* __restrict__ x, const short* __restrict__ w2c,
        const float* __restrict__ cb, short* __restrict__ tokens) {
    const int wg  = blockIdx.x;
    const int swz_id = (wg & 7) * 768 + (wg >> 3);   // 6144 = 8*768, bijective
    const int b   = swz_id / 192;
    const int rem = swz_id - b * 192;
    const int oh  = rem / 3;
    const int br  = rem - oh * 3;
    const int d   = br + 1;
    const int tid = threadIdx.x;
    const int lane = tid & 63;
    const int wv = tid >> 6;
    const int cl = lane & 31;
    const int g  = lane >> 5;
    const int wm = wv & 1;
    const int wn = wv >> 1;

    __shared__ short sA[3 * 68 * 2 * 32];   // 26112 B

    const int ow = wm * 32 + cl;
    const int ecol = wn * 32 + cl;
    const short* wbr = w2c + br * 9 * 4096;

    f32x16 acc = {0.f, 0.f, 0.f, 0.f, 0.f, 0.f, 0.f, 0.f,
                  0.f, 0.f, 0.f, 0.f, 0.f, 0.f, 0.f, 0.f};

    for (int h = 0; h < 2; ++h) {
        if (h == 0 && tid < 96) {
            int s16 = tid & 7;
            int ii  = (tid >> 3) & 3;
            int r   = tid >> 5;
            int i   = (ii < 2) ? ii : (64 + ii);
            short8 z = {0, 0, 0, 0, 0, 0, 0, 0};
            *(short8*)((char*)sA + (r * 68 + i) * 128 + s16 * 16) = z;
        }
        for (int it = 0; it < 6; ++it) {
            int flat = it * 256 + tid;
            int c8l = flat & 3;
            int iw  = (flat >> 2) & 127;
            int r   = flat >> 9;
            int ih  = 2 * oh + (r - 1) * d;
            int iw4 = iw + 4;
            int i   = iw4 >> 1;
            int p   = iw4 & 1;
            char* dst = (char*)sA + (r * 68 + i) * 128
                      + ((((p * 4 + c8l) * 16)) ^ ((i & 7) << 4));
            if ((unsigned)ih < 128u) {
                const float* src = x + ((size_t)(b * 16384 + ih * 128 + iw)) * 64
                                 + h * 32 + c8l * 8;
                float4 f0 = *(const float4*)(src);
                float4 f1 = *(const float4*)(src + 4);
                short8 v;
                v[0] = f2bf(f0.x); v[1] = f2bf(f0.y); v[2] = f2bf(f0.z); v[3] = f2bf(f0.w);
                v[4] = f2bf(f1.x); v[5] = f2bf(f1.y); v[6] = f2bf(f1.z); v[7] = f2bf(f1.w);
                *(short8*)dst = v;
            } else {
                short8 z = {0, 0, 0, 0, 0, 0, 0, 0};
                *(short8*)dst = z;
            }
        }
        __syncthreads();

#pragma unroll
        for (int r = 0; r < 3; ++r) {
#pragma unroll
            for (int kwi = 0; kwi < 3; ++kwi) {
                const int iw4 = 2 * ow + (kwi - 1) * d + 4;   // in [1,133]
                const int i   = iw4 >> 1;
                const int p   = iw4 & 1;
                const char* arow = (const char*)sA + (r * 68 + i) * 128;
                const int swzk = (i & 7) << 4;
                const short* wt = wbr + (r * 3 + kwi) * 4096;
#pragma unroll
                for (int kk = 0; kk < 2; ++kk) {
                    const int ks = h * 2 + kk;
                    short8 a = *(const short8*)(arow + ((((p * 4 + kk * 2 + g) * 16)) ^ swzk));
                    short8 bf = *(const short8*)(wt + ((ks * 2 + g) * 64 + ecol) * 8);
                    acc = __builtin_amdgcn_mfma_f32_32x32x16_bf16(a, bf, acc, 0, 0, 0);
                }
            }
        }
        __syncthreads();
    }

    const int eG = br * 64 + wn * 32 + cl;
    const float bias = cb[eG];
    short* outb = tokens + ((size_t)(b * TOK + oh * 64 + wm * 32)) * 192 + eG;
#pragma unroll
    for (int reg = 0; reg < 16; ++reg) {
        int owl = (reg & 3) + 8 * (reg >> 2) + 4 * g;
        outb[(size_t)owl * 192] = f2bf(gelu_fast(acc[reg] + bias));
    }
}

// ---------------------------------------------------------------------------
// LN1 + kqv + performer features, all MFMA. Block = 64 tokens, 4 waves.
// Main GEMM as before (acc0=k o[0,64), acc1=q o[64,128), acc2=v o[128,192)).
// Then: v -> vT global; 0.5|k|^2,0.5|q|^2 from fragments (shfl_xor + LDS);
// k,q bf16 -> LDS (reusing dead sB, row-XOR swizzle); 4 waves run
// w_perf[32x64] @ {k,q}[64x64] MFMA; kp=exp(pre-xd)/sqrt(32) -> kpT/qpT.
// k,q never written to global.
// ---------------------------------------------------------------------------
__global__ __launch_bounds__(256) void k_lnkqvp(
        const short* __restrict__ tokens, const float* __restrict__ g,
        const float* __restrict__ be, const short* __restrict__ wbf,
        const float* __restrict__ bias, const short* __restrict__ wpbf,
        short* __restrict__ vT, short* __restrict__ kpT,
        short* __restrict__ qpT) {
    const int b = blockIdx.y;
    const int t0 = blockIdx.x * 64;
    const int tid = threadIdx.x;

    __shared__ short sB[64 * 192];        // 24576 B; later: kS=[0,8K), qS=[8K,16K)
    __shared__ float red[64 * 8];
    __shared__ float xdk[128];            // [wo][t]
    __shared__ float xdq[128];

    // ---- LN1 ----
    const int r = tid >> 2, q = tid & 3;
    const short* rowp = tokens + ((size_t)(b * TOK + t0 + r)) * 192 + q * 48;
    float v[48];
    float s1 = 0.f, s2 = 0.f;
#pragma unroll
    for (int i = 0; i < 6; ++i) {
        short8 x8 = *(const short8*)(rowp + i * 8);
#pragma unroll
        for (int j = 0; j < 8; ++j) {
            float f = bf2f(x8[j]);
            v[i * 8 + j] = f;
            s1 += f;
            s2 = fmaf(f, f, s2);
        }
    }
    red[r * 8 + q] = s1;
    red[r * 8 + 4 + q] = s2;
    __syncthreads();
    const float m1 = red[r * 8 + 0] + red[r * 8 + 1] + red[r * 8 + 2] + red[r * 8 + 3];
    const float m2 = red[r * 8 + 4] + red[r * 8 + 5] + red[r * 8 + 6] + red[r * 8 + 7];
    const float mu = m1 * (1.f / 192.f);
    const float var = m2 * (1.f / 192.f) - mu * mu;
    const float rs = rsqrtf(fmaxf(var, 0.f) + 1e-5f);
    const float4* g4 = (const float4*)(g + q * 48);
    const float4* b4 = (const float4*)(be + q * 48);
    char* rowB = (char*)sB + r * 384;
    const int swz = (r & 7) << 4;
#pragma unroll
    for (int i = 0; i < 12; ++i) {
        float4 gg = g4[i], bb = b4[i];
        short4v pk;
        pk.x = f2bf((v[4 * i + 0] - mu) * rs * gg.x + bb.x);
        pk.y = f2bf((v[4 * i + 1] - mu) * rs * gg.y + bb.y);
        pk.z = f2bf((v[4 * i + 2] - mu) * rs * gg.z + bb.z);
        pk.w = f2bf((v[4 * i + 3] - mu) * rs * gg.w + bb.w);
        *(short4v*)(rowB + (((q * 48 + i * 4) * 2) ^ swz)) = pk;
    }
    __syncthreads();

    // ---- main kqv GEMM ----
    const int lane = tid & 63;
    const int wv = tid >> 6;
    const int tt = wv & 1;
    const int wo = wv >> 1;
    const int colL = lane & 31;
    const int gq = lane >> 5;

    f32x16 acc0 = {0.f, 0.f, 0.f, 0.f, 0.f, 0.f, 0.f, 0.f,
                   0.f, 0.f, 0.f, 0.f, 0.f, 0.f, 0.f, 0.f};
    f32x16 acc1 = acc0, acc2 = acc0;
    const char* bbase = (const char*)sB + (tt * 32 + colL) * 384;
    const int bswz = ((tt * 32 + colL) & 7) << 4;
    const int ocol = wo * 32 + colL;

    for (int kk = 0; kk < 12; ++kk) {
        short8 bf = *(const short8*)(bbase + (((kk * 16 + gq * 8) * 2) ^ bswz));
        const short* ak = wbf + ((kk * 2 + gq) * 192 + ocol) * 8;
        short8 a0 = *(const short8*)(ak);
        short8 a1 = *(const short8*)(ak + 64 * 8);
        short8 a2 = *(const short8*)(ak + 128 * 8);
        acc0 = __builtin_amdgcn_mfma_f32_32x32x16_bf16(a0, bf, acc0, 0, 0, 0);
        acc1 = __builtin_amdgcn_mfma_f32_32x32x16_bf16(a1, bf, acc1, 0, 0, 0);
        acc2 = __builtin_amdgcn_mfma_f32_32x32x16_bf16(a2, bf, acc2, 0, 0, 0);
    }

    const int tl = tt * 32 + colL;           // local token
    const int tglob = t0 + tl;

    // ---- bias; v -> global; k,q regs + |.|^2 partials ----
    float kb[16], qb[16];
    float sk = 0.f, sq = 0.f;
    {
        short* vb = vT + (size_t)b * 64 * TOK + tglob;
#pragma unroll
        for (int reg = 0; reg < 16; ++reg) {
            int orow = (reg & 3) + 8 * (reg >> 2) + 4 * gq;
            int d = wo * 32 + orow;
            kb[reg] = acc0[reg] + bias[d];
            qb[reg] = acc1[reg] + bias[64 + d];
            float vv = acc2[reg] + bias[128 + d];
            vb[(size_t)d * TOK] = f2bf(vv);
            sk = fmaf(kb[reg], kb[reg], sk);
            sq = fmaf(qb[reg], qb[reg], sq);
        }
    }
    sk += __shfl_xor(sk, 32, 64);
    sq += __shfl_xor(sq, 32, 64);
    __syncthreads();                          // all waves done reading sB

    // ---- stage k,q bf16 into LDS (kS/qS alias sB), xd partials ----
    if (gq == 0) {
        xdk[wo * 64 + tl] = 0.5f * sk;
        xdq[wo * 64 + tl] = 0.5f * sq;
    }
    {
        char* kS = (char*)sB;
        char* qS = (char*)sB + 8192;
        const int tswz = (tl & 7) << 4;
#pragma unroll
        for (int rq = 0; rq < 4; ++rq) {
            int d0 = wo * 32 + 8 * rq + 4 * gq;
            short4v pk, pq;
#pragma unroll
            for (int j = 0; j < 4; ++j) {
                ((short*)&pk)[j] = f2bf(kb[rq * 4 + j]);
                ((short*)&pq)[j] = f2bf(qb[rq * 4 + j]);
            }
            *(short4v*)(kS + tl * 128 + ((d0 * 2) ^ tswz)) = pk;
            *(short4v*)(qS + tl * 128 + ((d0 * 2) ^ tswz)) = pq;
        }
    }
    __syncthreads();

    // ---- performer MFMA: wave (pass, tt2); pass 0 = kp, 1 = qp ----
    {
        const int pass = wv >> 1;
        const int tt2 = wv & 1;
        const char* S = (char*)sB + pass * 8192;
        const int t2 = tt2 * 32 + colL;
        const int t2swz = (t2 & 7) << 4;
        f32x16 pacc = {0.f, 0.f, 0.f, 0.f, 0.f, 0.f, 0.f, 0.f,
                       0.f, 0.f, 0.f, 0.f, 0.f, 0.f, 0.f, 0.f};
#pragma unroll
        for (int ks = 0; ks < 4; ++ks) {
            short8 a = *(const short8*)(wpbf + ((ks * 2 + gq) * 32 + colL) * 8);
            short8 bb = *(const short8*)(S + t2 * 128 + (((ks * 16 + gq * 8) * 2) ^ t2swz));
            pacc = __builtin_amdgcn_mfma_f32_32x32x16_bf16(a, bb, pacc, 0, 0, 0);
        }
        const float* xda = pass ? xdq : xdk;
        const float xdv = xda[t2] + xda[64 + t2];
        short* dst = (pass ? qpT : kpT) + (size_t)b * 32 * TOK + t0 + t2;
#pragma unroll
        for (int reg = 0; reg < 16; ++reg) {
            int m = (reg & 3) + 8 * (reg >> 2) + 4 * gq;
            float kpv = __expf(pacc[reg] - xdv) * 0.17677669529663687f;
            dst[(size_t)m * TOK] = f2bf(kpv);
        }
    }
}

// ---------------------------------------------------------------------------
// kptv chunk partials; vT/kpT bf16 in (converted on LDS stage).
// ---------------------------------------------------------------------------
__global__ __launch_bounds__(256) void k_kptv(
        const short* __restrict__ vT, const short* __restrict__ kpT,
        float* __restrict__ kvp, float* __restrict__ skpp) {
    const int b = blockIdx.y, ch = blockIdx.x, tid = threadIdx.x;
    const int t = ch * 256 + tid;
    __shared__ float sv[256 * 65 + 256 * 36];
    float* skp = sv + 256 * 65;
    for (int dd = 0; dd < 64; ++dd)
        sv[tid * 65 + dd] = bf2f(vT[((size_t)(b * 64 + dd)) * TOK + t]);
    for (int m = 0; m < 32; ++m)
        skp[tid * 36 + m] = bf2f(kpT[((size_t)(b * 32 + m)) * TOK + t]);
    __syncthreads();

    const int dd = tid & 63;
    const int mg = __builtin_amdgcn_readfirstlane(tid >> 6);
    float acc[8];
#pragma unroll
    for (int j = 0; j < 8; ++j) acc[j] = 0.f;
    for (int tt = 0; tt < 256; ++tt) {
        float vv = sv[tt * 65 + dd];
        const float4* kq = (const float4*)(skp + tt * 36 + mg * 8);
        float4 a0 = kq[0], a1 = kq[1];
        acc[0] = fmaf(vv, a0.x, acc[0]);
        acc[1] = fmaf(vv, a0.y, acc[1]);
        acc[2] = fmaf(vv, a0.z, acc[2]);
        acc[3] = fmaf(vv, a0.w, acc[3]);
        acc[4] = fmaf(vv, a1.x, acc[4]);
        acc[5] = fmaf(vv, a1.y, acc[5]);
        acc[6] = fmaf(vv, a1.z, acc[6]);
        acc[7] = fmaf(vv, a1.w, acc[7]);
    }
    float* dst = kvp + (((size_t)(b * 16 + ch) * 64 + dd) * 32) + mg * 8;
#pragma unroll
    for (int j = 0; j < 8; ++j) dst[j] = acc[j];

    if (tid < 32) {
        float s = 0.f;
        for (int tt = 0; tt < 256; ++tt) s += skp[tt * 36 + tid];
        skpp[(b * 16 + ch) * 32 + tid] = s;
    }
}

// Reduce partials -> kvbf MFMA-native [b][ms][g][d][8m] bf16, sum_kp fp32.
__global__ __launch_bounds__(256) void k_reduce2(
        const float* __restrict__ kvp, const float* __restrict__ skpp,
        short* __restrict__ kvbf, float* __restrict__ sum_kp) {
    int idx = blockIdx.x * 256 + threadIdx.x;
    if (idx < 65536) {
        int b = idx >> 11, rem = idx & 2047, dd = rem >> 5, m = rem & 31;
        float s = 0.f;
        for (int ch = 0; ch < 16; ++ch) s += kvp[((b * 16 + ch) * 64 + dd) * 32 + m];
        int dst = (((b * 2 + (m >> 4)) * 2 + ((m >> 3) & 1)) * 64 + dd) * 8 + (m & 7);
        kvbf[dst] = f2bf(s);
    } else if (idx < 65536 + 1024) {
        int i = idx - 65536;
        int b = i >> 5, m = i & 31;
        float s = 0.f;
        for (int ch = 0; ch < 16; ++ch) s += skpp[(b * 16 + ch) * 32 + m];
        sum_kp[i] = s;
    }
}

// ---------------------------------------------------------------------------
// Fused: yatt = (qp@kv^T)*rD -> proj+v+b -> LN2 -> w1+GELU -> w2 + skip.
// v now from vT [b][64 d][4096 t].
// ---------------------------------------------------------------------------
__global__ __launch_bounds__(256) void k_fuse(
        const short* __restrict__ vT, const short* __restrict__ qpT,
        const short* __restrict__ kvbf, const float* __restrict__ sum_kp,
        const short* __restrict__ pTbf, const float* __restrict__ proj_b,
        const float* __restrict__ g2, const float* __restrict__ b2ln,
        const short* __restrict__ w1bf, const float* __restrict__ b1,
        const short* __restrict__ w2bf, const float* __restrict__ b2,
        float* __restrict__ out) {
    const int b = blockIdx.y;
    const int t0 = blockIdx.x * 64;
    const int tid = threadIdx.x;
    const int lane = tid & 63;
    const int cl = lane & 31;
    const int g  = lane >> 5;
    const int wv = tid >> 6;
    const int wr = wv & 1;
    const int wc = wv >> 1;

    __shared__ __align__(16) char pool[29952];
    short* qpS  = (short*)(pool + 0);
    short* ytS  = (short*)(pool + 5120);
    short* xnS  = (short*)(pool + 14336);
    short* hgS  = (short*)(pool + 0);
    float* outS = (float*)(pool + 9216);
    float* red  = (float*)(pool + 26624);
    float* stat = (float*)(pool + 27648);
    float* coefS= (float*)(pool + 28672);

    if (tid < 64) {
        coefS[tid]       = proj_b[tid];
        coefS[64 + tid]  = g2[tid];
        coefS[128 + tid] = b2ln[tid];
        coefS[192 + tid] = b1[tid];
        coefS[256 + tid] = b2[tid];
    }
    {
        const int t = tid & 63, q = tid >> 6;
        const float* sk = sum_kp + b * 32;
        float dsum = 0.f;
        short8 pk;
#pragma unroll
        for (int i = 0; i < 8; ++i) {
            int m = q * 8 + i;
            short s = qpT[((size_t)(b * 32 + m)) * TOK + t0 + t];
            dsum = fmaf(bf2f(s), sk[m], dsum);
            pk[i] = s;
        }
        *(short8*)(qpS + t * 40 + q * 8) = pk;
        red[t * 4 + q] = dsum;
    }
    __syncthreads();

    const int tl = wc * 32 + cl;
    const int tg = t0 + tl;
    const int rcol = wr * 32 + cl;

    f32x16 acc = {0.f, 0.f, 0.f, 0.f, 0.f, 0.f, 0.f, 0.f,
                  0.f, 0.f, 0.f, 0.f, 0.f, 0.f, 0.f, 0.f};
    {
        const short* Ab = kvbf + (size_t)b * 2048;
        short8 a0 = *(const short8*)(Ab + (g * 64 + rcol) * 8);
        short8 a1 = *(const short8*)(Ab + ((2 + g) * 64 + rcol) * 8);
        short8 b0 = *(const short8*)(qpS + tl * 40 + g * 8);
        short8 b1v = *(const short8*)(qpS + tl * 40 + 16 + g * 8);
        acc = __builtin_amdgcn_mfma_f32_32x32x16_bf16(a0, b0, acc, 0, 0, 0);
        acc = __builtin_amdgcn_mfma_f32_32x32x16_bf16(a1, b1v, acc, 0, 0, 0);
    }
    {
        float Dv = red[tl * 4 + 0] + red[tl * 4 + 1] + red[tl * 4 + 2] + red[tl * 4 + 3];
        float rD = 1.f / (Dv + 1e-8f);
#pragma unroll
        for (int rq = 0; rq < 4; ++rq) {
            int d0 = wr * 32 + 8 * rq + 4 * g;
            short4v p;
            p.x = f2bf(acc[rq * 4 + 0] * rD);
            p.y = f2bf(acc[rq * 4 + 1] * rD);
            p.z = f2bf(acc[rq * 4 + 2] * rD);
            p.w = f2bf(acc[rq * 4 + 3] * rD);
            *(short4v*)(ytS + tl * 72 + d0) = p;
        }
    }
    __syncthreads();

    f32x16 acc2 = {0.f, 0.f, 0.f, 0.f, 0.f, 0.f, 0.f, 0.f,
                   0.f, 0.f, 0.f, 0.f, 0.f, 0.f, 0.f, 0.f};
    {
#pragma unroll
        for (int ks = 0; ks < 4; ++ks) {
            short8 a = *(const short8*)(pTbf + ((ks * 2 + g) * 64 + rcol) * 8);
            short8 bb = *(const short8*)(ytS + tl * 72 + ks * 16 + g * 8);
            acc2 = __builtin_amdgcn_mfma_f32_32x32x16_bf16(a, bb, acc2, 0, 0, 0);
        }
    }
    float skv[16];
    {
        const short* vb = vT + (size_t)b * 64 * TOK + tg;
#pragma unroll
        for (int reg = 0; reg < 16; ++reg) {
            int o = wr * 32 + (reg & 3) + 8 * (reg >> 2) + 4 * g;
            skv[reg] = acc2[reg] + bf2f(vb[(size_t)o * TOK]) + coefS[o];
        }
    }

    {
        float s1 = 0.f, s2 = 0.f;
#pragma unroll
        for (int reg = 0; reg < 16; ++reg) {
            s1 += skv[reg];
            s2 = fmaf(skv[reg], skv[reg], s2);
        }
        s1 += __shfl_xor(s1, 32, 64);
        s2 += __shfl_xor(s2, 32, 64);
        if (g == 0) {
            stat[(wr * 64 + tl) * 2 + 0] = s1;
            stat[(wr * 64 + tl) * 2 + 1] = s2;
        }
        __syncthreads();
        float S1 = s1 + stat[((wr ^ 1) * 64 + tl) * 2 + 0];
        float S2 = s2 + stat[((wr ^ 1) * 64 + tl) * 2 + 1];
        float mu = S1 * (1.f / 64.f);
        float var = S2 * (1.f / 64.f) - mu * mu;
        float rs = rsqrtf(fmaxf(var, 0.f) + 1e-5f);
#pragma unroll
        for (int rq = 0; rq < 4; ++rq) {
            int o0 = wr * 32 + 8 * rq + 4 * g;
            short4v p;
#pragma unroll
            for (int j = 0; j < 4; ++j) {
                int o = o0 + j;
                float xn = (skv[rq * 4 + j] - mu) * rs * coefS[64 + o] + coefS[128 + o];
                ((short*)&p)[j] = f2bf(xn);
            }
            *(short4v*)(xnS + tl * 72 + o0) = p;
        }
    }
    __syncthreads();

    f32x16 acc3 = {0.f, 0.f, 0.f, 0.f, 0.f, 0.f, 0.f, 0.f,
                   0.f, 0.f, 0.f, 0.f, 0.f, 0.f, 0.f, 0.f};
    {
#pragma unroll
        for (int ks = 0; ks < 4; ++ks) {
            short8 a = *(const short8*)(w1bf + ((ks * 2 + g) * 64 + rcol) * 8);
            short8 bb = *(const short8*)(xnS + tl * 72 + ks * 16 + g * 8);
            acc3 = __builtin_amdgcn_mfma_f32_32x32x16_bf16(a, bb, acc3, 0, 0, 0);
        }
    }
    __syncthreads();
    {
#pragma unroll
        for (int rq = 0; rq < 4; ++rq) {
            int i0 = wr * 32 + 8 * rq + 4 * g;
            short4v p;
#pragma unroll
            for (int j = 0; j < 4; ++j) {
                int i = i0 + j;
                float hgv = gelu_fast(acc3[rq * 4 + j] + coefS[192 + i]);
                ((short*)&p)[j] = f2bf(hgv);
            }
            *(short4v*)(hgS + tl * 72 + i0) = p;
        }
    }
    __syncthreads();

    f32x16 acc4 = {0.f, 0.f, 0.f, 0.f, 0.f, 0.f, 0.f, 0.f,
                   0.f, 0.f, 0.f, 0.f, 0.f, 0.f, 0.f, 0.f};
    {
#pragma unroll
        for (int ks = 0; ks < 4; ++ks) {
            short8 a = *(const short8*)(w2bf + ((ks * 2 + g) * 64 + rcol) * 8);
            short8 bb = *(const short8*)(hgS + tl * 72 + ks * 16 + g * 8);
            acc4 = __builtin_amdgcn_mfma_f32_32x32x16_bf16(a, bb, acc4, 0, 0, 0);
        }
    }
    {
#pragma unroll
        for (int rq = 0; rq < 4; ++rq) {
            int o0 = wr * 32 + 8 * rq + 4 * g;
            float4 f;
#pragma unroll
            for (int j = 0; j < 4; ++j) {
                int o = o0 + j;
                ((float*)&f)[j] = skv[rq * 4 + j] + acc4[rq * 4 + j] + coefS[256 + o];
            }
            *(float4*)(outS + tl * 68 + o0) = f;
        }
    }
    __syncthreads();

    {
        const int tt = tid >> 2, qq = tid & 3;
        float* ob = out + ((size_t)(b * TOK) + t0 + tt) * 64;
#pragma unroll
        for (int it = 0; it < 4; ++it) {
            *(float4*)(ob + it * 16 + qq * 4) =
                *(float4*)(outS + tt * 68 + it * 16 + qq * 4);
        }
    }
}

// ---------------------------------------------------------------------------
extern "C" void kernel_launch(void* const* d_in, const int* in_sizes, int n_in,
                              void* d_out, int out_size, void* d_ws, size_t ws_size,
                              hipStream_t stream) {
    const float* x      = (const float*)d_in[0];
    const float* conv_w = (const float*)d_in[1];
    const float* conv_b = (const float*)d_in[2];
    const float* ln1_g  = (const float*)d_in[3];
    const float* ln1_b  = (const float*)d_in[4];
    const float* kqv_w  = (const float*)d_in[5];
    const float* kqv_b  = (const float*)d_in[6];
    const float* proj_w = (const float*)d_in[7];
    const float* proj_b = (const float*)d_in[8];
    const float* w_perf = (const float*)d_in[9];
    const float* ln2_g  = (const float*)d_in[10];
    const float* ln2_b  = (const float*)d_in[11];
    const float* mlp_w1 = (const float*)d_in[12];
    const float* mlp_b1 = (const float*)d_in[13];
    const float* mlp_w2 = (const float*)d_in[14];
    const float* mlp_b2 = (const float*)d_in[15];

    float* ws = (float*)d_ws;
    short* w2c    = (short*)ws;                 // 110592 sh
    short* kwbf   = (short*)(ws + 55296);       // 36864 sh
    short* pTbf   = (short*)(ws + 73728);       // 4096 sh
    short* w1bf   = (short*)(ws + 75776);       // 4096 sh
    short* w2bf   = (short*)(ws + 77824);       // 4096 sh
    short* wpbf   = (short*)(ws + 79872);       // 2048 sh
    float* sum_kp = ws + 80896;                 // 1024 f
    short* kvbf   = (short*)(ws + 81920);       // 65536 sh -> ends ws+114688
    // tokens bf16 (dead after lnkqvp)
    short* tokens = (short*)(ws + 114688);      // 25165824 sh
    // region B: outputs of lnkqvp (must not alias tokens)
    float* wsB    = ws + 114688 + 12582912;
    short* vT     = (short*)wsB;                // 8388608 sh
    short* qpT    = (short*)(wsB + 4194304);    // 4194304 sh
    short* kpT    = (short*)(wsB + 6291456);    // 4194304 sh
    float* skpp   = wsB + 8388608;              // 16384 f
    float* kvp    = wsB + 8404992;              // 1048576 f
    float* outp   = (float*)d_out;

    k_prep   <<<632, 256, 0, stream>>>(conv_w, kqv_w, proj_w, mlp_w1, mlp_w2,
                                       w_perf, w2c, kwbf, pTbf, w1bf, w2bf, wpbf);
    k_conv6  <<<6144, 256, 0, stream>>>(x, w2c, conv_b, tokens);
    k_lnkqvp <<<dim3(64, 32), 256, 0, stream>>>(tokens, ln1_g, ln1_b, kwbf,
                                                kqv_b, wpbf, vT, kpT, qpT);
    k_kptv   <<<dim3(16, 32), 256, 0, stream>>>(vT, kpT, kvp, skpp);
    k_reduce2<<<260, 256, 0, stream>>>(kvp, skpp, kvbf, sum_kp);
    k_fuse   <<<dim3(64, 32), 256, 0, stream>>>(vT, qpT, kvbf, sum_kp,
                                                pTbf, proj_b, ln2_g, ln2_b,
                                                w1bf, mlp_b1, w2bf, mlp_b2, outp);
}